// Round 11
// baseline (1879.878 us; speedup 1.0000x reference)
//
#include <hip/hip_runtime.h>

typedef unsigned int uint32;
typedef __attribute__((ext_vector_type(4))) float  f32x4;
typedef __attribute__((ext_vector_type(8))) short  bf16x8;
typedef __attribute__((ext_vector_type(4))) unsigned short us4;
typedef __attribute__((ext_vector_type(8))) unsigned short us8;

#define N_ROWS   16384
#define D_IN     512
#define D_DICT   8192
#define TOPK     256
#define BAND     2e-3f
#define BCAP     64
#define CCAP     2048      // Tier C candidate cap
#define CAND_CAP 2048      // Tier B per-row global candidate capacity
#define TFIX     1.38f     // fixed collect threshold (see analysis)

__device__ __forceinline__ unsigned short f2bf_rne(float f) {
    unsigned u = __float_as_uint(f);
    unsigned r = u + 0x7FFFu + ((u >> 16) & 1u);
    return (unsigned short)(r >> 16);
}
__device__ __forceinline__ float bf2f(unsigned short h) {
    return __uint_as_float(((unsigned)h) << 16);
}
__device__ __forceinline__ uint32 okey(float v) {
    uint32 u = __float_as_uint(v);
    return (u & 0x80000000u) ? ~u : (u | 0x80000000u);
}
// XOR-swizzled LDS element address for [256][64] bf16 tiles (validated r5-r10)
__device__ __forceinline__ int swz(int row, int k) {
    return row * 64 + (k ^ ((row & 7) << 3));
}

// ---------------------------------------------------------------------------
// Kernel 0a: cast W_dec [512][8192] fp32 -> bf16 (same layout) into ws
// ---------------------------------------------------------------------------
__launch_bounds__(256)
__global__ void cast_wdec_kernel(const float* __restrict__ W,
                                 unsigned short* __restrict__ Wb) {
    size_t i = ((size_t)blockIdx.x * 256 + threadIdx.x) * 4;
    float4 v = *(const float4*)&W[i];
    us4 o;
    o.x = f2bf_rne(v.x); o.y = f2bf_rne(v.y);
    o.z = f2bf_rne(v.z); o.w = f2bf_rne(v.w);
    *(us4*)&Wb[i] = o;
}

// ---------------------------------------------------------------------------
// Kernel 0b: pre-split [nrows][512] fp32 -> [nrows][16][64] bf16 hi|lo with
// the per-row XOR swizzle baked in (validated r10).
// ---------------------------------------------------------------------------
__launch_bounds__(256)
__global__ void split_hilo_kernel(const float* __restrict__ W,
                                  unsigned short* __restrict__ S) {
    int idx = blockIdx.x * 256 + threadIdx.x;
    int row = idx >> 4;
    int c   = idx & 15;
    const float* src = W + (size_t)row * D_IN + c * 32;
    unsigned short hi[32], lo[32];
    #pragma unroll
    for (int j = 0; j < 32; ++j) {
        float v = src[j];
        unsigned short h = f2bf_rne(v);
        hi[j] = h; lo[j] = f2bf_rne(v - bf2f(h));
    }
    int m = row & 7;
    unsigned short* dst = S + ((size_t)row * 16 + c) * 64;
    #pragma unroll
    for (int g = 0; g < 8; ++g) {
        int lg = g ^ m;
        us8 o;
        #pragma unroll
        for (int j = 0; j < 8; ++j)
            o[j] = (lg < 4) ? hi[lg * 8 + j] : lo[(lg - 4) * 8 + j];
        *(us8*)&dst[g * 8] = o;
    }
}

// ---------------------------------------------------------------------------
// Kernel 1: MFMA encode, candidate-push epilogue. No P store. For each output
// element v = acc + bias: if v > TFIX, push (v, col) to the per-row global
// list via 16-lane-subgroup prefix + one atomicAdd per subgroup. Values are
// bitwise identical to r10's P entries.
// ---------------------------------------------------------------------------
__launch_bounds__(512)
__global__ void encode_mfma_cand(const unsigned short* __restrict__ Xs,
                                 const unsigned short* __restrict__ Ws,
                                 const float* __restrict__ b_enc,
                                 uint2* __restrict__ Cand,
                                 uint32* __restrict__ CandCnt) {
    __shared__ unsigned short At[256 * 64];
    __shared__ unsigned short Bt[256 * 64];

    int tid  = threadIdx.x;
    int lane = tid & 63;
    int wid  = tid >> 6;
    int wm   = wid >> 2;
    int wn   = wid & 3;
    int bm   = blockIdx.x * 256;
    int bn   = blockIdx.y * 256;
    int fr   = lane & 15;
    int fk   = (lane >> 4) << 3;

    f32x4 acc[8][4];
    #pragma unroll
    for (int i = 0; i < 8; ++i)
        #pragma unroll
        for (int j = 0; j < 4; ++j) acc[i][j] = (f32x4)0.f;

    int r8 = tid >> 3;
    int b8 = (tid & 7) * 8;

    for (int k0 = 0; k0 < D_IN; k0 += 32) {
        int c = k0 >> 5;
        #pragma unroll
        for (int q = 0; q < 4; ++q) {
            int row = q * 64 + r8;
            *(us8*)&At[row * 64 + b8] =
                *(const us8*)&Xs[((size_t)(bm + row) * 16 + c) * 64 + b8];
            *(us8*)&Bt[row * 64 + b8] =
                *(const us8*)&Ws[((size_t)(bn + row) * 16 + c) * 64 + b8];
        }
        __syncthreads();

        bf16x8 bh[4], bl[4];
        #pragma unroll
        for (int nj = 0; nj < 4; ++nj) {
            bh[nj] = *(const bf16x8*)&Bt[swz(wn * 64 + nj * 16 + fr, fk)];
            bl[nj] = *(const bf16x8*)&Bt[swz(wn * 64 + nj * 16 + fr, 32 + fk)];
        }
        #pragma unroll
        for (int mi = 0; mi < 8; ++mi) {
            bf16x8 ah = *(const bf16x8*)&At[swz(wm * 128 + mi * 16 + fr, fk)];
            bf16x8 al = *(const bf16x8*)&At[swz(wm * 128 + mi * 16 + fr, 32 + fk)];
            #pragma unroll
            for (int nj = 0; nj < 4; ++nj) {
                acc[mi][nj] = __builtin_amdgcn_mfma_f32_16x16x32_bf16(ah, bh[nj], acc[mi][nj], 0, 0, 0);
                acc[mi][nj] = __builtin_amdgcn_mfma_f32_16x16x32_bf16(ah, bl[nj], acc[mi][nj], 0, 0, 0);
                acc[mi][nj] = __builtin_amdgcn_mfma_f32_16x16x32_bf16(al, bh[nj], acc[mi][nj], 0, 0, 0);
            }
        }
        __syncthreads();
    }

    // epilogue: threshold + subgroup-aggregated candidate push
    float bcol[4];
    #pragma unroll
    for (int nj = 0; nj < 4; ++nj)
        bcol[nj] = b_enc[bn + wn * 64 + nj * 16 + fr];

    #pragma unroll
    for (int mi = 0; mi < 8; ++mi) {
        int rbase = bm + wm * 128 + mi * 16 + (lane >> 4) * 4;
        #pragma unroll
        for (int reg = 0; reg < 4; ++reg) {
            int r = rbase + reg;
            float v[4]; int pr[4]; int c = 0;
            #pragma unroll
            for (int nj = 0; nj < 4; ++nj) {
                v[nj] = acc[mi][nj][reg] + bcol[nj];
                pr[nj] = (v[nj] > TFIX) ? 1 : 0;
                c += pr[nj];
            }
            int incl = c;
            #pragma unroll
            for (int d = 1; d < 16; d <<= 1) {
                int tv = __shfl_up(incl, d, 16);
                if (fr >= d) incl += tv;
            }
            int total = __shfl(incl, 15, 16);
            if (total > 0) {
                int base = 0;
                if (fr == 0) base = (int)atomicAdd(&CandCnt[r], (uint32)total);
                base = __shfl(base, 0, 16);
                int slot = base + (incl - c);
                #pragma unroll
                for (int nj = 0; nj < 4; ++nj) {
                    if (pr[nj]) {
                        if (slot < CAND_CAP)
                            Cand[(size_t)r * CAND_CAP + slot] =
                                make_uint2(__float_as_uint(v[nj]),
                                           (uint32)(bn + wn * 64 + nj * 16 + fr));
                        ++slot;
                    }
                }
            }
        }
    }
}

// ---------------------------------------------------------------------------
// Kernel 2: select — radix over per-row candidates, exact band fixup, build
// row in LDS, stream to hidden (full-line writes). Flags pathological rows.
// ---------------------------------------------------------------------------
__launch_bounds__(256)
__global__ void select_kernel(const uint2* __restrict__ Cand,
                              const uint32* __restrict__ CandCnt,
                              const float* __restrict__ x,
                              const float* __restrict__ Wenc,
                              const float* __restrict__ b_enc,
                              float* __restrict__ hidden,
                              uint32* __restrict__ flags) {
    __shared__ float  row_buf[D_DICT];     // 32 KiB
    __shared__ float  cand_val[CAND_CAP];  // 8 KiB
    __shared__ int    cand_idx[CAND_CAP];  // 8 KiB
    __shared__ uint32 hist[256];
    __shared__ uint32 sh_prefix, sh_need;
    __shared__ int    c_clear, bcnt;
    __shared__ int    bidx_s[BCAP];
    __shared__ float  bval_s[BCAP];

    int row = blockIdx.x;
    int t = threadIdx.x;
    float* hrow = hidden + (size_t)row * D_DICT;

    int n = (int)CandCnt[row];
    bool ok = (n >= TOPK && n <= CAND_CAP);

    #pragma unroll
    for (int c = 0; c < 8; ++c)
        *(float4*)&row_buf[(c * 256 + t) * 4] = make_float4(0.f, 0.f, 0.f, 0.f);
    if (ok) {
        for (int e = t; e < n; e += 256) {
            uint2 cv = Cand[(size_t)row * CAND_CAP + e];
            cand_val[e] = __uint_as_float(cv.x);
            cand_idx[e] = (int)cv.y;
        }
    }
    __syncthreads();

    float vT0 = 0.f;
    if (ok) {
        uint32 prefix = 0, need = TOPK;
        for (int pass = 0; pass < 4; ++pass) {
            int shift = 24 - 8 * pass;
            hist[t] = 0;
            __syncthreads();
            uint32 mask_hi = pass ? (0xFFFFFFFFu << (shift + 8)) : 0u;
            for (int e = t; e < n; e += 256) {
                uint32 u = okey(cand_val[e]);
                if ((u & mask_hi) == prefix)
                    atomicAdd(&hist[(u >> shift) & 255u], 1u);
            }
            __syncthreads();
            if (t == 0) {
                uint32 cum = 0;
                int d = 255;
                for (; d > 0; --d) {
                    uint32 h = hist[d];
                    if (cum + h >= need) break;
                    cum += h;
                }
                sh_prefix = prefix | ((uint32)d << shift);
                sh_need = need - cum;
            }
            __syncthreads();
            prefix = sh_prefix;
            need = sh_need;
            __syncthreads();
        }
        uint32 tb = (prefix & 0x80000000u) ? (prefix & 0x7FFFFFFFu) : ~prefix;
        vT0 = __uint_as_float(tb);
        if (!(vT0 - BAND - 1e-3f > TFIX)) ok = false;   // pruning must be provably safe
    }

    if (!ok) {
        // flag for exact repair; stream zeros so the row is defined either way
        if (t == 0) flags[row] = 1u;
        #pragma unroll
        for (int c = 0; c < 8; ++c)
            *(float4*)&hrow[(c * 256 + t) * 4] = make_float4(0.f, 0.f, 0.f, 0.f);
        return;
    }

    if (t == 0) { c_clear = 0; bcnt = 0; }
    __syncthreads();
    for (int e = t; e < n; e += 256) {
        float v = cand_val[e];
        int i = cand_idx[e];
        if (v > vT0 + BAND) {
            row_buf[i] = fmaxf(v, 0.f);
            atomicAdd((uint32*)&c_clear, 1u);
        } else if (v >= vT0 - BAND) {
            int slot = atomicAdd((uint32*)&bcnt, 1u);
            if (slot < BCAP) bidx_s[slot] = i;
        }
    }
    __syncthreads();

    // exact recompute of band entries (np rounding class: ascending-k fmaf)
    int nb = bcnt < BCAP ? bcnt : BCAP;
    if (t < nb) {
        const float* xr = x + (size_t)row * D_IN;
        const float* wr = Wenc + (size_t)bidx_s[t] * D_IN;
        float acc = 0.f;
        #pragma unroll 8
        for (int k = 0; k < D_IN; ++k)   // ascending k — do not reorder
            acc = fmaf(xr[k], wr[k], acc);
        bval_s[t] = acc + b_enc[bidx_s[t]];
    }
    __syncthreads();
    if (t == 0) {
        int take = TOPK - c_clear;
        for (int rr = 0; rr < take; ++rr) {
            int best = -1; float bv = 0.f; int bi = 0;
            for (int e = 0; e < nb; ++e) {
                int idx = bidx_s[e];
                if (idx < 0) continue;
                float v = bval_s[e];
                if (best < 0 || v > bv || (v == bv && idx < bi)) {
                    best = e; bv = v; bi = idx;
                }
            }
            if (best < 0) break;
            bidx_s[best] = -1;
            row_buf[bi] = fmaxf(bv, 0.f);
        }
    }
    __syncthreads();

    #pragma unroll
    for (int c = 0; c < 8; ++c) {
        int e4 = (c * 256 + t) * 4;
        *(float4*)&hrow[e4] = *(const float4*)&row_buf[e4];
    }
}

// ---------------------------------------------------------------------------
// Kernel 2b: exact repair for flagged rows — full np-class recompute + exact
// radix select with tie handling (ties -> lowest index). Statistically never
// runs; correctness insurance for the fixed-threshold model.
// ---------------------------------------------------------------------------
__launch_bounds__(256)
__global__ void repair_kernel(const uint32* __restrict__ flags,
                              const float* __restrict__ x,
                              const float* __restrict__ Wenc,
                              const float* __restrict__ b_enc,
                              float* __restrict__ hidden) {
    int row = blockIdx.x;
    if (flags[row] == 0u) return;
    __shared__ float  vals[D_DICT];    // 32 KiB
    __shared__ float  xs[D_IN];
    __shared__ uint32 hist[256];
    __shared__ uint32 pscan[257];
    __shared__ uint32 cnt_eq[256];
    __shared__ uint32 sh_prefix, sh_need;
    int t = threadIdx.x;

    for (int c = t; c < D_IN; c += 256) xs[c] = x[(size_t)row * D_IN + c];
    __syncthreads();
    for (int e = t; e < D_DICT; e += 256) {
        const float* wr = Wenc + (size_t)e * D_IN;
        float acc = 0.f;
        #pragma unroll 8
        for (int k = 0; k < D_IN; ++k)   // ascending k — np rounding class
            acc = fmaf(xs[k], wr[k], acc);
        vals[e] = acc + b_enc[e];
    }
    __syncthreads();

    uint32 prefix = 0, need = TOPK;
    for (int pass = 0; pass < 4; ++pass) {
        int shift = 24 - 8 * pass;
        hist[t] = 0;
        __syncthreads();
        uint32 mask_hi = pass ? (0xFFFFFFFFu << (shift + 8)) : 0u;
        #pragma unroll 4
        for (int c = 0; c < 32; ++c) {
            uint32 u = okey(vals[c * 256 + t]);
            if ((u & mask_hi) == prefix)
                atomicAdd(&hist[(u >> shift) & 255u], 1u);
        }
        __syncthreads();
        if (t == 0) {
            uint32 cum = 0;
            int d = 255;
            for (; d > 0; --d) {
                uint32 h = hist[d];
                if (cum + h >= need) break;
                cum += h;
            }
            sh_prefix = prefix | ((uint32)d << shift);
            sh_need = need - cum;
        }
        __syncthreads();
        prefix = sh_prefix;
        need = sh_need;
        __syncthreads();
    }
    uint32 T = prefix;
    uint32 r = need;
    float* hrow = hidden + (size_t)row * D_DICT;

    #pragma unroll 2
    for (int c = 0; c < 32; ++c) {
        int i = c * 256 + t;
        uint32 u = okey(vals[i]);
        hrow[i] = (u > T) ? fmaxf(vals[i], 0.f) : 0.f;
    }
    __syncthreads();

    int base = t * 32;
    uint32 local = 0;
    for (int j = 0; j < 32; ++j) local += (okey(vals[base + j]) == T) ? 1u : 0u;
    cnt_eq[t] = local;
    __syncthreads();
    if (t == 0) {
        uint32 s = 0;
        for (int i = 0; i < 256; ++i) { pscan[i] = s; s += cnt_eq[i]; }
    }
    __syncthreads();
    uint32 myoff = pscan[t];
    if (local > 0 && myoff < r) {
        uint32 tb = (T & 0x80000000u) ? (T & 0x7FFFFFFFu) : ~T;
        float hv = fmaxf(__uint_as_float(tb), 0.f);
        uint32 rank = myoff;
        for (int j = 0; j < 32 && rank < r; ++j) {
            int i = base + j;
            if (okey(vals[i]) == T) { hrow[i] = hv; rank++; }
        }
    }
}

// ---------------------------------------------------------------------------
// Kernel 3: dense bf16 MFMA decode (validated rounds 5-10).
// ---------------------------------------------------------------------------
__launch_bounds__(512)
__global__ void mfma_decode_kernel(const float* __restrict__ hidden,
                                   const unsigned short* __restrict__ Wb,
                                   const float* __restrict__ b_dec,
                                   float* __restrict__ recon) {
    __shared__ unsigned short At[256 * 64];
    __shared__ unsigned short Bt[256 * 64];

    int tid  = threadIdx.x;
    int lane = tid & 63;
    int wid  = tid >> 6;
    int wm   = wid >> 2;
    int wn   = wid & 3;

    int bid = blockIdx.x;
    int bn  = (bid & 1) * 256;
    int bm  = (bid >> 1) * 256;

    f32x4 acc[8][4];
    #pragma unroll
    for (int i = 0; i < 8; ++i)
        #pragma unroll
        for (int j = 0; j < 4; ++j) acc[i][j] = (f32x4)0.f;

    for (int k0 = 0; k0 < D_DICT; k0 += 64) {
        #pragma unroll
        for (int i = 0; i < 8; ++i) {
            int idx = i * 512 + tid;
            int row = idx >> 4;
            int kq  = (idx & 15) * 4;
            float4 h4 = *(const float4*)&hidden[(size_t)(bm + row) * D_DICT + k0 + kq];
            us4 o;
            o.x = f2bf_rne(h4.x); o.y = f2bf_rne(h4.y);
            o.z = f2bf_rne(h4.z); o.w = f2bf_rne(h4.w);
            *(us4*)&At[swz(row, kq)] = o;
        }
        #pragma unroll
        for (int i = 0; i < 4; ++i) {
            int idx = i * 512 + tid;
            int row = idx >> 3;
            int kq8 = (idx & 7) * 8;
            us8 w8 = *(const us8*)&Wb[(size_t)(bn + row) * D_DICT + k0 + kq8];
            *(us8*)&Bt[swz(row, kq8)] = w8;
        }
        __syncthreads();

        #pragma unroll
        for (int ks = 0; ks < 2; ++ks) {
            int kb = ks * 32 + (lane >> 4) * 8;
            bf16x8 av[8], bv[4];
            #pragma unroll
            for (int mi = 0; mi < 8; ++mi)
                av[mi] = *(const bf16x8*)&At[swz(wm * 128 + mi * 16 + (lane & 15), kb)];
            #pragma unroll
            for (int nj = 0; nj < 4; ++nj)
                bv[nj] = *(const bf16x8*)&Bt[swz(wn * 64 + nj * 16 + (lane & 15), kb)];
            #pragma unroll
            for (int mi = 0; mi < 8; ++mi)
                #pragma unroll
                for (int nj = 0; nj < 4; ++nj)
                    acc[mi][nj] = __builtin_amdgcn_mfma_f32_16x16x32_bf16(
                        av[mi], bv[nj], acc[mi][nj], 0, 0, 0);
        }
        __syncthreads();
    }

    #pragma unroll
    for (int mi = 0; mi < 8; ++mi) {
        int r0 = bm + wm * 128 + mi * 16 + (lane >> 4) * 4;
        #pragma unroll
        for (int nj = 0; nj < 4; ++nj) {
            int col = bn + wn * 64 + nj * 16 + (lane & 15);
            float bd = b_dec[col];
            #pragma unroll
            for (int reg = 0; reg < 4; ++reg)
                recon[(size_t)(r0 + reg) * D_IN + col] = acc[mi][nj][reg] + bd;
        }
    }
}

// ---------------------------------------------------------------------------
// Tier C fallback kernels (validated r10): exact fp32 encode + topk + gather
// ---------------------------------------------------------------------------
#define EBK 8
#define ESTR 132

__launch_bounds__(256)
__global__ void encode_gemm_kernel(const float* __restrict__ X,
                                   const float* __restrict__ Wenc,
                                   const float* __restrict__ b_enc,
                                   float* __restrict__ P,
                                   int row0, int nrows) {
    __shared__ float As[EBK][ESTR];
    __shared__ float Bs[EBK][ESTR];
    int tid = threadIdx.x;
    int tx = tid & 15;
    int ty = tid >> 4;
    int bm = blockIdx.x * 128;
    int bn = blockIdx.y * 128;
    int srow = tid >> 1;
    int skq  = (tid & 1) * 4;

    float acc[8][8];
    #pragma unroll
    for (int i = 0; i < 8; ++i)
        #pragma unroll
        for (int j = 0; j < 8; ++j) acc[i][j] = 0.f;

    for (int k0 = 0; k0 < D_IN; k0 += EBK) {
        float4 a4 = make_float4(0.f, 0.f, 0.f, 0.f);
        if (bm + srow < nrows)
            a4 = *(const float4*)&X[(size_t)(row0 + bm + srow) * D_IN + k0 + skq];
        float4 b4 = *(const float4*)&Wenc[(size_t)(bn + srow) * D_IN + k0 + skq];
        As[skq + 0][srow] = a4.x; As[skq + 1][srow] = a4.y;
        As[skq + 2][srow] = a4.z; As[skq + 3][srow] = a4.w;
        Bs[skq + 0][srow] = b4.x; Bs[skq + 1][srow] = b4.y;
        Bs[skq + 2][srow] = b4.z; Bs[skq + 3][srow] = b4.w;
        __syncthreads();
        #pragma unroll
        for (int k = 0; k < EBK; ++k) {
            float4 a0 = *(const float4*)&As[k][ty * 4];
            float4 a1 = *(const float4*)&As[k][64 + ty * 4];
            float4 b0 = *(const float4*)&Bs[k][tx * 4];
            float4 b1 = *(const float4*)&Bs[k][64 + tx * 4];
            float a[8] = {a0.x, a0.y, a0.z, a0.w, a1.x, a1.y, a1.z, a1.w};
            float b[8] = {b0.x, b0.y, b0.z, b0.w, b1.x, b1.y, b1.z, b1.w};
            #pragma unroll
            for (int i = 0; i < 8; ++i)
                #pragma unroll
                for (int j = 0; j < 8; ++j)
                    acc[i][j] = fmaf(a[i], b[j], acc[i][j]);
        }
        __syncthreads();
    }

    float4 bias0 = *(const float4*)&b_enc[bn + tx * 4];
    float4 bias1 = *(const float4*)&b_enc[bn + 64 + tx * 4];
    float bb[8] = {bias0.x, bias0.y, bias0.z, bias0.w,
                   bias1.x, bias1.y, bias1.z, bias1.w};
    #pragma unroll
    for (int i = 0; i < 8; ++i) {
        int r = bm + (i < 4 ? ty * 4 + i : 64 + ty * 4 + (i - 4));
        if (r < nrows) {
            float4 o0, o1;
            o0.x = acc[i][0] + bb[0]; o0.y = acc[i][1] + bb[1];
            o0.z = acc[i][2] + bb[2]; o0.w = acc[i][3] + bb[3];
            o1.x = acc[i][4] + bb[4]; o1.y = acc[i][5] + bb[5];
            o1.z = acc[i][6] + bb[6]; o1.w = acc[i][7] + bb[7];
            *(float4*)&P[(size_t)r * D_DICT + bn + tx * 4] = o0;
            *(float4*)&P[(size_t)r * D_DICT + bn + 64 + tx * 4] = o1;
        }
    }
}

__launch_bounds__(256)
__global__ void topk_band_kernel(const float* __restrict__ P,
                                 int row0,
                                 const float* __restrict__ x,
                                 const float* __restrict__ Wenc,
                                 const float* __restrict__ b_enc,
                                 float* __restrict__ hidden) {
    __shared__ float  cand_val[CCAP];
    __shared__ int    cand_idx[CCAP];
    __shared__ uint32 hist[256];
    __shared__ float  redS[4], redS2[4];
    __shared__ float  sh_mu, sh_sig;
    __shared__ uint32 sh_prefix, sh_need;
    __shared__ int    sh_cnt, c_clear, bcnt;
    __shared__ int    bidx_s[BCAP];
    __shared__ float  bval_s[BCAP];

    int lrow = blockIdx.x;
    int grow = row0 + lrow;
    const float* p = P + (size_t)lrow * D_DICT;
    float* hrow = hidden + (size_t)grow * D_DICT;
    int t = threadIdx.x;

    if (t == 0) sh_cnt = 0;
    float s = 0.f, s2 = 0.f;
    #pragma unroll 2
    for (int c = 0; c < 8; ++c) {
        int e4 = c * 256 + t;
        float4 v4 = ((const float4*)p)[e4];
        s  += v4.x + v4.y + v4.z + v4.w;
        s2 += v4.x*v4.x + v4.y*v4.y + v4.z*v4.z + v4.w*v4.w;
        *(float4*)&hrow[e4 * 4] = make_float4(0.f, 0.f, 0.f, 0.f);
    }
    #pragma unroll
    for (int off = 32; off; off >>= 1) {
        s  += __shfl_down(s, off);
        s2 += __shfl_down(s2, off);
    }
    if ((t & 63) == 0) { redS[t >> 6] = s; redS2[t >> 6] = s2; }
    __syncthreads();
    if (t == 0) {
        float S  = redS[0] + redS[1] + redS[2] + redS[3];
        float S2 = redS2[0] + redS2[1] + redS2[2] + redS2[3];
        float mu = S * (1.f / D_DICT);
        float var = S2 * (1.f / D_DICT) - mu * mu;
        sh_mu = mu;
        sh_sig = sqrtf(fmaxf(var, 1e-20f));
    }
    __syncthreads();
    float Tlo = sh_mu + 1.3f * sh_sig;

    #pragma unroll 2
    for (int c = 0; c < 8; ++c) {
        int e4 = c * 256 + t;
        float4 v4 = ((const float4*)p)[e4];
        float vv[4] = {v4.x, v4.y, v4.z, v4.w};
        #pragma unroll
        for (int j = 0; j < 4; ++j) {
            if (vv[j] > Tlo) {
                int slot = atomicAdd((uint32*)&sh_cnt, 1u);
                if (slot < CCAP) { cand_val[slot] = vv[j]; cand_idx[slot] = e4 * 4 + j; }
            }
        }
    }
    __syncthreads();
    int n = sh_cnt;
    bool found = (n >= TOPK && n <= CCAP);

    float vT0 = 0.f;
    for (int rtry = 0; rtry < 2; ++rtry) {
        uint32 prefix = 0, need = TOPK;
        for (int pass = 0; pass < 4; ++pass) {
            int shift = 24 - 8 * pass;
            hist[t] = 0;
            __syncthreads();
            uint32 mask_hi = pass ? (0xFFFFFFFFu << (shift + 8)) : 0u;
            if (found) {
                for (int e = t; e < n; e += 256) {
                    uint32 u = okey(cand_val[e]);
                    if ((u & mask_hi) == prefix)
                        atomicAdd(&hist[(u >> shift) & 255u], 1u);
                }
            } else {
                for (int e = t; e < D_DICT; e += 256) {
                    uint32 u = okey(p[e]);
                    if ((u & mask_hi) == prefix)
                        atomicAdd(&hist[(u >> shift) & 255u], 1u);
                }
            }
            __syncthreads();
            if (t == 0) {
                uint32 cum = 0;
                int d = 255;
                for (; d > 0; --d) {
                    uint32 h = hist[d];
                    if (cum + h >= need) break;
                    cum += h;
                }
                sh_prefix = prefix | ((uint32)d << shift);
                sh_need = need - cum;
            }
            __syncthreads();
            prefix = sh_prefix;
            need = sh_need;
            __syncthreads();
        }
        uint32 tb = (prefix & 0x80000000u) ? (prefix & 0x7FFFFFFFu) : ~prefix;
        vT0 = __uint_as_float(tb);
        if (!found) break;
        if (vT0 - BAND - 1e-3f > Tlo) break;
        found = false;
        __syncthreads();
    }

    if (t == 0) { c_clear = 0; bcnt = 0; }
    __syncthreads();
    if (found) {
        for (int e = t; e < n; e += 256) {
            float v = cand_val[e];
            int i = cand_idx[e];
            if (v > vT0 + BAND) {
                hrow[i] = fmaxf(v, 0.f);
                atomicAdd((uint32*)&c_clear, 1u);
            } else if (v >= vT0 - BAND) {
                int slot = atomicAdd((uint32*)&bcnt, 1u);
                if (slot < BCAP) bidx_s[slot] = i;
            }
        }
    } else {
        for (int e = t; e < D_DICT; e += 256) {
            float v = p[e];
            if (v > vT0 + BAND) {
                hrow[e] = fmaxf(v, 0.f);
                atomicAdd((uint32*)&c_clear, 1u);
            } else if (v >= vT0 - BAND) {
                int slot = atomicAdd((uint32*)&bcnt, 1u);
                if (slot < BCAP) bidx_s[slot] = e;
            }
        }
    }
    __syncthreads();

    int nb = bcnt < BCAP ? bcnt : BCAP;
    if (t < nb) {
        const float* xr = x + (size_t)grow * D_IN;
        const float* wr = Wenc + (size_t)bidx_s[t] * D_IN;
        float acc = 0.f;
        #pragma unroll 8
        for (int k = 0; k < D_IN; ++k)
            acc = fmaf(xr[k], wr[k], acc);
        bval_s[t] = acc + b_enc[bidx_s[t]];
    }
    __syncthreads();
    if (t == 0) {
        int take = TOPK - c_clear;
        for (int rr = 0; rr < take; ++rr) {
            int best = -1; float bv = 0.f; int bi = 0;
            for (int e = 0; e < nb; ++e) {
                int idx = bidx_s[e];
                if (idx < 0) continue;
                float v = bval_s[e];
                if (best < 0 || v > bv || (v == bv && idx < bi)) {
                    best = e; bv = v; bi = idx;
                }
            }
            if (best < 0) break;
            bidx_s[best] = -1;
            hrow[bi] = fmaxf(bv, 0.f);
        }
    }
}

__launch_bounds__(256)
__global__ void decode_direct_kernel(const float* __restrict__ hidden,
                                     const float* __restrict__ W_dec,
                                     const float* __restrict__ b_dec,
                                     float* __restrict__ recon) {
    __shared__ float  sv[TOPK];
    __shared__ int    sidx[TOPK];
    __shared__ int    offs[257];
    int row = blockIdx.x;
    int t = threadIdx.x;
    const float* hrow = hidden + (size_t)row * D_DICT;

    int base = t * 32;
    int c = 0;
    for (int j = 0; j < 32; ++j) c += (hrow[base + j] > 0.f) ? 1 : 0;
    offs[t + 1] = c;
    __syncthreads();
    if (t == 0) {
        offs[0] = 0;
        for (int i = 0; i < 256; ++i) offs[i + 1] += offs[i];
    }
    __syncthreads();
    int o = offs[t];
    for (int j = 0; j < 32; ++j) {
        float v = hrow[base + j];
        if (v > 0.f) { sv[o] = v; sidx[o] = base + j; ++o; }
    }
    __syncthreads();
    int total = offs[256];

    int d0 = 2 * t;
    float acc0 = b_dec[d0];
    float acc1 = b_dec[d0 + 1];
    for (int k = 0; k < total; ++k) {
        float v = sv[k];
        int idx = sidx[k];
        acc0 = fmaf(v, W_dec[(size_t)d0 * D_DICT + idx], acc0);
        acc1 = fmaf(v, W_dec[(size_t)(d0 + 1) * D_DICT + idx], acc1);
    }
    *(float2*)&recon[(size_t)row * D_IN + d0] = make_float2(acc0, acc1);
}

// ---------------------------------------------------------------------------
extern "C" void kernel_launch(void* const* d_in, const int* in_sizes, int n_in,
                              void* d_out, int out_size, void* d_ws, size_t ws_size,
                              hipStream_t stream) {
    const float* x     = (const float*)d_in[0];
    const float* W_enc = (const float*)d_in[1];
    const float* b_enc = (const float*)d_in[2];
    const float* W_dec = (const float*)d_in[3];
    const float* b_dec = (const float*)d_in[4];

    float* out    = (float*)d_out;
    float* recon  = out;                          // 16384*512 fp32
    float* hidden = out + (size_t)N_ROWS * D_IN;  // 16384*8192 fp32

    const size_t CNT_BYTES  = (size_t)N_ROWS * sizeof(uint32);                   // 64 KiB
    const size_t FLG_BYTES  = (size_t)N_ROWS * sizeof(uint32);                   // 64 KiB
    const size_t WB_BYTES   = (size_t)D_IN * D_DICT * sizeof(unsigned short);    // 8 MiB
    const size_t WS_BYTES   = (size_t)D_DICT * 16 * 64 * sizeof(unsigned short); // 16 MiB
    const size_t XS_BYTES   = (size_t)N_ROWS * 16 * 64 * sizeof(unsigned short); // 32 MiB
    const size_t CAND_BYTES = (size_t)N_ROWS * CAND_CAP * sizeof(uint2);         // 256 MiB
    const size_t FIXED_B    = CNT_BYTES + FLG_BYTES + WB_BYTES + WS_BYTES + XS_BYTES + CAND_BYTES;
    const size_t ROW_BYTES  = (size_t)D_DICT * sizeof(float);

    char* ws = (char*)d_ws;

    if (ws_size >= FIXED_B) {
        // Tier B: candidate-push MFMA encode + select/repair + MFMA decode
        uint32*         CandCnt = (uint32*)ws;
        uint32*         flags   = (uint32*)(ws + CNT_BYTES);
        unsigned short* Wb      = (unsigned short*)(ws + CNT_BYTES + FLG_BYTES);
        unsigned short* Wsp     = (unsigned short*)(ws + CNT_BYTES + FLG_BYTES + WB_BYTES);
        unsigned short* Xsp     = (unsigned short*)(ws + CNT_BYTES + FLG_BYTES + WB_BYTES + WS_BYTES);
        uint2*          Cand    = (uint2*)(ws + CNT_BYTES + FLG_BYTES + WB_BYTES + WS_BYTES + XS_BYTES);

        hipMemsetAsync(CandCnt, 0, CNT_BYTES + FLG_BYTES, stream);
        cast_wdec_kernel<<<(D_IN * D_DICT) / 1024, 256, 0, stream>>>(W_dec, Wb);
        split_hilo_kernel<<<(D_DICT * 16) / 256, 256, 0, stream>>>(W_enc, Wsp);
        split_hilo_kernel<<<(N_ROWS * 16) / 256, 256, 0, stream>>>(x, Xsp);

        encode_mfma_cand<<<dim3(N_ROWS / 256, D_DICT / 256), 512, 0, stream>>>(
            Xsp, Wsp, b_enc, Cand, CandCnt);
        select_kernel<<<N_ROWS, 256, 0, stream>>>(Cand, CandCnt, x, W_enc, b_enc, hidden, flags);
        repair_kernel<<<N_ROWS, 256, 0, stream>>>(flags, x, W_enc, b_enc, hidden);

        mfma_decode_kernel<<<(N_ROWS / 256) * 2, 512, 0, stream>>>(hidden, Wb, b_dec, recon);
    } else {
        // Tier C: exact fp32 encode + two-pass topk + gather decode (tiny ws)
        float* pre = (float*)ws;
        long long cl = (long long)(ws_size / ROW_BYTES);
        int chunk;
        if (cl >= 128) { chunk = (cl > 2048) ? 2048 : (int)cl; chunk &= ~127; }
        else chunk = (cl < 1) ? 1 : (int)cl;

        for (int r0 = 0; r0 < N_ROWS; r0 += chunk) {
            int nr = (N_ROWS - r0 < chunk) ? (N_ROWS - r0) : chunk;
            dim3 grid((nr + 127) / 128, D_DICT / 128);
            encode_gemm_kernel<<<grid, 256, 0, stream>>>(x, W_enc, b_enc, pre, r0, nr);
            topk_band_kernel<<<nr, 256, 0, stream>>>(pre, r0, x, W_enc, b_enc, hidden);
        }
        decode_direct_kernel<<<N_ROWS, 256, 0, stream>>>(hidden, W_dec, b_dec, recon);
    }
}

// Round 12
// 1457.901 us; speedup vs baseline: 1.2894x; 1.2894x over previous
//
#include <hip/hip_runtime.h>

typedef unsigned int uint32;
typedef __attribute__((ext_vector_type(4))) float  f32x4;
typedef __attribute__((ext_vector_type(8))) short  bf16x8;
typedef __attribute__((ext_vector_type(4))) unsigned short us4;
typedef __attribute__((ext_vector_type(8))) unsigned short us8;

#define N_ROWS   16384
#define D_IN     512
#define D_DICT   8192
#define TOPK     256
#define BAND     2e-3f
#define BCAP     64
#define CCAP     2048      // Tier C candidate cap
#define CAND_CAP 2048      // Tier B per-row global candidate capacity
#define TFIX     1.38f     // fixed collect threshold (validated r11: no repairs fired)

__device__ __forceinline__ unsigned short f2bf_rne(float f) {
    unsigned u = __float_as_uint(f);
    unsigned r = u + 0x7FFFu + ((u >> 16) & 1u);
    return (unsigned short)(r >> 16);
}
__device__ __forceinline__ float bf2f(unsigned short h) {
    return __uint_as_float(((unsigned)h) << 16);
}
__device__ __forceinline__ uint32 okey(float v) {
    uint32 u = __float_as_uint(v);
    return (u & 0x80000000u) ? ~u : (u | 0x80000000u);
}
// XOR-swizzled LDS element address for [256][64] bf16 tiles (validated r5-r11)
__device__ __forceinline__ int swz(int row, int k) {
    return row * 64 + (k ^ ((row & 7) << 3));
}

// ---------------------------------------------------------------------------
// Kernel 0a: cast W_dec [512][8192] fp32 -> bf16 (same layout) into ws
// ---------------------------------------------------------------------------
__launch_bounds__(256)
__global__ void cast_wdec_kernel(const float* __restrict__ W,
                                 unsigned short* __restrict__ Wb) {
    size_t i = ((size_t)blockIdx.x * 256 + threadIdx.x) * 4;
    float4 v = *(const float4*)&W[i];
    us4 o;
    o.x = f2bf_rne(v.x); o.y = f2bf_rne(v.y);
    o.z = f2bf_rne(v.z); o.w = f2bf_rne(v.w);
    *(us4*)&Wb[i] = o;
}

// ---------------------------------------------------------------------------
// Kernel 0b: pre-split [nrows][512] fp32 -> [nrows][16][64] bf16 hi|lo with
// the per-row XOR swizzle baked in (validated r10/r11).
// ---------------------------------------------------------------------------
__launch_bounds__(256)
__global__ void split_hilo_kernel(const float* __restrict__ W,
                                  unsigned short* __restrict__ S) {
    int idx = blockIdx.x * 256 + threadIdx.x;
    int row = idx >> 4;
    int c   = idx & 15;
    const float* src = W + (size_t)row * D_IN + c * 32;
    unsigned short hi[32], lo[32];
    #pragma unroll
    for (int j = 0; j < 32; ++j) {
        float v = src[j];
        unsigned short h = f2bf_rne(v);
        hi[j] = h; lo[j] = f2bf_rne(v - bf2f(h));
    }
    int m = row & 7;
    unsigned short* dst = S + ((size_t)row * 16 + c) * 64;
    #pragma unroll
    for (int g = 0; g < 8; ++g) {
        int lg = g ^ m;
        us8 o;
        #pragma unroll
        for (int j = 0; j < 8; ++j)
            o[j] = (lg < 4) ? hi[lg * 8 + j] : lo[(lg - 4) * 8 + j];
        *(us8*)&dst[g * 8] = o;
    }
}

// ---------------------------------------------------------------------------
// Kernel 1: MFMA encode, candidate-push epilogue (validated r11). No P store.
// ---------------------------------------------------------------------------
__launch_bounds__(512)
__global__ void encode_mfma_cand(const unsigned short* __restrict__ Xs,
                                 const unsigned short* __restrict__ Ws,
                                 const float* __restrict__ b_enc,
                                 uint2* __restrict__ Cand,
                                 uint32* __restrict__ CandCnt) {
    __shared__ unsigned short At[256 * 64];
    __shared__ unsigned short Bt[256 * 64];

    int tid  = threadIdx.x;
    int lane = tid & 63;
    int wid  = tid >> 6;
    int wm   = wid >> 2;
    int wn   = wid & 3;
    int bm   = blockIdx.x * 256;
    int bn   = blockIdx.y * 256;
    int fr   = lane & 15;
    int fk   = (lane >> 4) << 3;

    f32x4 acc[8][4];
    #pragma unroll
    for (int i = 0; i < 8; ++i)
        #pragma unroll
        for (int j = 0; j < 4; ++j) acc[i][j] = (f32x4)0.f;

    int r8 = tid >> 3;
    int b8 = (tid & 7) * 8;

    for (int k0 = 0; k0 < D_IN; k0 += 32) {
        int c = k0 >> 5;
        #pragma unroll
        for (int q = 0; q < 4; ++q) {
            int row = q * 64 + r8;
            *(us8*)&At[row * 64 + b8] =
                *(const us8*)&Xs[((size_t)(bm + row) * 16 + c) * 64 + b8];
            *(us8*)&Bt[row * 64 + b8] =
                *(const us8*)&Ws[((size_t)(bn + row) * 16 + c) * 64 + b8];
        }
        __syncthreads();

        bf16x8 bh[4], bl[4];
        #pragma unroll
        for (int nj = 0; nj < 4; ++nj) {
            bh[nj] = *(const bf16x8*)&Bt[swz(wn * 64 + nj * 16 + fr, fk)];
            bl[nj] = *(const bf16x8*)&Bt[swz(wn * 64 + nj * 16 + fr, 32 + fk)];
        }
        #pragma unroll
        for (int mi = 0; mi < 8; ++mi) {
            bf16x8 ah = *(const bf16x8*)&At[swz(wm * 128 + mi * 16 + fr, fk)];
            bf16x8 al = *(const bf16x8*)&At[swz(wm * 128 + mi * 16 + fr, 32 + fk)];
            #pragma unroll
            for (int nj = 0; nj < 4; ++nj) {
                acc[mi][nj] = __builtin_amdgcn_mfma_f32_16x16x32_bf16(ah, bh[nj], acc[mi][nj], 0, 0, 0);
                acc[mi][nj] = __builtin_amdgcn_mfma_f32_16x16x32_bf16(ah, bl[nj], acc[mi][nj], 0, 0, 0);
                acc[mi][nj] = __builtin_amdgcn_mfma_f32_16x16x32_bf16(al, bh[nj], acc[mi][nj], 0, 0, 0);
            }
        }
        __syncthreads();
    }

    float bcol[4];
    #pragma unroll
    for (int nj = 0; nj < 4; ++nj)
        bcol[nj] = b_enc[bn + wn * 64 + nj * 16 + fr];

    #pragma unroll
    for (int mi = 0; mi < 8; ++mi) {
        int rbase = bm + wm * 128 + mi * 16 + (lane >> 4) * 4;
        #pragma unroll
        for (int reg = 0; reg < 4; ++reg) {
            int r = rbase + reg;
            float v[4]; int pr[4]; int c = 0;
            #pragma unroll
            for (int nj = 0; nj < 4; ++nj) {
                v[nj] = acc[mi][nj][reg] + bcol[nj];
                pr[nj] = (v[nj] > TFIX) ? 1 : 0;
                c += pr[nj];
            }
            int incl = c;
            #pragma unroll
            for (int d = 1; d < 16; d <<= 1) {
                int tv = __shfl_up(incl, d, 16);
                if (fr >= d) incl += tv;
            }
            int total = __shfl(incl, 15, 16);
            if (total > 0) {
                int base = 0;
                if (fr == 0) base = (int)atomicAdd(&CandCnt[r], (uint32)total);
                base = __shfl(base, 0, 16);
                int slot = base + (incl - c);
                #pragma unroll
                for (int nj = 0; nj < 4; ++nj) {
                    if (pr[nj]) {
                        if (slot < CAND_CAP)
                            Cand[(size_t)r * CAND_CAP + slot] =
                                make_uint2(__float_as_uint(v[nj]),
                                           (uint32)(bn + wn * 64 + nj * 16 + fr));
                        ++slot;
                    }
                }
            }
        }
    }
}

// ---------------------------------------------------------------------------
// Kernel 2 (v2): select — zero-fill hidden with STREAMING stores, radix over
// LDS-resident candidates, scatter winners DIRECTLY to global hidden (no
// 32KB row_buf -> ~18KB LDS -> thread-capped occupancy; r7/r11 lesson).
// Semantics bitwise identical to r11's select.
// ---------------------------------------------------------------------------
__launch_bounds__(256)
__global__ void select_kernel(const uint2* __restrict__ Cand,
                              const uint32* __restrict__ CandCnt,
                              const float* __restrict__ x,
                              const float* __restrict__ Wenc,
                              const float* __restrict__ b_enc,
                              float* __restrict__ hidden,
                              uint32* __restrict__ flags) {
    __shared__ float  cand_val[CAND_CAP];  // 8 KiB
    __shared__ int    cand_idx[CAND_CAP];  // 8 KiB
    __shared__ uint32 hist[256];           // 1 KiB
    __shared__ uint32 sh_prefix, sh_need;
    __shared__ int    c_clear, bcnt;
    __shared__ int    bidx_s[BCAP];
    __shared__ float  bval_s[BCAP];

    int row = blockIdx.x;
    int t = threadIdx.x;
    float* hrow = hidden + (size_t)row * D_DICT;

    int n = (int)CandCnt[row];
    bool ok = (n >= TOPK && n <= CAND_CAP);

    // zero-fill hidden row (streaming float4) + load candidates to LDS
    #pragma unroll
    for (int c = 0; c < 8; ++c)
        *(float4*)&hrow[(c * 256 + t) * 4] = make_float4(0.f, 0.f, 0.f, 0.f);
    if (ok) {
        for (int e = t; e < n; e += 256) {
            uint2 cv = Cand[(size_t)row * CAND_CAP + e];
            cand_val[e] = __uint_as_float(cv.x);
            cand_idx[e] = (int)cv.y;
        }
    }
    __syncthreads();

    float vT0 = 0.f;
    if (ok) {
        uint32 prefix = 0, need = TOPK;
        for (int pass = 0; pass < 4; ++pass) {
            int shift = 24 - 8 * pass;
            hist[t] = 0;
            __syncthreads();
            uint32 mask_hi = pass ? (0xFFFFFFFFu << (shift + 8)) : 0u;
            for (int e = t; e < n; e += 256) {
                uint32 u = okey(cand_val[e]);
                if ((u & mask_hi) == prefix)
                    atomicAdd(&hist[(u >> shift) & 255u], 1u);
            }
            __syncthreads();
            if (t == 0) {
                uint32 cum = 0;
                int d = 255;
                for (; d > 0; --d) {
                    uint32 h = hist[d];
                    if (cum + h >= need) break;
                    cum += h;
                }
                sh_prefix = prefix | ((uint32)d << shift);
                sh_need = need - cum;
            }
            __syncthreads();
            prefix = sh_prefix;
            need = sh_need;
            __syncthreads();
        }
        uint32 tb = (prefix & 0x80000000u) ? (prefix & 0x7FFFFFFFu) : ~prefix;
        vT0 = __uint_as_float(tb);
        if (!(vT0 - BAND - 1e-3f > TFIX)) ok = false;   // pruning must be provably safe
    }

    if (!ok) {
        if (t == 0) flags[row] = 1u;   // repaired exactly later; row already zeroed
        return;
    }

    if (t == 0) { c_clear = 0; bcnt = 0; }
    __syncthreads();
    // classify: clear winners scatter directly to global; band -> exact list
    for (int e = t; e < n; e += 256) {
        float v = cand_val[e];
        int i = cand_idx[e];
        if (v > vT0 + BAND) {
            hrow[i] = fmaxf(v, 0.f);
            atomicAdd((uint32*)&c_clear, 1u);
        } else if (v >= vT0 - BAND) {
            int slot = atomicAdd((uint32*)&bcnt, 1u);
            if (slot < BCAP) bidx_s[slot] = i;
        }
    }
    __syncthreads();

    // exact recompute of band entries (np rounding class: ascending-k fmaf)
    int nb = bcnt < BCAP ? bcnt : BCAP;
    if (t < nb) {
        const float* xr = x + (size_t)row * D_IN;
        const float* wr = Wenc + (size_t)bidx_s[t] * D_IN;
        float acc = 0.f;
        #pragma unroll 8
        for (int k = 0; k < D_IN; ++k)   // ascending k — do not reorder
            acc = fmaf(xr[k], wr[k], acc);
        bval_s[t] = acc + b_enc[bidx_s[t]];
    }
    __syncthreads();
    if (t == 0) {
        int take = TOPK - c_clear;
        for (int rr = 0; rr < take; ++rr) {
            int best = -1; float bv = 0.f; int bi = 0;
            for (int e = 0; e < nb; ++e) {
                int idx = bidx_s[e];
                if (idx < 0) continue;
                float v = bval_s[e];
                if (best < 0 || v > bv || (v == bv && idx < bi)) {
                    best = e; bv = v; bi = idx;
                }
            }
            if (best < 0) break;
            bidx_s[best] = -1;
            hrow[bi] = fmaxf(bv, 0.f);
        }
    }
}

// ---------------------------------------------------------------------------
// Kernel 2b: exact repair for flagged rows (validated r11; statistically never
// runs — correctness insurance for the fixed-threshold model).
// ---------------------------------------------------------------------------
__launch_bounds__(256)
__global__ void repair_kernel(const uint32* __restrict__ flags,
                              const float* __restrict__ x,
                              const float* __restrict__ Wenc,
                              const float* __restrict__ b_enc,
                              float* __restrict__ hidden) {
    int row = blockIdx.x;
    if (flags[row] == 0u) return;
    __shared__ float  vals[D_DICT];
    __shared__ float  xs[D_IN];
    __shared__ uint32 hist[256];
    __shared__ uint32 pscan[257];
    __shared__ uint32 cnt_eq[256];
    __shared__ uint32 sh_prefix, sh_need;
    int t = threadIdx.x;

    for (int c = t; c < D_IN; c += 256) xs[c] = x[(size_t)row * D_IN + c];
    __syncthreads();
    for (int e = t; e < D_DICT; e += 256) {
        const float* wr = Wenc + (size_t)e * D_IN;
        float acc = 0.f;
        #pragma unroll 8
        for (int k = 0; k < D_IN; ++k)   // ascending k — np rounding class
            acc = fmaf(xs[k], wr[k], acc);
        vals[e] = acc + b_enc[e];
    }
    __syncthreads();

    uint32 prefix = 0, need = TOPK;
    for (int pass = 0; pass < 4; ++pass) {
        int shift = 24 - 8 * pass;
        hist[t] = 0;
        __syncthreads();
        uint32 mask_hi = pass ? (0xFFFFFFFFu << (shift + 8)) : 0u;
        #pragma unroll 4
        for (int c = 0; c < 32; ++c) {
            uint32 u = okey(vals[c * 256 + t]);
            if ((u & mask_hi) == prefix)
                atomicAdd(&hist[(u >> shift) & 255u], 1u);
        }
        __syncthreads();
        if (t == 0) {
            uint32 cum = 0;
            int d = 255;
            for (; d > 0; --d) {
                uint32 h = hist[d];
                if (cum + h >= need) break;
                cum += h;
            }
            sh_prefix = prefix | ((uint32)d << shift);
            sh_need = need - cum;
        }
        __syncthreads();
        prefix = sh_prefix;
        need = sh_need;
        __syncthreads();
    }
    uint32 T = prefix;
    uint32 r = need;
    float* hrow = hidden + (size_t)row * D_DICT;

    #pragma unroll 2
    for (int c = 0; c < 32; ++c) {
        int i = c * 256 + t;
        uint32 u = okey(vals[i]);
        hrow[i] = (u > T) ? fmaxf(vals[i], 0.f) : 0.f;
    }
    __syncthreads();

    int base = t * 32;
    uint32 local = 0;
    for (int j = 0; j < 32; ++j) local += (okey(vals[base + j]) == T) ? 1u : 0u;
    cnt_eq[t] = local;
    __syncthreads();
    if (t == 0) {
        uint32 s = 0;
        for (int i = 0; i < 256; ++i) { pscan[i] = s; s += cnt_eq[i]; }
    }
    __syncthreads();
    uint32 myoff = pscan[t];
    if (local > 0 && myoff < r) {
        uint32 tb = (T & 0x80000000u) ? (T & 0x7FFFFFFFu) : ~T;
        float hv = fmaxf(__uint_as_float(tb), 0.f);
        uint32 rank = myoff;
        for (int j = 0; j < 32 && rank < r; ++j) {
            int i = base + j;
            if (okey(vals[i]) == T) { hrow[i] = hv; rank++; }
        }
    }
}

// ---------------------------------------------------------------------------
// Kernel 3: dense bf16 MFMA decode (validated rounds 5-11).
// ---------------------------------------------------------------------------
__launch_bounds__(512)
__global__ void mfma_decode_kernel(const float* __restrict__ hidden,
                                   const unsigned short* __restrict__ Wb,
                                   const float* __restrict__ b_dec,
                                   float* __restrict__ recon) {
    __shared__ unsigned short At[256 * 64];
    __shared__ unsigned short Bt[256 * 64];

    int tid  = threadIdx.x;
    int lane = tid & 63;
    int wid  = tid >> 6;
    int wm   = wid >> 2;
    int wn   = wid & 3;

    int bid = blockIdx.x;
    int bn  = (bid & 1) * 256;
    int bm  = (bid >> 1) * 256;

    f32x4 acc[8][4];
    #pragma unroll
    for (int i = 0; i < 8; ++i)
        #pragma unroll
        for (int j = 0; j < 4; ++j) acc[i][j] = (f32x4)0.f;

    for (int k0 = 0; k0 < D_DICT; k0 += 64) {
        #pragma unroll
        for (int i = 0; i < 8; ++i) {
            int idx = i * 512 + tid;
            int row = idx >> 4;
            int kq  = (idx & 15) * 4;
            float4 h4 = *(const float4*)&hidden[(size_t)(bm + row) * D_DICT + k0 + kq];
            us4 o;
            o.x = f2bf_rne(h4.x); o.y = f2bf_rne(h4.y);
            o.z = f2bf_rne(h4.z); o.w = f2bf_rne(h4.w);
            *(us4*)&At[swz(row, kq)] = o;
        }
        #pragma unroll
        for (int i = 0; i < 4; ++i) {
            int idx = i * 512 + tid;
            int row = idx >> 3;
            int kq8 = (idx & 7) * 8;
            us8 w8 = *(const us8*)&Wb[(size_t)(bn + row) * D_DICT + k0 + kq8];
            *(us8*)&Bt[swz(row, kq8)] = w8;
        }
        __syncthreads();

        #pragma unroll
        for (int ks = 0; ks < 2; ++ks) {
            int kb = ks * 32 + (lane >> 4) * 8;
            bf16x8 av[8], bv[4];
            #pragma unroll
            for (int mi = 0; mi < 8; ++mi)
                av[mi] = *(const bf16x8*)&At[swz(wm * 128 + mi * 16 + (lane & 15), kb)];
            #pragma unroll
            for (int nj = 0; nj < 4; ++nj)
                bv[nj] = *(const bf16x8*)&Bt[swz(wn * 64 + nj * 16 + (lane & 15), kb)];
            #pragma unroll
            for (int mi = 0; mi < 8; ++mi)
                #pragma unroll
                for (int nj = 0; nj < 4; ++nj)
                    acc[mi][nj] = __builtin_amdgcn_mfma_f32_16x16x32_bf16(
                        av[mi], bv[nj], acc[mi][nj], 0, 0, 0);
        }
        __syncthreads();
    }

    #pragma unroll
    for (int mi = 0; mi < 8; ++mi) {
        int r0 = bm + wm * 128 + mi * 16 + (lane >> 4) * 4;
        #pragma unroll
        for (int nj = 0; nj < 4; ++nj) {
            int col = bn + wn * 64 + nj * 16 + (lane & 15);
            float bd = b_dec[col];
            #pragma unroll
            for (int reg = 0; reg < 4; ++reg)
                recon[(size_t)(r0 + reg) * D_IN + col] = acc[mi][nj][reg] + bd;
        }
    }
}

// ---------------------------------------------------------------------------
// Tier C fallback kernels (validated r10): exact fp32 encode + topk + gather
// ---------------------------------------------------------------------------
#define EBK 8
#define ESTR 132

__launch_bounds__(256)
__global__ void encode_gemm_kernel(const float* __restrict__ X,
                                   const float* __restrict__ Wenc,
                                   const float* __restrict__ b_enc,
                                   float* __restrict__ P,
                                   int row0, int nrows) {
    __shared__ float As[EBK][ESTR];
    __shared__ float Bs[EBK][ESTR];
    int tid = threadIdx.x;
    int tx = tid & 15;
    int ty = tid >> 4;
    int bm = blockIdx.x * 128;
    int bn = blockIdx.y * 128;
    int srow = tid >> 1;
    int skq  = (tid & 1) * 4;

    float acc[8][8];
    #pragma unroll
    for (int i = 0; i < 8; ++i)
        #pragma unroll
        for (int j = 0; j < 8; ++j) acc[i][j] = 0.f;

    for (int k0 = 0; k0 < D_IN; k0 += EBK) {
        float4 a4 = make_float4(0.f, 0.f, 0.f, 0.f);
        if (bm + srow < nrows)
            a4 = *(const float4*)&X[(size_t)(row0 + bm + srow) * D_IN + k0 + skq];
        float4 b4 = *(const float4*)&Wenc[(size_t)(bn + srow) * D_IN + k0 + skq];
        As[skq + 0][srow] = a4.x; As[skq + 1][srow] = a4.y;
        As[skq + 2][srow] = a4.z; As[skq + 3][srow] = a4.w;
        Bs[skq + 0][srow] = b4.x; Bs[skq + 1][srow] = b4.y;
        Bs[skq + 2][srow] = b4.z; Bs[skq + 3][srow] = b4.w;
        __syncthreads();
        #pragma unroll
        for (int k = 0; k < EBK; ++k) {
            float4 a0 = *(const float4*)&As[k][ty * 4];
            float4 a1 = *(const float4*)&As[k][64 + ty * 4];
            float4 b0 = *(const float4*)&Bs[k][tx * 4];
            float4 b1 = *(const float4*)&Bs[k][64 + tx * 4];
            float a[8] = {a0.x, a0.y, a0.z, a0.w, a1.x, a1.y, a1.z, a1.w};
            float b[8] = {b0.x, b0.y, b0.z, b0.w, b1.x, b1.y, b1.z, b1.w};
            #pragma unroll
            for (int i = 0; i < 8; ++i)
                #pragma unroll
                for (int j = 0; j < 8; ++j)
                    acc[i][j] = fmaf(a[i], b[j], acc[i][j]);
        }
        __syncthreads();
    }

    float4 bias0 = *(const float4*)&b_enc[bn + tx * 4];
    float4 bias1 = *(const float4*)&b_enc[bn + 64 + tx * 4];
    float bb[8] = {bias0.x, bias0.y, bias0.z, bias0.w,
                   bias1.x, bias1.y, bias1.z, bias1.w};
    #pragma unroll
    for (int i = 0; i < 8; ++i) {
        int r = bm + (i < 4 ? ty * 4 + i : 64 + ty * 4 + (i - 4));
        if (r < nrows) {
            float4 o0, o1;
            o0.x = acc[i][0] + bb[0]; o0.y = acc[i][1] + bb[1];
            o0.z = acc[i][2] + bb[2]; o0.w = acc[i][3] + bb[3];
            o1.x = acc[i][4] + bb[4]; o1.y = acc[i][5] + bb[5];
            o1.z = acc[i][6] + bb[6]; o1.w = acc[i][7] + bb[7];
            *(float4*)&P[(size_t)r * D_DICT + bn + tx * 4] = o0;
            *(float4*)&P[(size_t)r * D_DICT + bn + 64 + tx * 4] = o1;
        }
    }
}

__launch_bounds__(256)
__global__ void topk_band_kernel(const float* __restrict__ P,
                                 int row0,
                                 const float* __restrict__ x,
                                 const float* __restrict__ Wenc,
                                 const float* __restrict__ b_enc,
                                 float* __restrict__ hidden) {
    __shared__ float  cand_val[CCAP];
    __shared__ int    cand_idx[CCAP];
    __shared__ uint32 hist[256];
    __shared__ float  redS[4], redS2[4];
    __shared__ float  sh_mu, sh_sig;
    __shared__ uint32 sh_prefix, sh_need;
    __shared__ int    sh_cnt, c_clear, bcnt;
    __shared__ int    bidx_s[BCAP];
    __shared__ float  bval_s[BCAP];

    int lrow = blockIdx.x;
    int grow = row0 + lrow;
    const float* p = P + (size_t)lrow * D_DICT;
    float* hrow = hidden + (size_t)grow * D_DICT;
    int t = threadIdx.x;

    if (t == 0) sh_cnt = 0;
    float s = 0.f, s2 = 0.f;
    #pragma unroll 2
    for (int c = 0; c < 8; ++c) {
        int e4 = c * 256 + t;
        float4 v4 = ((const float4*)p)[e4];
        s  += v4.x + v4.y + v4.z + v4.w;
        s2 += v4.x*v4.x + v4.y*v4.y + v4.z*v4.z + v4.w*v4.w;
        *(float4*)&hrow[e4 * 4] = make_float4(0.f, 0.f, 0.f, 0.f);
    }
    #pragma unroll
    for (int off = 32; off; off >>= 1) {
        s  += __shfl_down(s, off);
        s2 += __shfl_down(s2, off);
    }
    if ((t & 63) == 0) { redS[t >> 6] = s; redS2[t >> 6] = s2; }
    __syncthreads();
    if (t == 0) {
        float S  = redS[0] + redS[1] + redS[2] + redS[3];
        float S2 = redS2[0] + redS2[1] + redS2[2] + redS2[3];
        float mu = S * (1.f / D_DICT);
        float var = S2 * (1.f / D_DICT) - mu * mu;
        sh_mu = mu;
        sh_sig = sqrtf(fmaxf(var, 1e-20f));
    }
    __syncthreads();
    float Tlo = sh_mu + 1.3f * sh_sig;

    #pragma unroll 2
    for (int c = 0; c < 8; ++c) {
        int e4 = c * 256 + t;
        float4 v4 = ((const float4*)p)[e4];
        float vv[4] = {v4.x, v4.y, v4.z, v4.w};
        #pragma unroll
        for (int j = 0; j < 4; ++j) {
            if (vv[j] > Tlo) {
                int slot = atomicAdd((uint32*)&sh_cnt, 1u);
                if (slot < CCAP) { cand_val[slot] = vv[j]; cand_idx[slot] = e4 * 4 + j; }
            }
        }
    }
    __syncthreads();
    int n = sh_cnt;
    bool found = (n >= TOPK && n <= CCAP);

    float vT0 = 0.f;
    for (int rtry = 0; rtry < 2; ++rtry) {
        uint32 prefix = 0, need = TOPK;
        for (int pass = 0; pass < 4; ++pass) {
            int shift = 24 - 8 * pass;
            hist[t] = 0;
            __syncthreads();
            uint32 mask_hi = pass ? (0xFFFFFFFFu << (shift + 8)) : 0u;
            if (found) {
                for (int e = t; e < n; e += 256) {
                    uint32 u = okey(cand_val[e]);
                    if ((u & mask_hi) == prefix)
                        atomicAdd(&hist[(u >> shift) & 255u], 1u);
                }
            } else {
                for (int e = t; e < D_DICT; e += 256) {
                    uint32 u = okey(p[e]);
                    if ((u & mask_hi) == prefix)
                        atomicAdd(&hist[(u >> shift) & 255u], 1u);
                }
            }
            __syncthreads();
            if (t == 0) {
                uint32 cum = 0;
                int d = 255;
                for (; d > 0; --d) {
                    uint32 h = hist[d];
                    if (cum + h >= need) break;
                    cum += h;
                }
                sh_prefix = prefix | ((uint32)d << shift);
                sh_need = need - cum;
            }
            __syncthreads();
            prefix = sh_prefix;
            need = sh_need;
            __syncthreads();
        }
        uint32 tb = (prefix & 0x80000000u) ? (prefix & 0x7FFFFFFFu) : ~prefix;
        vT0 = __uint_as_float(tb);
        if (!found) break;
        if (vT0 - BAND - 1e-3f > Tlo) break;
        found = false;
        __syncthreads();
    }

    if (t == 0) { c_clear = 0; bcnt = 0; }
    __syncthreads();
    if (found) {
        for (int e = t; e < n; e += 256) {
            float v = cand_val[e];
            int i = cand_idx[e];
            if (v > vT0 + BAND) {
                hrow[i] = fmaxf(v, 0.f);
                atomicAdd((uint32*)&c_clear, 1u);
            } else if (v >= vT0 - BAND) {
                int slot = atomicAdd((uint32*)&bcnt, 1u);
                if (slot < BCAP) bidx_s[slot] = i;
            }
        }
    } else {
        for (int e = t; e < D_DICT; e += 256) {
            float v = p[e];
            if (v > vT0 + BAND) {
                hrow[e] = fmaxf(v, 0.f);
                atomicAdd((uint32*)&c_clear, 1u);
            } else if (v >= vT0 - BAND) {
                int slot = atomicAdd((uint32*)&bcnt, 1u);
                if (slot < BCAP) bidx_s[slot] = e;
            }
        }
    }
    __syncthreads();

    int nb = bcnt < BCAP ? bcnt : BCAP;
    if (t < nb) {
        const float* xr = x + (size_t)grow * D_IN;
        const float* wr = Wenc + (size_t)bidx_s[t] * D_IN;
        float acc = 0.f;
        #pragma unroll 8
        for (int k = 0; k < D_IN; ++k)
            acc = fmaf(xr[k], wr[k], acc);
        bval_s[t] = acc + b_enc[bidx_s[t]];
    }
    __syncthreads();
    if (t == 0) {
        int take = TOPK - c_clear;
        for (int rr = 0; rr < take; ++rr) {
            int best = -1; float bv = 0.f; int bi = 0;
            for (int e = 0; e < nb; ++e) {
                int idx = bidx_s[e];
                if (idx < 0) continue;
                float v = bval_s[e];
                if (best < 0 || v > bv || (v == bv && idx < bi)) {
                    best = e; bv = v; bi = idx;
                }
            }
            if (best < 0) break;
            bidx_s[best] = -1;
            hrow[bi] = fmaxf(bv, 0.f);
        }
    }
}

__launch_bounds__(256)
__global__ void decode_direct_kernel(const float* __restrict__ hidden,
                                     const float* __restrict__ W_dec,
                                     const float* __restrict__ b_dec,
                                     float* __restrict__ recon) {
    __shared__ float  sv[TOPK];
    __shared__ int    sidx[TOPK];
    __shared__ int    offs[257];
    int row = blockIdx.x;
    int t = threadIdx.x;
    const float* hrow = hidden + (size_t)row * D_DICT;

    int base = t * 32;
    int c = 0;
    for (int j = 0; j < 32; ++j) c += (hrow[base + j] > 0.f) ? 1 : 0;
    offs[t + 1] = c;
    __syncthreads();
    if (t == 0) {
        offs[0] = 0;
        for (int i = 0; i < 256; ++i) offs[i + 1] += offs[i];
    }
    __syncthreads();
    int o = offs[t];
    for (int j = 0; j < 32; ++j) {
        float v = hrow[base + j];
        if (v > 0.f) { sv[o] = v; sidx[o] = base + j; ++o; }
    }
    __syncthreads();
    int total = offs[256];

    int d0 = 2 * t;
    float acc0 = b_dec[d0];
    float acc1 = b_dec[d0 + 1];
    for (int k = 0; k < total; ++k) {
        float v = sv[k];
        int idx = sidx[k];
        acc0 = fmaf(v, W_dec[(size_t)d0 * D_DICT + idx], acc0);
        acc1 = fmaf(v, W_dec[(size_t)(d0 + 1) * D_DICT + idx], acc1);
    }
    *(float2*)&recon[(size_t)row * D_IN + d0] = make_float2(acc0, acc1);
}

// ---------------------------------------------------------------------------
extern "C" void kernel_launch(void* const* d_in, const int* in_sizes, int n_in,
                              void* d_out, int out_size, void* d_ws, size_t ws_size,
                              hipStream_t stream) {
    const float* x     = (const float*)d_in[0];
    const float* W_enc = (const float*)d_in[1];
    const float* b_enc = (const float*)d_in[2];
    const float* W_dec = (const float*)d_in[3];
    const float* b_dec = (const float*)d_in[4];

    float* out    = (float*)d_out;
    float* recon  = out;                          // 16384*512 fp32
    float* hidden = out + (size_t)N_ROWS * D_IN;  // 16384*8192 fp32

    const size_t CNT_BYTES  = (size_t)N_ROWS * sizeof(uint32);                   // 64 KiB
    const size_t FLG_BYTES  = (size_t)N_ROWS * sizeof(uint32);                   // 64 KiB
    const size_t WB_BYTES   = (size_t)D_IN * D_DICT * sizeof(unsigned short);    // 8 MiB
    const size_t WS_BYTES   = (size_t)D_DICT * 16 * 64 * sizeof(unsigned short); // 16 MiB
    const size_t XS_BYTES   = (size_t)N_ROWS * 16 * 64 * sizeof(unsigned short); // 32 MiB
    const size_t CAND_BYTES = (size_t)N_ROWS * CAND_CAP * sizeof(uint2);         // 256 MiB
    const size_t FIXED_B    = CNT_BYTES + FLG_BYTES + WB_BYTES + WS_BYTES + XS_BYTES + CAND_BYTES;
    const size_t ROW_BYTES  = (size_t)D_DICT * sizeof(float);

    char* ws = (char*)d_ws;

    if (ws_size >= FIXED_B) {
        // Tier B: candidate-push MFMA encode + select/repair + MFMA decode
        uint32*         CandCnt = (uint32*)ws;
        uint32*         flags   = (uint32*)(ws + CNT_BYTES);
        unsigned short* Wb      = (unsigned short*)(ws + CNT_BYTES + FLG_BYTES);
        unsigned short* Wsp     = (unsigned short*)(ws + CNT_BYTES + FLG_BYTES + WB_BYTES);
        unsigned short* Xsp     = (unsigned short*)(ws + CNT_BYTES + FLG_BYTES + WB_BYTES + WS_BYTES);
        uint2*          Cand    = (uint2*)(ws + CNT_BYTES + FLG_BYTES + WB_BYTES + WS_BYTES + XS_BYTES);

        hipMemsetAsync(CandCnt, 0, CNT_BYTES + FLG_BYTES, stream);
        cast_wdec_kernel<<<(D_IN * D_DICT) / 1024, 256, 0, stream>>>(W_dec, Wb);
        split_hilo_kernel<<<(D_DICT * 16) / 256, 256, 0, stream>>>(W_enc, Wsp);
        split_hilo_kernel<<<(N_ROWS * 16) / 256, 256, 0, stream>>>(x, Xsp);

        encode_mfma_cand<<<dim3(N_ROWS / 256, D_DICT / 256), 512, 0, stream>>>(
            Xsp, Wsp, b_enc, Cand, CandCnt);
        select_kernel<<<N_ROWS, 256, 0, stream>>>(Cand, CandCnt, x, W_enc, b_enc, hidden, flags);
        repair_kernel<<<N_ROWS, 256, 0, stream>>>(flags, x, W_enc, b_enc, hidden);

        mfma_decode_kernel<<<(N_ROWS / 256) * 2, 512, 0, stream>>>(hidden, Wb, b_dec, recon);
    } else {
        // Tier C: exact fp32 encode + two-pass topk + gather decode (tiny ws)
        float* pre = (float*)ws;
        long long cl = (long long)(ws_size / ROW_BYTES);
        int chunk;
        if (cl >= 128) { chunk = (cl > 2048) ? 2048 : (int)cl; chunk &= ~127; }
        else chunk = (cl < 1) ? 1 : (int)cl;

        for (int r0 = 0; r0 < N_ROWS; r0 += chunk) {
            int nr = (N_ROWS - r0 < chunk) ? (N_ROWS - r0) : chunk;
            dim3 grid((nr + 127) / 128, D_DICT / 128);
            encode_gemm_kernel<<<grid, 256, 0, stream>>>(x, W_enc, b_enc, pre, r0, nr);
            topk_band_kernel<<<nr, 256, 0, stream>>>(pre, r0, x, W_enc, b_enc, hidden);
        }
        decode_direct_kernel<<<N_ROWS, 256, 0, stream>>>(hidden, W_dec, b_dec, recon);
    }
}

// Round 13
// 1415.645 us; speedup vs baseline: 1.3279x; 1.0298x over previous
//
#include <hip/hip_runtime.h>

typedef unsigned int uint32;
typedef __attribute__((ext_vector_type(4))) float  f32x4;
typedef __attribute__((ext_vector_type(8))) short  bf16x8;
typedef __attribute__((ext_vector_type(4))) unsigned short us4;
typedef __attribute__((ext_vector_type(8))) unsigned short us8;

#define N_ROWS   16384
#define D_IN     512
#define D_DICT   8192
#define TOPK     256
#define BAND     2e-3f
#define BCAP     64
#define CCAP     2048
#define CAND_CAP 2048
#define TFIX     1.38f

__device__ __forceinline__ unsigned short f2bf_rne(float f) {
    unsigned u = __float_as_uint(f);
    unsigned r = u + 0x7FFFu + ((u >> 16) & 1u);
    return (unsigned short)(r >> 16);
}
__device__ __forceinline__ float bf2f(unsigned short h) {
    return __uint_as_float(((unsigned)h) << 16);
}
__device__ __forceinline__ uint32 okey(float v) {
    uint32 u = __float_as_uint(v);
    return (u & 0x80000000u) ? ~u : (u | 0x80000000u);
}
// XOR-swizzled LDS element address (validated r5-r12)
__device__ __forceinline__ int swz(int row, int k) {
    return row * 64 + (k ^ ((row & 7) << 3));
}
// async global->LDS, 16B per lane; LDS dest must be uniform-base + lane*16
__device__ __forceinline__ void gll16(const unsigned short* g, unsigned short* l) {
    __builtin_amdgcn_global_load_lds(
        (const __attribute__((address_space(1))) unsigned int*)g,
        (__attribute__((address_space(3))) unsigned int*)l, 16, 0, 0);
}

// ---------------------------------------------------------------------------
// Kernel 0a: cast W_dec [512][8192] fp32 -> bf16 with the per-row LDS XOR
// swizzle PRE-BAKED (within each 64-elem k-chunk, 8-elem group g -> g^(d&7)),
// so decode can stage it with linear global_load_lds and read via swz().
// ---------------------------------------------------------------------------
__launch_bounds__(256)
__global__ void cast_wdec_swz_kernel(const float* __restrict__ W,
                                     unsigned short* __restrict__ Wb) {
    int idx = blockIdx.x * 256 + threadIdx.x;   // us8-group id
    int d = idx >> 10;            // 1024 groups per d-row
    int g = idx & 1023;
    const float* src = W + (size_t)d * D_DICT + g * 8;
    us8 o;
    #pragma unroll
    for (int j = 0; j < 8; ++j) o[j] = f2bf_rne(src[j]);
    int gout = (g & ~7) | ((g ^ d) & 7);
    *(us8*)&Wb[(size_t)d * D_DICT + gout * 8] = o;
}

// ---------------------------------------------------------------------------
// Kernel 0b: pre-split [nrows][512] fp32 -> [nrows][16][64] bf16 hi|lo with
// per-row XOR swizzle baked in (validated r10-r12).
// ---------------------------------------------------------------------------
__launch_bounds__(256)
__global__ void split_hilo_kernel(const float* __restrict__ W,
                                  unsigned short* __restrict__ S) {
    int idx = blockIdx.x * 256 + threadIdx.x;
    int row = idx >> 4;
    int c   = idx & 15;
    const float* src = W + (size_t)row * D_IN + c * 32;
    unsigned short hi[32], lo[32];
    #pragma unroll
    for (int j = 0; j < 32; ++j) {
        float v = src[j];
        unsigned short h = f2bf_rne(v);
        hi[j] = h; lo[j] = f2bf_rne(v - bf2f(h));
    }
    int m = row & 7;
    unsigned short* dst = S + ((size_t)row * 16 + c) * 64;
    #pragma unroll
    for (int g = 0; g < 8; ++g) {
        int lg = g ^ m;
        us8 o;
        #pragma unroll
        for (int j = 0; j < 8; ++j)
            o[j] = (lg < 4) ? hi[lg * 8 + j] : lo[(lg - 4) * 8 + j];
        *(us8*)&dst[g * 8] = o;
    }
}

// ---------------------------------------------------------------------------
// Kernel 1 (v3): MFMA encode + candidate push. 128x128 tile, 256 thr (4 waves
// 2Mx2N, per-wave 64x64 -> acc 64 AGPR: 3-4 waves/SIMD vs r12's 2), staging
// via global_load_lds (LDS dest = uniform + lane*16 by construction).
// MFMA count/order per output element identical to r12 -> same Cand values.
// ---------------------------------------------------------------------------
__launch_bounds__(256)
__global__ void encode_mfma_cand(const unsigned short* __restrict__ Xs,
                                 const unsigned short* __restrict__ Ws,
                                 const float* __restrict__ b_enc,
                                 uint2* __restrict__ Cand,
                                 uint32* __restrict__ CandCnt) {
    __shared__ unsigned short At[128 * 64];   // 16KB
    __shared__ unsigned short Bt[128 * 64];   // 16KB

    int tid  = threadIdx.x;
    int lane = tid & 63;
    int wid  = tid >> 6;          // 0..3
    int wm   = wid >> 1;          // 0..1
    int wn   = wid & 1;           // 0..1
    int bn   = blockIdx.x * 128;  // dict cols (x fast: consecutive blocks share bm)
    int bm   = blockIdx.y * 128;  // rows
    int fr   = lane & 15;
    int fk   = (lane >> 4) << 3;

    f32x4 acc[4][4];
    #pragma unroll
    for (int i = 0; i < 4; ++i)
        #pragma unroll
        for (int j = 0; j < 4; ++j) acc[i][j] = (f32x4)0.f;

    for (int c = 0; c < 16; ++c) {
        #pragma unroll
        for (int q = 0; q < 4; ++q) {
            int s = q * 256 + tid;
            int row = s >> 3;
            int b8  = (s & 7) * 8;
            gll16(&Xs[((size_t)(bm + row) * 16 + c) * 64 + b8], &At[row * 64 + b8]);
            gll16(&Ws[((size_t)(bn + row) * 16 + c) * 64 + b8], &Bt[row * 64 + b8]);
        }
        __syncthreads();

        bf16x8 bh[4], bl[4];
        #pragma unroll
        for (int nj = 0; nj < 4; ++nj) {
            bh[nj] = *(const bf16x8*)&Bt[swz(wn * 64 + nj * 16 + fr, fk)];
            bl[nj] = *(const bf16x8*)&Bt[swz(wn * 64 + nj * 16 + fr, 32 + fk)];
        }
        #pragma unroll
        for (int mi = 0; mi < 4; ++mi) {
            bf16x8 ah = *(const bf16x8*)&At[swz(wm * 64 + mi * 16 + fr, fk)];
            bf16x8 al = *(const bf16x8*)&At[swz(wm * 64 + mi * 16 + fr, 32 + fk)];
            #pragma unroll
            for (int nj = 0; nj < 4; ++nj) {
                acc[mi][nj] = __builtin_amdgcn_mfma_f32_16x16x32_bf16(ah, bh[nj], acc[mi][nj], 0, 0, 0);
                acc[mi][nj] = __builtin_amdgcn_mfma_f32_16x16x32_bf16(ah, bl[nj], acc[mi][nj], 0, 0, 0);
                acc[mi][nj] = __builtin_amdgcn_mfma_f32_16x16x32_bf16(al, bh[nj], acc[mi][nj], 0, 0, 0);
            }
        }
        __syncthreads();
    }

    float bcol[4];
    #pragma unroll
    for (int nj = 0; nj < 4; ++nj)
        bcol[nj] = b_enc[bn + wn * 64 + nj * 16 + fr];

    #pragma unroll
    for (int mi = 0; mi < 4; ++mi) {
        int rbase = bm + wm * 64 + mi * 16 + (lane >> 4) * 4;
        #pragma unroll
        for (int reg = 0; reg < 4; ++reg) {
            int r = rbase + reg;
            float v[4]; int pr[4]; int cc = 0;
            #pragma unroll
            for (int nj = 0; nj < 4; ++nj) {
                v[nj] = acc[mi][nj][reg] + bcol[nj];
                pr[nj] = (v[nj] > TFIX) ? 1 : 0;
                cc += pr[nj];
            }
            int incl = cc;
            #pragma unroll
            for (int d = 1; d < 16; d <<= 1) {
                int tv = __shfl_up(incl, d, 16);
                if (fr >= d) incl += tv;
            }
            int total = __shfl(incl, 15, 16);
            if (total > 0) {
                int base = 0;
                if (fr == 0) base = (int)atomicAdd(&CandCnt[r], (uint32)total);
                base = __shfl(base, 0, 16);
                int slot = base + (incl - cc);
                #pragma unroll
                for (int nj = 0; nj < 4; ++nj) {
                    if (pr[nj]) {
                        if (slot < CAND_CAP)
                            Cand[(size_t)r * CAND_CAP + slot] =
                                make_uint2(__float_as_uint(v[nj]),
                                           (uint32)(bn + wn * 64 + nj * 16 + fr));
                        ++slot;
                    }
                }
            }
        }
    }
}

// ---------------------------------------------------------------------------
// Kernel 2: select (validated r12: streaming zero-fill + direct scatter).
// ---------------------------------------------------------------------------
__launch_bounds__(256)
__global__ void select_kernel(const uint2* __restrict__ Cand,
                              const uint32* __restrict__ CandCnt,
                              const float* __restrict__ x,
                              const float* __restrict__ Wenc,
                              const float* __restrict__ b_enc,
                              float* __restrict__ hidden,
                              uint32* __restrict__ flags) {
    __shared__ float  cand_val[CAND_CAP];
    __shared__ int    cand_idx[CAND_CAP];
    __shared__ uint32 hist[256];
    __shared__ uint32 sh_prefix, sh_need;
    __shared__ int    c_clear, bcnt;
    __shared__ int    bidx_s[BCAP];
    __shared__ float  bval_s[BCAP];

    int row = blockIdx.x;
    int t = threadIdx.x;
    float* hrow = hidden + (size_t)row * D_DICT;

    int n = (int)CandCnt[row];
    bool ok = (n >= TOPK && n <= CAND_CAP);

    #pragma unroll
    for (int c = 0; c < 8; ++c)
        *(float4*)&hrow[(c * 256 + t) * 4] = make_float4(0.f, 0.f, 0.f, 0.f);
    if (ok) {
        for (int e = t; e < n; e += 256) {
            uint2 cv = Cand[(size_t)row * CAND_CAP + e];
            cand_val[e] = __uint_as_float(cv.x);
            cand_idx[e] = (int)cv.y;
        }
    }
    __syncthreads();

    float vT0 = 0.f;
    if (ok) {
        uint32 prefix = 0, need = TOPK;
        for (int pass = 0; pass < 4; ++pass) {
            int shift = 24 - 8 * pass;
            hist[t] = 0;
            __syncthreads();
            uint32 mask_hi = pass ? (0xFFFFFFFFu << (shift + 8)) : 0u;
            for (int e = t; e < n; e += 256) {
                uint32 u = okey(cand_val[e]);
                if ((u & mask_hi) == prefix)
                    atomicAdd(&hist[(u >> shift) & 255u], 1u);
            }
            __syncthreads();
            if (t == 0) {
                uint32 cum = 0;
                int d = 255;
                for (; d > 0; --d) {
                    uint32 h = hist[d];
                    if (cum + h >= need) break;
                    cum += h;
                }
                sh_prefix = prefix | ((uint32)d << shift);
                sh_need = need - cum;
            }
            __syncthreads();
            prefix = sh_prefix;
            need = sh_need;
            __syncthreads();
        }
        uint32 tb = (prefix & 0x80000000u) ? (prefix & 0x7FFFFFFFu) : ~prefix;
        vT0 = __uint_as_float(tb);
        if (!(vT0 - BAND - 1e-3f > TFIX)) ok = false;
    }

    if (!ok) {
        if (t == 0) flags[row] = 1u;
        return;
    }

    if (t == 0) { c_clear = 0; bcnt = 0; }
    __syncthreads();
    for (int e = t; e < n; e += 256) {
        float v = cand_val[e];
        int i = cand_idx[e];
        if (v > vT0 + BAND) {
            hrow[i] = fmaxf(v, 0.f);
            atomicAdd((uint32*)&c_clear, 1u);
        } else if (v >= vT0 - BAND) {
            int slot = atomicAdd((uint32*)&bcnt, 1u);
            if (slot < BCAP) bidx_s[slot] = i;
        }
    }
    __syncthreads();

    int nb = bcnt < BCAP ? bcnt : BCAP;
    if (t < nb) {
        const float* xr = x + (size_t)row * D_IN;
        const float* wr = Wenc + (size_t)bidx_s[t] * D_IN;
        float acc = 0.f;
        #pragma unroll 8
        for (int k = 0; k < D_IN; ++k)   // ascending k — np rounding class
            acc = fmaf(xr[k], wr[k], acc);
        bval_s[t] = acc + b_enc[bidx_s[t]];
    }
    __syncthreads();
    if (t == 0) {
        int take = TOPK - c_clear;
        for (int rr = 0; rr < take; ++rr) {
            int best = -1; float bv = 0.f; int bi = 0;
            for (int e = 0; e < nb; ++e) {
                int idx = bidx_s[e];
                if (idx < 0) continue;
                float v = bval_s[e];
                if (best < 0 || v > bv || (v == bv && idx < bi)) {
                    best = e; bv = v; bi = idx;
                }
            }
            if (best < 0) break;
            bidx_s[best] = -1;
            hrow[bi] = fmaxf(bv, 0.f);
        }
    }
}

// ---------------------------------------------------------------------------
// Kernel 2b: exact repair for flagged rows (validated r11/r12).
// ---------------------------------------------------------------------------
__launch_bounds__(256)
__global__ void repair_kernel(const uint32* __restrict__ flags,
                              const float* __restrict__ x,
                              const float* __restrict__ Wenc,
                              const float* __restrict__ b_enc,
                              float* __restrict__ hidden) {
    int row = blockIdx.x;
    if (flags[row] == 0u) return;
    __shared__ float  vals[D_DICT];
    __shared__ float  xs[D_IN];
    __shared__ uint32 hist[256];
    __shared__ uint32 pscan[257];
    __shared__ uint32 cnt_eq[256];
    __shared__ uint32 sh_prefix, sh_need;
    int t = threadIdx.x;

    for (int c = t; c < D_IN; c += 256) xs[c] = x[(size_t)row * D_IN + c];
    __syncthreads();
    for (int e = t; e < D_DICT; e += 256) {
        const float* wr = Wenc + (size_t)e * D_IN;
        float acc = 0.f;
        #pragma unroll 8
        for (int k = 0; k < D_IN; ++k)
            acc = fmaf(xs[k], wr[k], acc);
        vals[e] = acc + b_enc[e];
    }
    __syncthreads();

    uint32 prefix = 0, need = TOPK;
    for (int pass = 0; pass < 4; ++pass) {
        int shift = 24 - 8 * pass;
        hist[t] = 0;
        __syncthreads();
        uint32 mask_hi = pass ? (0xFFFFFFFFu << (shift + 8)) : 0u;
        #pragma unroll 4
        for (int c = 0; c < 32; ++c) {
            uint32 u = okey(vals[c * 256 + t]);
            if ((u & mask_hi) == prefix)
                atomicAdd(&hist[(u >> shift) & 255u], 1u);
        }
        __syncthreads();
        if (t == 0) {
            uint32 cum = 0;
            int d = 255;
            for (; d > 0; --d) {
                uint32 h = hist[d];
                if (cum + h >= need) break;
                cum += h;
            }
            sh_prefix = prefix | ((uint32)d << shift);
            sh_need = need - cum;
        }
        __syncthreads();
        prefix = sh_prefix;
        need = sh_need;
        __syncthreads();
    }
    uint32 T = prefix;
    uint32 r = need;
    float* hrow = hidden + (size_t)row * D_DICT;

    #pragma unroll 2
    for (int c = 0; c < 32; ++c) {
        int i = c * 256 + t;
        uint32 u = okey(vals[i]);
        hrow[i] = (u > T) ? fmaxf(vals[i], 0.f) : 0.f;
    }
    __syncthreads();

    int base = t * 32;
    uint32 local = 0;
    for (int j = 0; j < 32; ++j) local += (okey(vals[base + j]) == T) ? 1u : 0u;
    cnt_eq[t] = local;
    __syncthreads();
    if (t == 0) {
        uint32 s = 0;
        for (int i = 0; i < 256; ++i) { pscan[i] = s; s += cnt_eq[i]; }
    }
    __syncthreads();
    uint32 myoff = pscan[t];
    if (local > 0 && myoff < r) {
        uint32 tb = (T & 0x80000000u) ? (T & 0x7FFFFFFFu) : ~T;
        float hv = fmaxf(__uint_as_float(tb), 0.f);
        uint32 rank = myoff;
        for (int j = 0; j < 32 && rank < r; ++j) {
            int i = base + j;
            if (okey(vals[i]) == T) { hrow[i] = hv; rank++; }
        }
    }
}

// ---------------------------------------------------------------------------
// Kernel 3 (v2): MFMA decode, 64x512 tile, 8 waves 1Mx8N (per-wave 64x64,
// acc 64 AGPR -> 4 waves/SIMD), hidden read ONCE (full 512 cols per block),
// B staged via global_load_lds from pre-swizzled Wb. Same MFMA shape and
// ascending-k order as r12 -> recon numerics unchanged.
// ---------------------------------------------------------------------------
__launch_bounds__(512)
__global__ void mfma_decode_kernel(const float* __restrict__ hidden,
                                   const unsigned short* __restrict__ Wb, // pre-swizzled
                                   const float* __restrict__ b_dec,
                                   float* __restrict__ recon) {
    __shared__ unsigned short At[64 * 64];    // 8KB
    __shared__ unsigned short Bt[512 * 64];   // 64KB

    int tid  = threadIdx.x;
    int lane = tid & 63;
    int wn   = tid >> 6;          // 0..7 -> cols wn*64..+64
    int bm   = blockIdx.x * 64;
    int fr   = lane & 15;

    f32x4 acc[4][4];
    #pragma unroll
    for (int i = 0; i < 4; ++i)
        #pragma unroll
        for (int j = 0; j < 4; ++j) acc[i][j] = (f32x4)0.f;

    for (int k0 = 0; k0 < D_DICT; k0 += 64) {
        // stage A: 64 rows x 64 k, fp32 -> bf16, swz write (reg-staged)
        #pragma unroll
        for (int i = 0; i < 2; ++i) {
            int idx = i * 512 + tid;
            int row = idx >> 4;
            int kq  = (idx & 15) * 4;
            float4 h4 = *(const float4*)&hidden[(size_t)(bm + row) * D_DICT + k0 + kq];
            us4 o;
            o.x = f2bf_rne(h4.x); o.y = f2bf_rne(h4.y);
            o.z = f2bf_rne(h4.z); o.w = f2bf_rne(h4.w);
            *(us4*)&At[swz(row, kq)] = o;
        }
        // stage B: 512 d-rows x 64 k via global_load_lds (pre-swizzled Wb)
        #pragma unroll
        for (int q = 0; q < 8; ++q) {
            int s = q * 512 + tid;
            int row = s >> 3;
            int b8  = (s & 7) * 8;
            gll16(&Wb[(size_t)row * D_DICT + k0 + b8], &Bt[row * 64 + b8]);
        }
        __syncthreads();

        #pragma unroll
        for (int ks = 0; ks < 2; ++ks) {
            int kb = ks * 32 + (lane >> 4) * 8;
            bf16x8 av[4], bv[4];
            #pragma unroll
            for (int mi = 0; mi < 4; ++mi)
                av[mi] = *(const bf16x8*)&At[swz(mi * 16 + fr, kb)];
            #pragma unroll
            for (int nj = 0; nj < 4; ++nj)
                bv[nj] = *(const bf16x8*)&Bt[swz(wn * 64 + nj * 16 + fr, kb)];
            #pragma unroll
            for (int mi = 0; mi < 4; ++mi)
                #pragma unroll
                for (int nj = 0; nj < 4; ++nj)
                    acc[mi][nj] = __builtin_amdgcn_mfma_f32_16x16x32_bf16(
                        av[mi], bv[nj], acc[mi][nj], 0, 0, 0);
        }
        __syncthreads();
    }

    #pragma unroll
    for (int mi = 0; mi < 4; ++mi) {
        int r0 = bm + mi * 16 + (lane >> 4) * 4;
        #pragma unroll
        for (int nj = 0; nj < 4; ++nj) {
            int col = wn * 64 + nj * 16 + fr;
            float bd = b_dec[col];
            #pragma unroll
            for (int reg = 0; reg < 4; ++reg)
                recon[(size_t)(r0 + reg) * D_IN + col] = acc[mi][nj][reg] + bd;
        }
    }
}

// ---------------------------------------------------------------------------
// Tier C fallback kernels (validated r10-r12)
// ---------------------------------------------------------------------------
#define EBK 8
#define ESTR 132

__launch_bounds__(256)
__global__ void encode_gemm_kernel(const float* __restrict__ X,
                                   const float* __restrict__ Wenc,
                                   const float* __restrict__ b_enc,
                                   float* __restrict__ P,
                                   int row0, int nrows) {
    __shared__ float As[EBK][ESTR];
    __shared__ float Bs[EBK][ESTR];
    int tid = threadIdx.x;
    int tx = tid & 15;
    int ty = tid >> 4;
    int bm = blockIdx.x * 128;
    int bn = blockIdx.y * 128;
    int srow = tid >> 1;
    int skq  = (tid & 1) * 4;

    float acc[8][8];
    #pragma unroll
    for (int i = 0; i < 8; ++i)
        #pragma unroll
        for (int j = 0; j < 8; ++j) acc[i][j] = 0.f;

    for (int k0 = 0; k0 < D_IN; k0 += EBK) {
        float4 a4 = make_float4(0.f, 0.f, 0.f, 0.f);
        if (bm + srow < nrows)
            a4 = *(const float4*)&X[(size_t)(row0 + bm + srow) * D_IN + k0 + skq];
        float4 b4 = *(const float4*)&Wenc[(size_t)(bn + srow) * D_IN + k0 + skq];
        As[skq + 0][srow] = a4.x; As[skq + 1][srow] = a4.y;
        As[skq + 2][srow] = a4.z; As[skq + 3][srow] = a4.w;
        Bs[skq + 0][srow] = b4.x; Bs[skq + 1][srow] = b4.y;
        Bs[skq + 2][srow] = b4.z; Bs[skq + 3][srow] = b4.w;
        __syncthreads();
        #pragma unroll
        for (int k = 0; k < EBK; ++k) {
            float4 a0 = *(const float4*)&As[k][ty * 4];
            float4 a1 = *(const float4*)&As[k][64 + ty * 4];
            float4 b0 = *(const float4*)&Bs[k][tx * 4];
            float4 b1 = *(const float4*)&Bs[k][64 + tx * 4];
            float a[8] = {a0.x, a0.y, a0.z, a0.w, a1.x, a1.y, a1.z, a1.w};
            float b[8] = {b0.x, b0.y, b0.z, b0.w, b1.x, b1.y, b1.z, b1.w};
            #pragma unroll
            for (int i = 0; i < 8; ++i)
                #pragma unroll
                for (int j = 0; j < 8; ++j)
                    acc[i][j] = fmaf(a[i], b[j], acc[i][j]);
        }
        __syncthreads();
    }

    float4 bias0 = *(const float4*)&b_enc[bn + tx * 4];
    float4 bias1 = *(const float4*)&b_enc[bn + 64 + tx * 4];
    float bb[8] = {bias0.x, bias0.y, bias0.z, bias0.w,
                   bias1.x, bias1.y, bias1.z, bias1.w};
    #pragma unroll
    for (int i = 0; i < 8; ++i) {
        int r = bm + (i < 4 ? ty * 4 + i : 64 + ty * 4 + (i - 4));
        if (r < nrows) {
            float4 o0, o1;
            o0.x = acc[i][0] + bb[0]; o0.y = acc[i][1] + bb[1];
            o0.z = acc[i][2] + bb[2]; o0.w = acc[i][3] + bb[3];
            o1.x = acc[i][4] + bb[4]; o1.y = acc[i][5] + bb[5];
            o1.z = acc[i][6] + bb[6]; o1.w = acc[i][7] + bb[7];
            *(float4*)&P[(size_t)r * D_DICT + bn + tx * 4] = o0;
            *(float4*)&P[(size_t)r * D_DICT + bn + 64 + tx * 4] = o1;
        }
    }
}

__launch_bounds__(256)
__global__ void topk_band_kernel(const float* __restrict__ P,
                                 int row0,
                                 const float* __restrict__ x,
                                 const float* __restrict__ Wenc,
                                 const float* __restrict__ b_enc,
                                 float* __restrict__ hidden) {
    __shared__ float  cand_val[CCAP];
    __shared__ int    cand_idx[CCAP];
    __shared__ uint32 hist[256];
    __shared__ float  redS[4], redS2[4];
    __shared__ float  sh_mu, sh_sig;
    __shared__ uint32 sh_prefix, sh_need;
    __shared__ int    sh_cnt, c_clear, bcnt;
    __shared__ int    bidx_s[BCAP];
    __shared__ float  bval_s[BCAP];

    int lrow = blockIdx.x;
    int grow = row0 + lrow;
    const float* p = P + (size_t)lrow * D_DICT;
    float* hrow = hidden + (size_t)grow * D_DICT;
    int t = threadIdx.x;

    if (t == 0) sh_cnt = 0;
    float s = 0.f, s2 = 0.f;
    #pragma unroll 2
    for (int c = 0; c < 8; ++c) {
        int e4 = c * 256 + t;
        float4 v4 = ((const float4*)p)[e4];
        s  += v4.x + v4.y + v4.z + v4.w;
        s2 += v4.x*v4.x + v4.y*v4.y + v4.z*v4.z + v4.w*v4.w;
        *(float4*)&hrow[e4 * 4] = make_float4(0.f, 0.f, 0.f, 0.f);
    }
    #pragma unroll
    for (int off = 32; off; off >>= 1) {
        s  += __shfl_down(s, off);
        s2 += __shfl_down(s2, off);
    }
    if ((t & 63) == 0) { redS[t >> 6] = s; redS2[t >> 6] = s2; }
    __syncthreads();
    if (t == 0) {
        float S  = redS[0] + redS[1] + redS[2] + redS[3];
        float S2 = redS2[0] + redS2[1] + redS2[2] + redS2[3];
        float mu = S * (1.f / D_DICT);
        float var = S2 * (1.f / D_DICT) - mu * mu;
        sh_mu = mu;
        sh_sig = sqrtf(fmaxf(var, 1e-20f));
    }
    __syncthreads();
    float Tlo = sh_mu + 1.3f * sh_sig;

    #pragma unroll 2
    for (int c = 0; c < 8; ++c) {
        int e4 = c * 256 + t;
        float4 v4 = ((const float4*)p)[e4];
        float vv[4] = {v4.x, v4.y, v4.z, v4.w};
        #pragma unroll
        for (int j = 0; j < 4; ++j) {
            if (vv[j] > Tlo) {
                int slot = atomicAdd((uint32*)&sh_cnt, 1u);
                if (slot < CCAP) { cand_val[slot] = vv[j]; cand_idx[slot] = e4 * 4 + j; }
            }
        }
    }
    __syncthreads();
    int n = sh_cnt;
    bool found = (n >= TOPK && n <= CCAP);

    float vT0 = 0.f;
    for (int rtry = 0; rtry < 2; ++rtry) {
        uint32 prefix = 0, need = TOPK;
        for (int pass = 0; pass < 4; ++pass) {
            int shift = 24 - 8 * pass;
            hist[t] = 0;
            __syncthreads();
            uint32 mask_hi = pass ? (0xFFFFFFFFu << (shift + 8)) : 0u;
            if (found) {
                for (int e = t; e < n; e += 256) {
                    uint32 u = okey(cand_val[e]);
                    if ((u & mask_hi) == prefix)
                        atomicAdd(&hist[(u >> shift) & 255u], 1u);
                }
            } else {
                for (int e = t; e < D_DICT; e += 256) {
                    uint32 u = okey(p[e]);
                    if ((u & mask_hi) == prefix)
                        atomicAdd(&hist[(u >> shift) & 255u], 1u);
                }
            }
            __syncthreads();
            if (t == 0) {
                uint32 cum = 0;
                int d = 255;
                for (; d > 0; --d) {
                    uint32 h = hist[d];
                    if (cum + h >= need) break;
                    cum += h;
                }
                sh_prefix = prefix | ((uint32)d << shift);
                sh_need = need - cum;
            }
            __syncthreads();
            prefix = sh_prefix;
            need = sh_need;
            __syncthreads();
        }
        uint32 tb = (prefix & 0x80000000u) ? (prefix & 0x7FFFFFFFu) : ~prefix;
        vT0 = __uint_as_float(tb);
        if (!found) break;
        if (vT0 - BAND - 1e-3f > Tlo) break;
        found = false;
        __syncthreads();
    }

    if (t == 0) { c_clear = 0; bcnt = 0; }
    __syncthreads();
    if (found) {
        for (int e = t; e < n; e += 256) {
            float v = cand_val[e];
            int i = cand_idx[e];
            if (v > vT0 + BAND) {
                hrow[i] = fmaxf(v, 0.f);
                atomicAdd((uint32*)&c_clear, 1u);
            } else if (v >= vT0 - BAND) {
                int slot = atomicAdd((uint32*)&bcnt, 1u);
                if (slot < BCAP) bidx_s[slot] = i;
            }
        }
    } else {
        for (int e = t; e < D_DICT; e += 256) {
            float v = p[e];
            if (v > vT0 + BAND) {
                hrow[e] = fmaxf(v, 0.f);
                atomicAdd((uint32*)&c_clear, 1u);
            } else if (v >= vT0 - BAND) {
                int slot = atomicAdd((uint32*)&bcnt, 1u);
                if (slot < BCAP) bidx_s[slot] = e;
            }
        }
    }
    __syncthreads();

    int nb = bcnt < BCAP ? bcnt : BCAP;
    if (t < nb) {
        const float* xr = x + (size_t)grow * D_IN;
        const float* wr = Wenc + (size_t)bidx_s[t] * D_IN;
        float acc = 0.f;
        #pragma unroll 8
        for (int k = 0; k < D_IN; ++k)
            acc = fmaf(xr[k], wr[k], acc);
        bval_s[t] = acc + b_enc[bidx_s[t]];
    }
    __syncthreads();
    if (t == 0) {
        int take = TOPK - c_clear;
        for (int rr = 0; rr < take; ++rr) {
            int best = -1; float bv = 0.f; int bi = 0;
            for (int e = 0; e < nb; ++e) {
                int idx = bidx_s[e];
                if (idx < 0) continue;
                float v = bval_s[e];
                if (best < 0 || v > bv || (v == bv && idx < bi)) {
                    best = e; bv = v; bi = idx;
                }
            }
            if (best < 0) break;
            bidx_s[best] = -1;
            hrow[bi] = fmaxf(bv, 0.f);
        }
    }
}

__launch_bounds__(256)
__global__ void decode_direct_kernel(const float* __restrict__ hidden,
                                     const float* __restrict__ W_dec,
                                     const float* __restrict__ b_dec,
                                     float* __restrict__ recon) {
    __shared__ float  sv[TOPK];
    __shared__ int    sidx[TOPK];
    __shared__ int    offs[257];
    int row = blockIdx.x;
    int t = threadIdx.x;
    const float* hrow = hidden + (size_t)row * D_DICT;

    int base = t * 32;
    int c = 0;
    for (int j = 0; j < 32; ++j) c += (hrow[base + j] > 0.f) ? 1 : 0;
    offs[t + 1] = c;
    __syncthreads();
    if (t == 0) {
        offs[0] = 0;
        for (int i = 0; i < 256; ++i) offs[i + 1] += offs[i];
    }
    __syncthreads();
    int o = offs[t];
    for (int j = 0; j < 32; ++j) {
        float v = hrow[base + j];
        if (v > 0.f) { sv[o] = v; sidx[o] = base + j; ++o; }
    }
    __syncthreads();
    int total = offs[256];

    int d0 = 2 * t;
    float acc0 = b_dec[d0];
    float acc1 = b_dec[d0 + 1];
    for (int k = 0; k < total; ++k) {
        float v = sv[k];
        int idx = sidx[k];
        acc0 = fmaf(v, W_dec[(size_t)d0 * D_DICT + idx], acc0);
        acc1 = fmaf(v, W_dec[(size_t)(d0 + 1) * D_DICT + idx], acc1);
    }
    *(float2*)&recon[(size_t)row * D_IN + d0] = make_float2(acc0, acc1);
}

// ---------------------------------------------------------------------------
extern "C" void kernel_launch(void* const* d_in, const int* in_sizes, int n_in,
                              void* d_out, int out_size, void* d_ws, size_t ws_size,
                              hipStream_t stream) {
    const float* x     = (const float*)d_in[0];
    const float* W_enc = (const float*)d_in[1];
    const float* b_enc = (const float*)d_in[2];
    const float* W_dec = (const float*)d_in[3];
    const float* b_dec = (const float*)d_in[4];

    float* out    = (float*)d_out;
    float* recon  = out;                          // 16384*512 fp32
    float* hidden = out + (size_t)N_ROWS * D_IN;  // 16384*8192 fp32

    const size_t CNT_BYTES  = (size_t)N_ROWS * sizeof(uint32);
    const size_t FLG_BYTES  = (size_t)N_ROWS * sizeof(uint32);
    const size_t WB_BYTES   = (size_t)D_IN * D_DICT * sizeof(unsigned short);
    const size_t WS_BYTES   = (size_t)D_DICT * 16 * 64 * sizeof(unsigned short);
    const size_t XS_BYTES   = (size_t)N_ROWS * 16 * 64 * sizeof(unsigned short);
    const size_t CAND_BYTES = (size_t)N_ROWS * CAND_CAP * sizeof(uint2);
    const size_t FIXED_B    = CNT_BYTES + FLG_BYTES + WB_BYTES + WS_BYTES + XS_BYTES + CAND_BYTES;
    const size_t ROW_BYTES  = (size_t)D_DICT * sizeof(float);

    char* ws = (char*)d_ws;

    if (ws_size >= FIXED_B) {
        uint32*         CandCnt = (uint32*)ws;
        uint32*         flags   = (uint32*)(ws + CNT_BYTES);
        unsigned short* Wb      = (unsigned short*)(ws + CNT_BYTES + FLG_BYTES);
        unsigned short* Wsp     = (unsigned short*)(ws + CNT_BYTES + FLG_BYTES + WB_BYTES);
        unsigned short* Xsp     = (unsigned short*)(ws + CNT_BYTES + FLG_BYTES + WB_BYTES + WS_BYTES);
        uint2*          Cand    = (uint2*)(ws + CNT_BYTES + FLG_BYTES + WB_BYTES + WS_BYTES + XS_BYTES);

        hipMemsetAsync(CandCnt, 0, CNT_BYTES + FLG_BYTES, stream);
        cast_wdec_swz_kernel<<<(D_IN * D_DICT / 8) / 256, 256, 0, stream>>>(W_dec, Wb);
        split_hilo_kernel<<<(D_DICT * 16) / 256, 256, 0, stream>>>(W_enc, Wsp);
        split_hilo_kernel<<<(N_ROWS * 16) / 256, 256, 0, stream>>>(x, Xsp);

        encode_mfma_cand<<<dim3(D_DICT / 128, N_ROWS / 128), 256, 0, stream>>>(
            Xsp, Wsp, b_enc, Cand, CandCnt);
        select_kernel<<<N_ROWS, 256, 0, stream>>>(Cand, CandCnt, x, W_enc, b_enc, hidden, flags);
        repair_kernel<<<N_ROWS, 256, 0, stream>>>(flags, x, W_enc, b_enc, hidden);

        mfma_decode_kernel<<<N_ROWS / 64, 512, 0, stream>>>(hidden, Wb, b_dec, recon);
    } else {
        float* pre = (float*)ws;
        long long cl = (long long)(ws_size / ROW_BYTES);
        int chunk;
        if (cl >= 128) { chunk = (cl > 2048) ? 2048 : (int)cl; chunk &= ~127; }
        else chunk = (cl < 1) ? 1 : (int)cl;

        for (int r0 = 0; r0 < N_ROWS; r0 += chunk) {
            int nr = (N_ROWS - r0 < chunk) ? (N_ROWS - r0) : chunk;
            dim3 grid((nr + 127) / 128, D_DICT / 128);
            encode_gemm_kernel<<<grid, 256, 0, stream>>>(x, W_enc, b_enc, pre, r0, nr);
            topk_band_kernel<<<nr, 256, 0, stream>>>(pre, r0, x, W_enc, b_enc, hidden);
        }
        decode_direct_kernel<<<N_ROWS, 256, 0, stream>>>(hidden, W_dec, b_dec, recon);
    }
}

// Round 14
// 1365.391 us; speedup vs baseline: 1.3768x; 1.0368x over previous
//
#include <hip/hip_runtime.h>

typedef unsigned int uint32;
typedef __attribute__((ext_vector_type(4))) float  f32x4;
typedef __attribute__((ext_vector_type(8))) short  bf16x8;
typedef __attribute__((ext_vector_type(4))) unsigned short us4;
typedef __attribute__((ext_vector_type(8))) unsigned short us8;

#define N_ROWS   16384
#define D_IN     512
#define D_DICT   8192
#define TOPK     256
#define BAND     2e-3f
#define BCAP     64
#define CCAP     2048
#define CAND_CAP 2048
#define TFIX     1.38f

__device__ __forceinline__ unsigned short f2bf_rne(float f) {
    unsigned u = __float_as_uint(f);
    unsigned r = u + 0x7FFFu + ((u >> 16) & 1u);
    return (unsigned short)(r >> 16);
}
__device__ __forceinline__ float bf2f(unsigned short h) {
    return __uint_as_float(((unsigned)h) << 16);
}
__device__ __forceinline__ uint32 okey(float v) {
    uint32 u = __float_as_uint(v);
    return (u & 0x80000000u) ? ~u : (u | 0x80000000u);
}
// XOR-swizzled LDS element address (validated r5-r13)
__device__ __forceinline__ int swz(int row, int k) {
    return row * 64 + (k ^ ((row & 7) << 3));
}
// async global->LDS, 16B per lane; LDS dest is uniform-base + lane*16 by construction
__device__ __forceinline__ void gll16(const unsigned short* g, unsigned short* l) {
    __builtin_amdgcn_global_load_lds(
        (const __attribute__((address_space(1))) unsigned int*)g,
        (__attribute__((address_space(3))) unsigned int*)l, 16, 0, 0);
}

// ---------------------------------------------------------------------------
// Kernel 0a: cast W_dec -> bf16 with per-row LDS XOR swizzle pre-baked (r13).
// ---------------------------------------------------------------------------
__launch_bounds__(256)
__global__ void cast_wdec_swz_kernel(const float* __restrict__ W,
                                     unsigned short* __restrict__ Wb) {
    int idx = blockIdx.x * 256 + threadIdx.x;
    int d = idx >> 10;
    int g = idx & 1023;
    const float* src = W + (size_t)d * D_DICT + g * 8;
    us8 o;
    #pragma unroll
    for (int j = 0; j < 8; ++j) o[j] = f2bf_rne(src[j]);
    int gout = (g & ~7) | ((g ^ d) & 7);
    *(us8*)&Wb[(size_t)d * D_DICT + gout * 8] = o;
}

// ---------------------------------------------------------------------------
// Kernel 0b: pre-split fp32 -> bf16 hi|lo with per-row swizzle (r10-r13).
// ---------------------------------------------------------------------------
__launch_bounds__(256)
__global__ void split_hilo_kernel(const float* __restrict__ W,
                                  unsigned short* __restrict__ S) {
    int idx = blockIdx.x * 256 + threadIdx.x;
    int row = idx >> 4;
    int c   = idx & 15;
    const float* src = W + (size_t)row * D_IN + c * 32;
    unsigned short hi[32], lo[32];
    #pragma unroll
    for (int j = 0; j < 32; ++j) {
        float v = src[j];
        unsigned short h = f2bf_rne(v);
        hi[j] = h; lo[j] = f2bf_rne(v - bf2f(h));
    }
    int m = row & 7;
    unsigned short* dst = S + ((size_t)row * 16 + c) * 64;
    #pragma unroll
    for (int g = 0; g < 8; ++g) {
        int lg = g ^ m;
        us8 o;
        #pragma unroll
        for (int j = 0; j < 8; ++j)
            o[j] = (lg < 4) ? hi[lg * 8 + j] : lo[(lg - 4) * 8 + j];
        *(us8*)&dst[g * 8] = o;
    }
}

// ---------------------------------------------------------------------------
// stage helper: issue 8 gll16 for one 32-k chunk into At/Bt (linear dest).
// ---------------------------------------------------------------------------
__device__ __forceinline__ void stage_chunk(const unsigned short* __restrict__ Xs,
                                            const unsigned short* __restrict__ Ws,
                                            unsigned short* At, unsigned short* Bt,
                                            int bm, int bn, int c, int tid) {
    #pragma unroll
    for (int q = 0; q < 4; ++q) {
        int s = q * 256 + tid;
        int row = s >> 3;
        int b8  = (s & 7) * 8;
        gll16(&Xs[((size_t)(bm + row) * 16 + c) * 64 + b8], &At[row * 64 + b8]);
        gll16(&Ws[((size_t)(bn + row) * 16 + c) * 64 + b8], &Bt[row * 64 + b8]);
    }
}

// ---------------------------------------------------------------------------
// Kernel 1 (v4): MFMA encode + candidate push, ASYNC 2-phase double-buffer.
// Raw s_barrier + explicit vmcnt(0): STAGE(c+1) issued before compute(c) so
// load latency hides under ds_read+MFMA. One barrier per chunk (vs 2 full
// drains in r13). MFMA count/order per output element unchanged -> Cand
// values bitwise identical to r12/r13.
// ---------------------------------------------------------------------------
__launch_bounds__(256)
__global__ void encode_mfma_cand(const unsigned short* __restrict__ Xs,
                                 const unsigned short* __restrict__ Ws,
                                 const float* __restrict__ b_enc,
                                 uint2* __restrict__ Cand,
                                 uint32* __restrict__ CandCnt) {
    __shared__ unsigned short At[2][128 * 64];   // 2 x 16KB
    __shared__ unsigned short Bt[2][128 * 64];   // 2 x 16KB

    int tid  = threadIdx.x;
    int lane = tid & 63;
    int wid  = tid >> 6;          // 0..3
    int wm   = wid >> 1;          // 0..1
    int wn   = wid & 1;           // 0..1
    int bn   = blockIdx.x * 128;  // dict cols
    int bm   = blockIdx.y * 128;  // rows
    int fr   = lane & 15;
    int fk   = (lane >> 4) << 3;

    f32x4 acc[4][4];
    #pragma unroll
    for (int i = 0; i < 4; ++i)
        #pragma unroll
        for (int j = 0; j < 4; ++j) acc[i][j] = (f32x4)0.f;

    stage_chunk(Xs, Ws, At[0], Bt[0], bm, bn, 0, tid);
    asm volatile("s_waitcnt vmcnt(0)" ::: "memory");
    __builtin_amdgcn_s_barrier();

    for (int c = 0; c < 16; ++c) {
        int cur = c & 1;
        if (c < 15)
            stage_chunk(Xs, Ws, At[cur ^ 1], Bt[cur ^ 1], bm, bn, c + 1, tid);

        const unsigned short* Ac = At[cur];
        const unsigned short* Bc = Bt[cur];
        bf16x8 bh[4], bl[4];
        #pragma unroll
        for (int nj = 0; nj < 4; ++nj) {
            bh[nj] = *(const bf16x8*)&Bc[swz(wn * 64 + nj * 16 + fr, fk)];
            bl[nj] = *(const bf16x8*)&Bc[swz(wn * 64 + nj * 16 + fr, 32 + fk)];
        }
        #pragma unroll
        for (int mi = 0; mi < 4; ++mi) {
            bf16x8 ah = *(const bf16x8*)&Ac[swz(wm * 64 + mi * 16 + fr, fk)];
            bf16x8 al = *(const bf16x8*)&Ac[swz(wm * 64 + mi * 16 + fr, 32 + fk)];
            #pragma unroll
            for (int nj = 0; nj < 4; ++nj) {
                acc[mi][nj] = __builtin_amdgcn_mfma_f32_16x16x32_bf16(ah, bh[nj], acc[mi][nj], 0, 0, 0);
                acc[mi][nj] = __builtin_amdgcn_mfma_f32_16x16x32_bf16(ah, bl[nj], acc[mi][nj], 0, 0, 0);
                acc[mi][nj] = __builtin_amdgcn_mfma_f32_16x16x32_bf16(al, bh[nj], acc[mi][nj], 0, 0, 0);
            }
        }
        // my c+1 loads landed (vmcnt) + everyone finished reading buf[cur]
        // (MFMA lgkm dependence) before any wave re-stages buf[cur] next iter.
        asm volatile("s_waitcnt vmcnt(0)" ::: "memory");
        __builtin_amdgcn_sched_barrier(0);
        __builtin_amdgcn_s_barrier();
    }

    float bcol[4];
    #pragma unroll
    for (int nj = 0; nj < 4; ++nj)
        bcol[nj] = b_enc[bn + wn * 64 + nj * 16 + fr];

    #pragma unroll
    for (int mi = 0; mi < 4; ++mi) {
        int rbase = bm + wm * 64 + mi * 16 + (lane >> 4) * 4;
        #pragma unroll
        for (int reg = 0; reg < 4; ++reg) {
            int r = rbase + reg;
            float v[4]; int pr[4]; int cc = 0;
            #pragma unroll
            for (int nj = 0; nj < 4; ++nj) {
                v[nj] = acc[mi][nj][reg] + bcol[nj];
                pr[nj] = (v[nj] > TFIX) ? 1 : 0;
                cc += pr[nj];
            }
            int incl = cc;
            #pragma unroll
            for (int d = 1; d < 16; d <<= 1) {
                int tv = __shfl_up(incl, d, 16);
                if (fr >= d) incl += tv;
            }
            int total = __shfl(incl, 15, 16);
            if (total > 0) {
                int base = 0;
                if (fr == 0) base = (int)atomicAdd(&CandCnt[r], (uint32)total);
                base = __shfl(base, 0, 16);
                int slot = base + (incl - cc);
                #pragma unroll
                for (int nj = 0; nj < 4; ++nj) {
                    if (pr[nj]) {
                        if (slot < CAND_CAP)
                            Cand[(size_t)r * CAND_CAP + slot] =
                                make_uint2(__float_as_uint(v[nj]),
                                           (uint32)(bn + wn * 64 + nj * 16 + fr));
                        ++slot;
                    }
                }
            }
        }
    }
}

// ---------------------------------------------------------------------------
// Kernel 2 (v3): select — streaming zero-fill + direct scatter (r12), with
// the radix bucket-select parallelized: wave-0 shfl suffix-scan over the 256
// buckets replaces the t0-serial 256-iter loop. Same d/need semantics.
// ---------------------------------------------------------------------------
__launch_bounds__(256)
__global__ void select_kernel(const uint2* __restrict__ Cand,
                              const uint32* __restrict__ CandCnt,
                              const float* __restrict__ x,
                              const float* __restrict__ Wenc,
                              const float* __restrict__ b_enc,
                              float* __restrict__ hidden,
                              uint32* __restrict__ flags) {
    __shared__ float  cand_val[CAND_CAP];
    __shared__ int    cand_idx[CAND_CAP];
    __shared__ uint32 hist[256];
    __shared__ uint32 sh_prefix, sh_need;
    __shared__ int    c_clear, bcnt;
    __shared__ int    bidx_s[BCAP];
    __shared__ float  bval_s[BCAP];

    int row = blockIdx.x;
    int t = threadIdx.x;
    float* hrow = hidden + (size_t)row * D_DICT;

    int n = (int)CandCnt[row];
    bool ok = (n >= TOPK && n <= CAND_CAP);

    #pragma unroll
    for (int c = 0; c < 8; ++c)
        *(float4*)&hrow[(c * 256 + t) * 4] = make_float4(0.f, 0.f, 0.f, 0.f);
    if (ok) {
        for (int e = t; e < n; e += 256) {
            uint2 cv = Cand[(size_t)row * CAND_CAP + e];
            cand_val[e] = __uint_as_float(cv.x);
            cand_idx[e] = (int)cv.y;
        }
    }
    __syncthreads();

    float vT0 = 0.f;
    if (ok) {
        uint32 prefix = 0, need = TOPK;
        for (int pass = 0; pass < 4; ++pass) {
            int shift = 24 - 8 * pass;
            hist[t] = 0;
            __syncthreads();
            uint32 mask_hi = pass ? (0xFFFFFFFFu << (shift + 8)) : 0u;
            for (int e = t; e < n; e += 256) {
                uint32 u = okey(cand_val[e]);
                if ((u & mask_hi) == prefix)
                    atomicAdd(&hist[(u >> shift) & 255u], 1u);
            }
            __syncthreads();
            // wave-0 parallel bucket select: d = max bucket with suffix>=need
            if (t < 64) {
                uint4 h4 = *(const uint4*)&hist[t * 4];
                uint32 lsum = h4.x + h4.y + h4.z + h4.w;
                uint32 s = lsum;
                #pragma unroll
                for (int off = 1; off < 64; off <<= 1) {
                    uint32 vv = __shfl_down(s, off);
                    if (t + off < 64) s += vv;
                }
                uint32 above = s - lsum;          // suffix(bucket 4t+4)
                uint32 suf3 = above + h4.w;
                uint32 suf2 = suf3 + h4.z;
                uint32 suf1 = suf2 + h4.y;
                uint32 suf0 = suf1 + h4.x;        // suffix(bucket 4t)
                if (above < need && suf0 >= need) {
                    int j; uint32 sufj, hj;
                    if (suf3 >= need)      { j = 3; sufj = suf3; hj = h4.w; }
                    else if (suf2 >= need) { j = 2; sufj = suf2; hj = h4.z; }
                    else if (suf1 >= need) { j = 1; sufj = suf1; hj = h4.y; }
                    else                   { j = 0; sufj = suf0; hj = h4.x; }
                    sh_prefix = prefix | ((uint32)(t * 4 + j) << shift);
                    sh_need = need - (sufj - hj);
                }
                if (t == 0 && s < need) {         // unreachable safety (d=0)
                    sh_prefix = prefix;
                    sh_need = need - (s - h4.x);
                }
            }
            __syncthreads();
            prefix = sh_prefix;
            need = sh_need;
            __syncthreads();
        }
        uint32 tb = (prefix & 0x80000000u) ? (prefix & 0x7FFFFFFFu) : ~prefix;
        vT0 = __uint_as_float(tb);
        if (!(vT0 - BAND - 1e-3f > TFIX)) ok = false;
    }

    if (!ok) {
        if (t == 0) flags[row] = 1u;
        return;
    }

    if (t == 0) { c_clear = 0; bcnt = 0; }
    __syncthreads();
    for (int e = t; e < n; e += 256) {
        float v = cand_val[e];
        int i = cand_idx[e];
        if (v > vT0 + BAND) {
            hrow[i] = fmaxf(v, 0.f);
            atomicAdd((uint32*)&c_clear, 1u);
        } else if (v >= vT0 - BAND) {
            int slot = atomicAdd((uint32*)&bcnt, 1u);
            if (slot < BCAP) bidx_s[slot] = i;
        }
    }
    __syncthreads();

    int nb = bcnt < BCAP ? bcnt : BCAP;
    if (t < nb) {
        const float* xr = x + (size_t)row * D_IN;
        const float* wr = Wenc + (size_t)bidx_s[t] * D_IN;
        float acc = 0.f;
        #pragma unroll 8
        for (int k = 0; k < D_IN; ++k)   // ascending k — np rounding class
            acc = fmaf(xr[k], wr[k], acc);
        bval_s[t] = acc + b_enc[bidx_s[t]];
    }
    __syncthreads();
    if (t == 0) {
        int take = TOPK - c_clear;
        for (int rr = 0; rr < take; ++rr) {
            int best = -1; float bv = 0.f; int bi = 0;
            for (int e = 0; e < nb; ++e) {
                int idx = bidx_s[e];
                if (idx < 0) continue;
                float v = bval_s[e];
                if (best < 0 || v > bv || (v == bv && idx < bi)) {
                    best = e; bv = v; bi = idx;
                }
            }
            if (best < 0) break;
            bidx_s[best] = -1;
            hrow[bi] = fmaxf(bv, 0.f);
        }
    }
}

// ---------------------------------------------------------------------------
// Kernel 2b: exact repair for flagged rows (validated r11-r13).
// ---------------------------------------------------------------------------
__launch_bounds__(256)
__global__ void repair_kernel(const uint32* __restrict__ flags,
                              const float* __restrict__ x,
                              const float* __restrict__ Wenc,
                              const float* __restrict__ b_enc,
                              float* __restrict__ hidden) {
    int row = blockIdx.x;
    if (flags[row] == 0u) return;
    __shared__ float  vals[D_DICT];
    __shared__ float  xs[D_IN];
    __shared__ uint32 hist[256];
    __shared__ uint32 pscan[257];
    __shared__ uint32 cnt_eq[256];
    __shared__ uint32 sh_prefix, sh_need;
    int t = threadIdx.x;

    for (int c = t; c < D_IN; c += 256) xs[c] = x[(size_t)row * D_IN + c];
    __syncthreads();
    for (int e = t; e < D_DICT; e += 256) {
        const float* wr = Wenc + (size_t)e * D_IN;
        float acc = 0.f;
        #pragma unroll 8
        for (int k = 0; k < D_IN; ++k)
            acc = fmaf(xs[k], wr[k], acc);
        vals[e] = acc + b_enc[e];
    }
    __syncthreads();

    uint32 prefix = 0, need = TOPK;
    for (int pass = 0; pass < 4; ++pass) {
        int shift = 24 - 8 * pass;
        hist[t] = 0;
        __syncthreads();
        uint32 mask_hi = pass ? (0xFFFFFFFFu << (shift + 8)) : 0u;
        #pragma unroll 4
        for (int c = 0; c < 32; ++c) {
            uint32 u = okey(vals[c * 256 + t]);
            if ((u & mask_hi) == prefix)
                atomicAdd(&hist[(u >> shift) & 255u], 1u);
        }
        __syncthreads();
        if (t == 0) {
            uint32 cum = 0;
            int d = 255;
            for (; d > 0; --d) {
                uint32 h = hist[d];
                if (cum + h >= need) break;
                cum += h;
            }
            sh_prefix = prefix | ((uint32)d << shift);
            sh_need = need - cum;
        }
        __syncthreads();
        prefix = sh_prefix;
        need = sh_need;
        __syncthreads();
    }
    uint32 T = prefix;
    uint32 r = need;
    float* hrow = hidden + (size_t)row * D_DICT;

    #pragma unroll 2
    for (int c = 0; c < 32; ++c) {
        int i = c * 256 + t;
        uint32 u = okey(vals[i]);
        hrow[i] = (u > T) ? fmaxf(vals[i], 0.f) : 0.f;
    }
    __syncthreads();

    int base = t * 32;
    uint32 local = 0;
    for (int j = 0; j < 32; ++j) local += (okey(vals[base + j]) == T) ? 1u : 0u;
    cnt_eq[t] = local;
    __syncthreads();
    if (t == 0) {
        uint32 s = 0;
        for (int i = 0; i < 256; ++i) { pscan[i] = s; s += cnt_eq[i]; }
    }
    __syncthreads();
    uint32 myoff = pscan[t];
    if (local > 0 && myoff < r) {
        uint32 tb = (T & 0x80000000u) ? (T & 0x7FFFFFFFu) : ~T;
        float hv = fmaxf(__uint_as_float(tb), 0.f);
        uint32 rank = myoff;
        for (int j = 0; j < 32 && rank < r; ++j) {
            int i = base + j;
            if (okey(vals[i]) == T) { hrow[i] = hv; rank++; }
        }
    }
}

// ---------------------------------------------------------------------------
// Kernel 3 (v2): MFMA decode, 64x512 tile (validated r13).
// ---------------------------------------------------------------------------
__launch_bounds__(512)
__global__ void mfma_decode_kernel(const float* __restrict__ hidden,
                                   const unsigned short* __restrict__ Wb, // pre-swizzled
                                   const float* __restrict__ b_dec,
                                   float* __restrict__ recon) {
    __shared__ unsigned short At[64 * 64];    // 8KB
    __shared__ unsigned short Bt[512 * 64];   // 64KB

    int tid  = threadIdx.x;
    int lane = tid & 63;
    int wn   = tid >> 6;
    int bm   = blockIdx.x * 64;
    int fr   = lane & 15;

    f32x4 acc[4][4];
    #pragma unroll
    for (int i = 0; i < 4; ++i)
        #pragma unroll
        for (int j = 0; j < 4; ++j) acc[i][j] = (f32x4)0.f;

    for (int k0 = 0; k0 < D_DICT; k0 += 64) {
        #pragma unroll
        for (int i = 0; i < 2; ++i) {
            int idx = i * 512 + tid;
            int row = idx >> 4;
            int kq  = (idx & 15) * 4;
            float4 h4 = *(const float4*)&hidden[(size_t)(bm + row) * D_DICT + k0 + kq];
            us4 o;
            o.x = f2bf_rne(h4.x); o.y = f2bf_rne(h4.y);
            o.z = f2bf_rne(h4.z); o.w = f2bf_rne(h4.w);
            *(us4*)&At[swz(row, kq)] = o;
        }
        #pragma unroll
        for (int q = 0; q < 8; ++q) {
            int s = q * 512 + tid;
            int row = s >> 3;
            int b8  = (s & 7) * 8;
            gll16(&Wb[(size_t)row * D_DICT + k0 + b8], &Bt[row * 64 + b8]);
        }
        __syncthreads();

        #pragma unroll
        for (int ks = 0; ks < 2; ++ks) {
            int kb = ks * 32 + (lane >> 4) * 8;
            bf16x8 av[4], bv[4];
            #pragma unroll
            for (int mi = 0; mi < 4; ++mi)
                av[mi] = *(const bf16x8*)&At[swz(mi * 16 + fr, kb)];
            #pragma unroll
            for (int nj = 0; nj < 4; ++nj)
                bv[nj] = *(const bf16x8*)&Bt[swz(wn * 64 + nj * 16 + fr, kb)];
            #pragma unroll
            for (int mi = 0; mi < 4; ++mi)
                #pragma unroll
                for (int nj = 0; nj < 4; ++nj)
                    acc[mi][nj] = __builtin_amdgcn_mfma_f32_16x16x32_bf16(
                        av[mi], bv[nj], acc[mi][nj], 0, 0, 0);
        }
        __syncthreads();
    }

    #pragma unroll
    for (int mi = 0; mi < 4; ++mi) {
        int r0 = bm + mi * 16 + (lane >> 4) * 4;
        #pragma unroll
        for (int nj = 0; nj < 4; ++nj) {
            int col = wn * 64 + nj * 16 + fr;
            float bd = b_dec[col];
            #pragma unroll
            for (int reg = 0; reg < 4; ++reg)
                recon[(size_t)(r0 + reg) * D_IN + col] = acc[mi][nj][reg] + bd;
        }
    }
}

// ---------------------------------------------------------------------------
// Tier C fallback kernels (validated r10-r13)
// ---------------------------------------------------------------------------
#define EBK 8
#define ESTR 132

__launch_bounds__(256)
__global__ void encode_gemm_kernel(const float* __restrict__ X,
                                   const float* __restrict__ Wenc,
                                   const float* __restrict__ b_enc,
                                   float* __restrict__ P,
                                   int row0, int nrows) {
    __shared__ float As[EBK][ESTR];
    __shared__ float Bs[EBK][ESTR];
    int tid = threadIdx.x;
    int tx = tid & 15;
    int ty = tid >> 4;
    int bm = blockIdx.x * 128;
    int bn = blockIdx.y * 128;
    int srow = tid >> 1;
    int skq  = (tid & 1) * 4;

    float acc[8][8];
    #pragma unroll
    for (int i = 0; i < 8; ++i)
        #pragma unroll
        for (int j = 0; j < 8; ++j) acc[i][j] = 0.f;

    for (int k0 = 0; k0 < D_IN; k0 += EBK) {
        float4 a4 = make_float4(0.f, 0.f, 0.f, 0.f);
        if (bm + srow < nrows)
            a4 = *(const float4*)&X[(size_t)(row0 + bm + srow) * D_IN + k0 + skq];
        float4 b4 = *(const float4*)&Wenc[(size_t)(bn + srow) * D_IN + k0 + skq];
        As[skq + 0][srow] = a4.x; As[skq + 1][srow] = a4.y;
        As[skq + 2][srow] = a4.z; As[skq + 3][srow] = a4.w;
        Bs[skq + 0][srow] = b4.x; Bs[skq + 1][srow] = b4.y;
        Bs[skq + 2][srow] = b4.z; Bs[skq + 3][srow] = b4.w;
        __syncthreads();
        #pragma unroll
        for (int k = 0; k < EBK; ++k) {
            float4 a0 = *(const float4*)&As[k][ty * 4];
            float4 a1 = *(const float4*)&As[k][64 + ty * 4];
            float4 b0 = *(const float4*)&Bs[k][tx * 4];
            float4 b1 = *(const float4*)&Bs[k][64 + tx * 4];
            float a[8] = {a0.x, a0.y, a0.z, a0.w, a1.x, a1.y, a1.z, a1.w};
            float b[8] = {b0.x, b0.y, b0.z, b0.w, b1.x, b1.y, b1.z, b1.w};
            #pragma unroll
            for (int i = 0; i < 8; ++i)
                #pragma unroll
                for (int j = 0; j < 8; ++j)
                    acc[i][j] = fmaf(a[i], b[j], acc[i][j]);
        }
        __syncthreads();
    }

    float4 bias0 = *(const float4*)&b_enc[bn + tx * 4];
    float4 bias1 = *(const float4*)&b_enc[bn + 64 + tx * 4];
    float bb[8] = {bias0.x, bias0.y, bias0.z, bias0.w,
                   bias1.x, bias1.y, bias1.z, bias1.w};
    #pragma unroll
    for (int i = 0; i < 8; ++i) {
        int r = bm + (i < 4 ? ty * 4 + i : 64 + ty * 4 + (i - 4));
        if (r < nrows) {
            float4 o0, o1;
            o0.x = acc[i][0] + bb[0]; o0.y = acc[i][1] + bb[1];
            o0.z = acc[i][2] + bb[2]; o0.w = acc[i][3] + bb[3];
            o1.x = acc[i][4] + bb[4]; o1.y = acc[i][5] + bb[5];
            o1.z = acc[i][6] + bb[6]; o1.w = acc[i][7] + bb[7];
            *(float4*)&P[(size_t)r * D_DICT + bn + tx * 4] = o0;
            *(float4*)&P[(size_t)r * D_DICT + bn + 64 + tx * 4] = o1;
        }
    }
}

__launch_bounds__(256)
__global__ void topk_band_kernel(const float* __restrict__ P,
                                 int row0,
                                 const float* __restrict__ x,
                                 const float* __restrict__ Wenc,
                                 const float* __restrict__ b_enc,
                                 float* __restrict__ hidden) {
    __shared__ float  cand_val[CCAP];
    __shared__ int    cand_idx[CCAP];
    __shared__ uint32 hist[256];
    __shared__ float  redS[4], redS2[4];
    __shared__ float  sh_mu, sh_sig;
    __shared__ uint32 sh_prefix, sh_need;
    __shared__ int    sh_cnt, c_clear, bcnt;
    __shared__ int    bidx_s[BCAP];
    __shared__ float  bval_s[BCAP];

    int lrow = blockIdx.x;
    int grow = row0 + lrow;
    const float* p = P + (size_t)lrow * D_DICT;
    float* hrow = hidden + (size_t)grow * D_DICT;
    int t = threadIdx.x;

    if (t == 0) sh_cnt = 0;
    float s = 0.f, s2 = 0.f;
    #pragma unroll 2
    for (int c = 0; c < 8; ++c) {
        int e4 = c * 256 + t;
        float4 v4 = ((const float4*)p)[e4];
        s  += v4.x + v4.y + v4.z + v4.w;
        s2 += v4.x*v4.x + v4.y*v4.y + v4.z*v4.z + v4.w*v4.w;
        *(float4*)&hrow[e4 * 4] = make_float4(0.f, 0.f, 0.f, 0.f);
    }
    #pragma unroll
    for (int off = 32; off; off >>= 1) {
        s  += __shfl_down(s, off);
        s2 += __shfl_down(s2, off);
    }
    if ((t & 63) == 0) { redS[t >> 6] = s; redS2[t >> 6] = s2; }
    __syncthreads();
    if (t == 0) {
        float S  = redS[0] + redS[1] + redS[2] + redS[3];
        float S2 = redS2[0] + redS2[1] + redS2[2] + redS2[3];
        float mu = S * (1.f / D_DICT);
        float var = S2 * (1.f / D_DICT) - mu * mu;
        sh_mu = mu;
        sh_sig = sqrtf(fmaxf(var, 1e-20f));
    }
    __syncthreads();
    float Tlo = sh_mu + 1.3f * sh_sig;

    #pragma unroll 2
    for (int c = 0; c < 8; ++c) {
        int e4 = c * 256 + t;
        float4 v4 = ((const float4*)p)[e4];
        float vv[4] = {v4.x, v4.y, v4.z, v4.w};
        #pragma unroll
        for (int j = 0; j < 4; ++j) {
            if (vv[j] > Tlo) {
                int slot = atomicAdd((uint32*)&sh_cnt, 1u);
                if (slot < CCAP) { cand_val[slot] = vv[j]; cand_idx[slot] = e4 * 4 + j; }
            }
        }
    }
    __syncthreads();
    int n = sh_cnt;
    bool found = (n >= TOPK && n <= CCAP);

    float vT0 = 0.f;
    for (int rtry = 0; rtry < 2; ++rtry) {
        uint32 prefix = 0, need = TOPK;
        for (int pass = 0; pass < 4; ++pass) {
            int shift = 24 - 8 * pass;
            hist[t] = 0;
            __syncthreads();
            uint32 mask_hi = pass ? (0xFFFFFFFFu << (shift + 8)) : 0u;
            if (found) {
                for (int e = t; e < n; e += 256) {
                    uint32 u = okey(cand_val[e]);
                    if ((u & mask_hi) == prefix)
                        atomicAdd(&hist[(u >> shift) & 255u], 1u);
                }
            } else {
                for (int e = t; e < D_DICT; e += 256) {
                    uint32 u = okey(p[e]);
                    if ((u & mask_hi) == prefix)
                        atomicAdd(&hist[(u >> shift) & 255u], 1u);
                }
            }
            __syncthreads();
            if (t == 0) {
                uint32 cum = 0;
                int d = 255;
                for (; d > 0; --d) {
                    uint32 h = hist[d];
                    if (cum + h >= need) break;
                    cum += h;
                }
                sh_prefix = prefix | ((uint32)d << shift);
                sh_need = need - cum;
            }
            __syncthreads();
            prefix = sh_prefix;
            need = sh_need;
            __syncthreads();
        }
        uint32 tb = (prefix & 0x80000000u) ? (prefix & 0x7FFFFFFFu) : ~prefix;
        vT0 = __uint_as_float(tb);
        if (!found) break;
        if (vT0 - BAND - 1e-3f > Tlo) break;
        found = false;
        __syncthreads();
    }

    if (t == 0) { c_clear = 0; bcnt = 0; }
    __syncthreads();
    if (found) {
        for (int e = t; e < n; e += 256) {
            float v = cand_val[e];
            int i = cand_idx[e];
            if (v > vT0 + BAND) {
                hrow[i] = fmaxf(v, 0.f);
                atomicAdd((uint32*)&c_clear, 1u);
            } else if (v >= vT0 - BAND) {
                int slot = atomicAdd((uint32*)&bcnt, 1u);
                if (slot < BCAP) bidx_s[slot] = i;
            }
        }
    } else {
        for (int e = t; e < D_DICT; e += 256) {
            float v = p[e];
            if (v > vT0 + BAND) {
                hrow[e] = fmaxf(v, 0.f);
                atomicAdd((uint32*)&c_clear, 1u);
            } else if (v >= vT0 - BAND) {
                int slot = atomicAdd((uint32*)&bcnt, 1u);
                if (slot < BCAP) bidx_s[slot] = e;
            }
        }
    }
    __syncthreads();

    int nb = bcnt < BCAP ? bcnt : BCAP;
    if (t < nb) {
        const float* xr = x + (size_t)grow * D_IN;
        const float* wr = Wenc + (size_t)bidx_s[t] * D_IN;
        float acc = 0.f;
        #pragma unroll 8
        for (int k = 0; k < D_IN; ++k)
            acc = fmaf(xr[k], wr[k], acc);
        bval_s[t] = acc + b_enc[bidx_s[t]];
    }
    __syncthreads();
    if (t == 0) {
        int take = TOPK - c_clear;
        for (int rr = 0; rr < take; ++rr) {
            int best = -1; float bv = 0.f; int bi = 0;
            for (int e = 0; e < nb; ++e) {
                int idx = bidx_s[e];
                if (idx < 0) continue;
                float v = bval_s[e];
                if (best < 0 || v > bv || (v == bv && idx < bi)) {
                    best = e; bv = v; bi = idx;
                }
            }
            if (best < 0) break;
            bidx_s[best] = -1;
            hrow[bi] = fmaxf(bv, 0.f);
        }
    }
}

__launch_bounds__(256)
__global__ void decode_direct_kernel(const float* __restrict__ hidden,
                                     const float* __restrict__ W_dec,
                                     const float* __restrict__ b_dec,
                                     float* __restrict__ recon) {
    __shared__ float  sv[TOPK];
    __shared__ int    sidx[TOPK];
    __shared__ int    offs[257];
    int row = blockIdx.x;
    int t = threadIdx.x;
    const float* hrow = hidden + (size_t)row * D_DICT;

    int base = t * 32;
    int c = 0;
    for (int j = 0; j < 32; ++j) c += (hrow[base + j] > 0.f) ? 1 : 0;
    offs[t + 1] = c;
    __syncthreads();
    if (t == 0) {
        offs[0] = 0;
        for (int i = 0; i < 256; ++i) offs[i + 1] += offs[i];
    }
    __syncthreads();
    int o = offs[t];
    for (int j = 0; j < 32; ++j) {
        float v = hrow[base + j];
        if (v > 0.f) { sv[o] = v; sidx[o] = base + j; ++o; }
    }
    __syncthreads();
    int total = offs[256];

    int d0 = 2 * t;
    float acc0 = b_dec[d0];
    float acc1 = b_dec[d0 + 1];
    for (int k = 0; k < total; ++k) {
        float v = sv[k];
        int idx = sidx[k];
        acc0 = fmaf(v, W_dec[(size_t)d0 * D_DICT + idx], acc0);
        acc1 = fmaf(v, W_dec[(size_t)(d0 + 1) * D_DICT + idx], acc1);
    }
    *(float2*)&recon[(size_t)row * D_IN + d0] = make_float2(acc0, acc1);
}

// ---------------------------------------------------------------------------
extern "C" void kernel_launch(void* const* d_in, const int* in_sizes, int n_in,
                              void* d_out, int out_size, void* d_ws, size_t ws_size,
                              hipStream_t stream) {
    const float* x     = (const float*)d_in[0];
    const float* W_enc = (const float*)d_in[1];
    const float* b_enc = (const float*)d_in[2];
    const float* W_dec = (const float*)d_in[3];
    const float* b_dec = (const float*)d_in[4];

    float* out    = (float*)d_out;
    float* recon  = out;                          // 16384*512 fp32
    float* hidden = out + (size_t)N_ROWS * D_IN;  // 16384*8192 fp32

    const size_t CNT_BYTES  = (size_t)N_ROWS * sizeof(uint32);
    const size_t FLG_BYTES  = (size_t)N_ROWS * sizeof(uint32);
    const size_t WB_BYTES   = (size_t)D_IN * D_DICT * sizeof(unsigned short);
    const size_t WS_BYTES   = (size_t)D_DICT * 16 * 64 * sizeof(unsigned short);
    const size_t XS_BYTES   = (size_t)N_ROWS * 16 * 64 * sizeof(unsigned short);
    const size_t CAND_BYTES = (size_t)N_ROWS * CAND_CAP * sizeof(uint2);
    const size_t FIXED_B    = CNT_BYTES + FLG_BYTES + WB_BYTES + WS_BYTES + XS_BYTES + CAND_BYTES;
    const size_t ROW_BYTES  = (size_t)D_DICT * sizeof(float);

    char* ws = (char*)d_ws;

    if (ws_size >= FIXED_B) {
        uint32*         CandCnt = (uint32*)ws;
        uint32*         flags   = (uint32*)(ws + CNT_BYTES);
        unsigned short* Wb      = (unsigned short*)(ws + CNT_BYTES + FLG_BYTES);
        unsigned short* Wsp     = (unsigned short*)(ws + CNT_BYTES + FLG_BYTES + WB_BYTES);
        unsigned short* Xsp     = (unsigned short*)(ws + CNT_BYTES + FLG_BYTES + WB_BYTES + WS_BYTES);
        uint2*          Cand    = (uint2*)(ws + CNT_BYTES + FLG_BYTES + WB_BYTES + WS_BYTES + XS_BYTES);

        hipMemsetAsync(CandCnt, 0, CNT_BYTES + FLG_BYTES, stream);
        cast_wdec_swz_kernel<<<(D_IN * D_DICT / 8) / 256, 256, 0, stream>>>(W_dec, Wb);
        split_hilo_kernel<<<(D_DICT * 16) / 256, 256, 0, stream>>>(W_enc, Wsp);
        split_hilo_kernel<<<(N_ROWS * 16) / 256, 256, 0, stream>>>(x, Xsp);

        encode_mfma_cand<<<dim3(D_DICT / 128, N_ROWS / 128), 256, 0, stream>>>(
            Xsp, Wsp, b_enc, Cand, CandCnt);
        select_kernel<<<N_ROWS, 256, 0, stream>>>(Cand, CandCnt, x, W_enc, b_enc, hidden, flags);
        repair_kernel<<<N_ROWS, 256, 0, stream>>>(flags, x, W_enc, b_enc, hidden);

        mfma_decode_kernel<<<N_ROWS / 64, 512, 0, stream>>>(hidden, Wb, b_dec, recon);
    } else {
        float* pre = (float*)ws;
        long long cl = (long long)(ws_size / ROW_BYTES);
        int chunk;
        if (cl >= 128) { chunk = (cl > 2048) ? 2048 : (int)cl; chunk &= ~127; }
        else chunk = (cl < 1) ? 1 : (int)cl;

        for (int r0 = 0; r0 < N_ROWS; r0 += chunk) {
            int nr = (N_ROWS - r0 < chunk) ? (N_ROWS - r0) : chunk;
            dim3 grid((nr + 127) / 128, D_DICT / 128);
            encode_gemm_kernel<<<grid, 256, 0, stream>>>(x, W_enc, b_enc, pre, r0, nr);
            topk_band_kernel<<<nr, 256, 0, stream>>>(pre, r0, x, W_enc, b_enc, hidden);
        }
        decode_direct_kernel<<<N_ROWS, 256, 0, stream>>>(hidden, W_dec, b_dec, recon);
    }
}

// Round 15
// 1248.210 us; speedup vs baseline: 1.5061x; 1.0939x over previous
//
#include <hip/hip_runtime.h>

typedef unsigned int uint32;
typedef __attribute__((ext_vector_type(4))) float  f32x4;
typedef __attribute__((ext_vector_type(8))) short  bf16x8;
typedef __attribute__((ext_vector_type(4))) unsigned short us4;
typedef __attribute__((ext_vector_type(8))) unsigned short us8;

#define N_ROWS   16384
#define D_IN     512
#define D_DICT   8192
#define TOPK     256
#define BAND     1.5e-2f   // widened for 1-term bf16 encode (err sigma ~1.6e-3, 9 sigma)
#define BCAP     64
#define CCAP     2048
#define CAND_CAP 2048
#define TFIX     1.38f

__device__ __forceinline__ unsigned short f2bf_rne(float f) {
    unsigned u = __float_as_uint(f);
    unsigned r = u + 0x7FFFu + ((u >> 16) & 1u);
    return (unsigned short)(r >> 16);
}
__device__ __forceinline__ float bf2f(unsigned short h) {
    return __uint_as_float(((unsigned)h) << 16);
}
__device__ __forceinline__ uint32 okey(float v) {
    uint32 u = __float_as_uint(v);
    return (u & 0x80000000u) ? ~u : (u | 0x80000000u);
}
// XOR-swizzled LDS element address (validated r5-r14)
__device__ __forceinline__ int swz(int row, int k) {
    return row * 64 + (k ^ ((row & 7) << 3));
}
// async global->LDS, 16B/lane; LDS dest = uniform-base + lane*16 by construction
__device__ __forceinline__ void gll16(const unsigned short* g, unsigned short* l) {
    __builtin_amdgcn_global_load_lds(
        (const __attribute__((address_space(1))) unsigned int*)g,
        (__attribute__((address_space(3))) unsigned int*)l, 16, 0, 0);
}

// ---------------------------------------------------------------------------
// Kernel 0: generic fp32 -> bf16 cast with the per-row LDS XOR swizzle baked
// in: within each 64-elem k-chunk, 8-elem group g -> g ^ (row & 7). Used for
// x, W_enc (gprl=6: 64 groups/row) and W_dec (gprl=10: 1024 groups/row).
// ---------------------------------------------------------------------------
__launch_bounds__(256)
__global__ void cast_swz_kernel(const float* __restrict__ src,
                                unsigned short* __restrict__ dst,
                                int gprl) {
    int idx = blockIdx.x * 256 + threadIdx.x;
    int row = idx >> gprl;
    int g   = idx & ((1 << gprl) - 1);
    const float* s = src + ((size_t)idx << 3);
    us8 o;
    #pragma unroll
    for (int j = 0; j < 8; ++j) o[j] = f2bf_rne(s[j]);
    int gout = (g & ~7) | ((g ^ row) & 7);
    *(us8*)&dst[(((size_t)row << gprl) + gout) << 3] = o;
}

// ---------------------------------------------------------------------------
// Kernel 1 (v5): single-term bf16 MFMA encode + candidate push. 128x128 tile,
// 256 thr (4 waves 2Mx2N, per-wave 64x64), BK=64 (8 chunks), plain 2-barrier
// loop (r14's explicit dbuf regressed; reverted per m99/m141). Approx err
// sigma ~1.6e-3 -> exact band fixup with BAND=1.5e-2 preserves selection.
// ---------------------------------------------------------------------------
__launch_bounds__(256)
__global__ void encode_mfma_cand(const unsigned short* __restrict__ Xb,
                                 const unsigned short* __restrict__ Web,
                                 const float* __restrict__ b_enc,
                                 uint2* __restrict__ Cand,
                                 uint32* __restrict__ CandCnt) {
    __shared__ unsigned short At[128 * 64];   // 16KB
    __shared__ unsigned short Bt[128 * 64];   // 16KB

    int tid  = threadIdx.x;
    int lane = tid & 63;
    int wid  = tid >> 6;          // 0..3
    int wm   = wid >> 1;          // 0..1
    int wn   = wid & 1;           // 0..1
    int bn   = blockIdx.x * 128;  // dict cols (fast dim: blocks share bm rows)
    int bm   = blockIdx.y * 128;  // rows
    int fr   = lane & 15;

    f32x4 acc[4][4];
    #pragma unroll
    for (int i = 0; i < 4; ++i)
        #pragma unroll
        for (int j = 0; j < 4; ++j) acc[i][j] = (f32x4)0.f;

    for (int c = 0; c < 8; ++c) {
        #pragma unroll
        for (int q = 0; q < 4; ++q) {
            int s = q * 256 + tid;
            int row = s >> 3;
            int g8  = (s & 7) * 8;
            gll16(&Xb[(size_t)(bm + row) * D_IN + c * 64 + g8], &At[row * 64 + g8]);
            gll16(&Web[(size_t)(bn + row) * D_IN + c * 64 + g8], &Bt[row * 64 + g8]);
        }
        __syncthreads();

        #pragma unroll
        for (int ks = 0; ks < 2; ++ks) {
            int kb = ks * 32 + (lane >> 4) * 8;
            bf16x8 av[4], bv[4];
            #pragma unroll
            for (int nj = 0; nj < 4; ++nj)
                bv[nj] = *(const bf16x8*)&Bt[swz(wn * 64 + nj * 16 + fr, kb)];
            #pragma unroll
            for (int mi = 0; mi < 4; ++mi)
                av[mi] = *(const bf16x8*)&At[swz(wm * 64 + mi * 16 + fr, kb)];
            #pragma unroll
            for (int mi = 0; mi < 4; ++mi)
                #pragma unroll
                for (int nj = 0; nj < 4; ++nj)
                    acc[mi][nj] = __builtin_amdgcn_mfma_f32_16x16x32_bf16(
                        av[mi], bv[nj], acc[mi][nj], 0, 0, 0);
        }
        __syncthreads();
    }

    float bcol[4];
    #pragma unroll
    for (int nj = 0; nj < 4; ++nj)
        bcol[nj] = b_enc[bn + wn * 64 + nj * 16 + fr];

    #pragma unroll
    for (int mi = 0; mi < 4; ++mi) {
        int rbase = bm + wm * 64 + mi * 16 + (lane >> 4) * 4;
        #pragma unroll
        for (int reg = 0; reg < 4; ++reg) {
            int r = rbase + reg;
            float v[4]; int pr[4]; int cc = 0;
            #pragma unroll
            for (int nj = 0; nj < 4; ++nj) {
                v[nj] = acc[mi][nj][reg] + bcol[nj];
                pr[nj] = (v[nj] > TFIX) ? 1 : 0;
                cc += pr[nj];
            }
            int incl = cc;
            #pragma unroll
            for (int d = 1; d < 16; d <<= 1) {
                int tv = __shfl_up(incl, d, 16);
                if (fr >= d) incl += tv;
            }
            int total = __shfl(incl, 15, 16);
            if (total > 0) {
                int base = 0;
                if (fr == 0) base = (int)atomicAdd(&CandCnt[r], (uint32)total);
                base = __shfl(base, 0, 16);
                int slot = base + (incl - cc);
                #pragma unroll
                for (int nj = 0; nj < 4; ++nj) {
                    if (pr[nj]) {
                        if (slot < CAND_CAP)
                            Cand[(size_t)r * CAND_CAP + slot] =
                                make_uint2(__float_as_uint(v[nj]),
                                           (uint32)(bn + wn * 64 + nj * 16 + fr));
                        ++slot;
                    }
                }
            }
        }
    }
}

// ---------------------------------------------------------------------------
// Kernel 2: select (r14 v3: streaming zero-fill + direct scatter + wave-0
// parallel bucket select) + NEW: band overflow (bcnt > BCAP) flags the row
// for exact repair instead of silently dropping entries.
// ---------------------------------------------------------------------------
__launch_bounds__(256)
__global__ void select_kernel(const uint2* __restrict__ Cand,
                              const uint32* __restrict__ CandCnt,
                              const float* __restrict__ x,
                              const float* __restrict__ Wenc,
                              const float* __restrict__ b_enc,
                              float* __restrict__ hidden,
                              uint32* __restrict__ flags) {
    __shared__ float  cand_val[CAND_CAP];
    __shared__ int    cand_idx[CAND_CAP];
    __shared__ uint32 hist[256];
    __shared__ uint32 sh_prefix, sh_need;
    __shared__ int    c_clear, bcnt;
    __shared__ int    bidx_s[BCAP];
    __shared__ float  bval_s[BCAP];

    int row = blockIdx.x;
    int t = threadIdx.x;
    float* hrow = hidden + (size_t)row * D_DICT;

    int n = (int)CandCnt[row];
    bool ok = (n >= TOPK && n <= CAND_CAP);

    #pragma unroll
    for (int c = 0; c < 8; ++c)
        *(float4*)&hrow[(c * 256 + t) * 4] = make_float4(0.f, 0.f, 0.f, 0.f);
    if (ok) {
        for (int e = t; e < n; e += 256) {
            uint2 cv = Cand[(size_t)row * CAND_CAP + e];
            cand_val[e] = __uint_as_float(cv.x);
            cand_idx[e] = (int)cv.y;
        }
    }
    __syncthreads();

    float vT0 = 0.f;
    if (ok) {
        uint32 prefix = 0, need = TOPK;
        for (int pass = 0; pass < 4; ++pass) {
            int shift = 24 - 8 * pass;
            hist[t] = 0;
            __syncthreads();
            uint32 mask_hi = pass ? (0xFFFFFFFFu << (shift + 8)) : 0u;
            for (int e = t; e < n; e += 256) {
                uint32 u = okey(cand_val[e]);
                if ((u & mask_hi) == prefix)
                    atomicAdd(&hist[(u >> shift) & 255u], 1u);
            }
            __syncthreads();
            if (t < 64) {
                uint4 h4 = *(const uint4*)&hist[t * 4];
                uint32 lsum = h4.x + h4.y + h4.z + h4.w;
                uint32 s = lsum;
                #pragma unroll
                for (int off = 1; off < 64; off <<= 1) {
                    uint32 vv = __shfl_down(s, off);
                    if (t + off < 64) s += vv;
                }
                uint32 above = s - lsum;
                uint32 suf3 = above + h4.w;
                uint32 suf2 = suf3 + h4.z;
                uint32 suf1 = suf2 + h4.y;
                uint32 suf0 = suf1 + h4.x;
                if (above < need && suf0 >= need) {
                    int j; uint32 sufj, hj;
                    if (suf3 >= need)      { j = 3; sufj = suf3; hj = h4.w; }
                    else if (suf2 >= need) { j = 2; sufj = suf2; hj = h4.z; }
                    else if (suf1 >= need) { j = 1; sufj = suf1; hj = h4.y; }
                    else                   { j = 0; sufj = suf0; hj = h4.x; }
                    sh_prefix = prefix | ((uint32)(t * 4 + j) << shift);
                    sh_need = need - (sufj - hj);
                }
                if (t == 0 && s < need) {
                    sh_prefix = prefix;
                    sh_need = need - (s - h4.x);
                }
            }
            __syncthreads();
            prefix = sh_prefix;
            need = sh_need;
            __syncthreads();
        }
        uint32 tb = (prefix & 0x80000000u) ? (prefix & 0x7FFFFFFFu) : ~prefix;
        vT0 = __uint_as_float(tb);
        if (!(vT0 - BAND - 1e-3f > TFIX)) ok = false;
    }

    if (!ok) {
        if (t == 0) flags[row] = 1u;
        return;
    }

    if (t == 0) { c_clear = 0; bcnt = 0; }
    __syncthreads();
    for (int e = t; e < n; e += 256) {
        float v = cand_val[e];
        int i = cand_idx[e];
        if (v > vT0 + BAND) {
            hrow[i] = fmaxf(v, 0.f);
            atomicAdd((uint32*)&c_clear, 1u);
        } else if (v >= vT0 - BAND) {
            int slot = atomicAdd((uint32*)&bcnt, 1u);
            if (slot < BCAP) bidx_s[slot] = i;
        }
    }
    __syncthreads();

    if (bcnt > BCAP) {              // band overflow: exact repair handles row
        if (t == 0) flags[row] = 1u;
        return;
    }

    int nb = bcnt;
    if (t < nb) {
        const float* xr = x + (size_t)row * D_IN;
        const float* wr = Wenc + (size_t)bidx_s[t] * D_IN;
        float acc = 0.f;
        #pragma unroll 8
        for (int k = 0; k < D_IN; ++k)   // ascending k — np rounding class
            acc = fmaf(xr[k], wr[k], acc);
        bval_s[t] = acc + b_enc[bidx_s[t]];
    }
    __syncthreads();
    if (t == 0) {
        int take = TOPK - c_clear;
        for (int rr = 0; rr < take; ++rr) {
            int best = -1; float bv = 0.f; int bi = 0;
            for (int e = 0; e < nb; ++e) {
                int idx = bidx_s[e];
                if (idx < 0) continue;
                float v = bval_s[e];
                if (best < 0 || v > bv || (v == bv && idx < bi)) {
                    best = e; bv = v; bi = idx;
                }
            }
            if (best < 0) break;
            bidx_s[best] = -1;
            hrow[bi] = fmaxf(bv, 0.f);
        }
    }
}

// ---------------------------------------------------------------------------
// Kernel 2b: exact repair for flagged rows (validated r11-r14).
// ---------------------------------------------------------------------------
__launch_bounds__(256)
__global__ void repair_kernel(const uint32* __restrict__ flags,
                              const float* __restrict__ x,
                              const float* __restrict__ Wenc,
                              const float* __restrict__ b_enc,
                              float* __restrict__ hidden) {
    int row = blockIdx.x;
    if (flags[row] == 0u) return;
    __shared__ float  vals[D_DICT];
    __shared__ float  xs[D_IN];
    __shared__ uint32 hist[256];
    __shared__ uint32 pscan[257];
    __shared__ uint32 cnt_eq[256];
    __shared__ uint32 sh_prefix, sh_need;
    int t = threadIdx.x;

    for (int c = t; c < D_IN; c += 256) xs[c] = x[(size_t)row * D_IN + c];
    __syncthreads();
    for (int e = t; e < D_DICT; e += 256) {
        const float* wr = Wenc + (size_t)e * D_IN;
        float acc = 0.f;
        #pragma unroll 8
        for (int k = 0; k < D_IN; ++k)   // ascending k — np rounding class
            acc = fmaf(xs[k], wr[k], acc);
        vals[e] = acc + b_enc[e];
    }
    __syncthreads();

    uint32 prefix = 0, need = TOPK;
    for (int pass = 0; pass < 4; ++pass) {
        int shift = 24 - 8 * pass;
        hist[t] = 0;
        __syncthreads();
        uint32 mask_hi = pass ? (0xFFFFFFFFu << (shift + 8)) : 0u;
        #pragma unroll 4
        for (int c = 0; c < 32; ++c) {
            uint32 u = okey(vals[c * 256 + t]);
            if ((u & mask_hi) == prefix)
                atomicAdd(&hist[(u >> shift) & 255u], 1u);
        }
        __syncthreads();
        if (t == 0) {
            uint32 cum = 0;
            int d = 255;
            for (; d > 0; --d) {
                uint32 h = hist[d];
                if (cum + h >= need) break;
                cum += h;
            }
            sh_prefix = prefix | ((uint32)d << shift);
            sh_need = need - cum;
        }
        __syncthreads();
        prefix = sh_prefix;
        need = sh_need;
        __syncthreads();
    }
    uint32 T = prefix;
    uint32 r = need;
    float* hrow = hidden + (size_t)row * D_DICT;

    #pragma unroll 2
    for (int c = 0; c < 32; ++c) {
        int i = c * 256 + t;
        uint32 u = okey(vals[i]);
        hrow[i] = (u > T) ? fmaxf(vals[i], 0.f) : 0.f;
    }
    __syncthreads();

    int base = t * 32;
    uint32 local = 0;
    for (int j = 0; j < 32; ++j) local += (okey(vals[base + j]) == T) ? 1u : 0u;
    cnt_eq[t] = local;
    __syncthreads();
    if (t == 0) {
        uint32 s = 0;
        for (int i = 0; i < 256; ++i) { pscan[i] = s; s += cnt_eq[i]; }
    }
    __syncthreads();
    uint32 myoff = pscan[t];
    if (local > 0 && myoff < r) {
        uint32 tb = (T & 0x80000000u) ? (T & 0x7FFFFFFFu) : ~T;
        float hv = fmaxf(__uint_as_float(tb), 0.f);
        uint32 rank = myoff;
        for (int j = 0; j < 32 && rank < r; ++j) {
            int i = base + j;
            if (okey(vals[i]) == T) { hrow[i] = hv; rank++; }
        }
    }
}

// ---------------------------------------------------------------------------
// Kernel 3: MFMA decode, 64x512 tile (validated r13/r14). Wb pre-swizzled.
// ---------------------------------------------------------------------------
__launch_bounds__(512)
__global__ void mfma_decode_kernel(const float* __restrict__ hidden,
                                   const unsigned short* __restrict__ Wb,
                                   const float* __restrict__ b_dec,
                                   float* __restrict__ recon) {
    __shared__ unsigned short At[64 * 64];    // 8KB
    __shared__ unsigned short Bt[512 * 64];   // 64KB

    int tid  = threadIdx.x;
    int lane = tid & 63;
    int wn   = tid >> 6;
    int bm   = blockIdx.x * 64;
    int fr   = lane & 15;

    f32x4 acc[4][4];
    #pragma unroll
    for (int i = 0; i < 4; ++i)
        #pragma unroll
        for (int j = 0; j < 4; ++j) acc[i][j] = (f32x4)0.f;

    for (int k0 = 0; k0 < D_DICT; k0 += 64) {
        #pragma unroll
        for (int i = 0; i < 2; ++i) {
            int idx = i * 512 + tid;
            int row = idx >> 4;
            int kq  = (idx & 15) * 4;
            float4 h4 = *(const float4*)&hidden[(size_t)(bm + row) * D_DICT + k0 + kq];
            us4 o;
            o.x = f2bf_rne(h4.x); o.y = f2bf_rne(h4.y);
            o.z = f2bf_rne(h4.z); o.w = f2bf_rne(h4.w);
            *(us4*)&At[swz(row, kq)] = o;
        }
        #pragma unroll
        for (int q = 0; q < 8; ++q) {
            int s = q * 512 + tid;
            int row = s >> 3;
            int b8  = (s & 7) * 8;
            gll16(&Wb[(size_t)row * D_DICT + k0 + b8], &Bt[row * 64 + b8]);
        }
        __syncthreads();

        #pragma unroll
        for (int ks = 0; ks < 2; ++ks) {
            int kb = ks * 32 + (lane >> 4) * 8;
            bf16x8 av[4], bv[4];
            #pragma unroll
            for (int mi = 0; mi < 4; ++mi)
                av[mi] = *(const bf16x8*)&At[swz(mi * 16 + fr, kb)];
            #pragma unroll
            for (int nj = 0; nj < 4; ++nj)
                bv[nj] = *(const bf16x8*)&Bt[swz(wn * 64 + nj * 16 + fr, kb)];
            #pragma unroll
            for (int mi = 0; mi < 4; ++mi)
                #pragma unroll
                for (int nj = 0; nj < 4; ++nj)
                    acc[mi][nj] = __builtin_amdgcn_mfma_f32_16x16x32_bf16(
                        av[mi], bv[nj], acc[mi][nj], 0, 0, 0);
        }
        __syncthreads();
    }

    #pragma unroll
    for (int mi = 0; mi < 4; ++mi) {
        int r0 = bm + mi * 16 + (lane >> 4) * 4;
        #pragma unroll
        for (int nj = 0; nj < 4; ++nj) {
            int col = wn * 64 + nj * 16 + fr;
            float bd = b_dec[col];
            #pragma unroll
            for (int reg = 0; reg < 4; ++reg)
                recon[(size_t)(r0 + reg) * D_IN + col] = acc[mi][nj][reg] + bd;
        }
    }
}

// ---------------------------------------------------------------------------
// Tier C fallback kernels (validated r10-r14)
// ---------------------------------------------------------------------------
#define EBK 8
#define ESTR 132

__launch_bounds__(256)
__global__ void encode_gemm_kernel(const float* __restrict__ X,
                                   const float* __restrict__ Wenc,
                                   const float* __restrict__ b_enc,
                                   float* __restrict__ P,
                                   int row0, int nrows) {
    __shared__ float As[EBK][ESTR];
    __shared__ float Bs[EBK][ESTR];
    int tid = threadIdx.x;
    int tx = tid & 15;
    int ty = tid >> 4;
    int bm = blockIdx.x * 128;
    int bn = blockIdx.y * 128;
    int srow = tid >> 1;
    int skq  = (tid & 1) * 4;

    float acc[8][8];
    #pragma unroll
    for (int i = 0; i < 8; ++i)
        #pragma unroll
        for (int j = 0; j < 8; ++j) acc[i][j] = 0.f;

    for (int k0 = 0; k0 < D_IN; k0 += EBK) {
        float4 a4 = make_float4(0.f, 0.f, 0.f, 0.f);
        if (bm + srow < nrows)
            a4 = *(const float4*)&X[(size_t)(row0 + bm + srow) * D_IN + k0 + skq];
        float4 b4 = *(const float4*)&Wenc[(size_t)(bn + srow) * D_IN + k0 + skq];
        As[skq + 0][srow] = a4.x; As[skq + 1][srow] = a4.y;
        As[skq + 2][srow] = a4.z; As[skq + 3][srow] = a4.w;
        Bs[skq + 0][srow] = b4.x; Bs[skq + 1][srow] = b4.y;
        Bs[skq + 2][srow] = b4.z; Bs[skq + 3][srow] = b4.w;
        __syncthreads();
        #pragma unroll
        for (int k = 0; k < EBK; ++k) {
            float4 a0 = *(const float4*)&As[k][ty * 4];
            float4 a1 = *(const float4*)&As[k][64 + ty * 4];
            float4 b0 = *(const float4*)&Bs[k][tx * 4];
            float4 b1 = *(const float4*)&Bs[k][64 + tx * 4];
            float a[8] = {a0.x, a0.y, a0.z, a0.w, a1.x, a1.y, a1.z, a1.w};
            float b[8] = {b0.x, b0.y, b0.z, b0.w, b1.x, b1.y, b1.z, b1.w};
            #pragma unroll
            for (int i = 0; i < 8; ++i)
                #pragma unroll
                for (int j = 0; j < 8; ++j)
                    acc[i][j] = fmaf(a[i], b[j], acc[i][j]);
        }
        __syncthreads();
    }

    float4 bias0 = *(const float4*)&b_enc[bn + tx * 4];
    float4 bias1 = *(const float4*)&b_enc[bn + 64 + tx * 4];
    float bb[8] = {bias0.x, bias0.y, bias0.z, bias0.w,
                   bias1.x, bias1.y, bias1.z, bias1.w};
    #pragma unroll
    for (int i = 0; i < 8; ++i) {
        int r = bm + (i < 4 ? ty * 4 + i : 64 + ty * 4 + (i - 4));
        if (r < nrows) {
            float4 o0, o1;
            o0.x = acc[i][0] + bb[0]; o0.y = acc[i][1] + bb[1];
            o0.z = acc[i][2] + bb[2]; o0.w = acc[i][3] + bb[3];
            o1.x = acc[i][4] + bb[4]; o1.y = acc[i][5] + bb[5];
            o1.z = acc[i][6] + bb[6]; o1.w = acc[i][7] + bb[7];
            *(float4*)&P[(size_t)r * D_DICT + bn + tx * 4] = o0;
            *(float4*)&P[(size_t)r * D_DICT + bn + 64 + tx * 4] = o1;
        }
    }
}

__launch_bounds__(256)
__global__ void topk_band_kernel(const float* __restrict__ P,
                                 int row0,
                                 const float* __restrict__ x,
                                 const float* __restrict__ Wenc,
                                 const float* __restrict__ b_enc,
                                 float* __restrict__ hidden) {
    __shared__ float  cand_val[CCAP];
    __shared__ int    cand_idx[CCAP];
    __shared__ uint32 hist[256];
    __shared__ float  redS[4], redS2[4];
    __shared__ float  sh_mu, sh_sig;
    __shared__ uint32 sh_prefix, sh_need;
    __shared__ int    sh_cnt, c_clear, bcnt;
    __shared__ int    bidx_s[BCAP];
    __shared__ float  bval_s[BCAP];

    int lrow = blockIdx.x;
    int grow = row0 + lrow;
    const float* p = P + (size_t)lrow * D_DICT;
    float* hrow = hidden + (size_t)grow * D_DICT;
    int t = threadIdx.x;

    if (t == 0) sh_cnt = 0;
    float s = 0.f, s2 = 0.f;
    #pragma unroll 2
    for (int c = 0; c < 8; ++c) {
        int e4 = c * 256 + t;
        float4 v4 = ((const float4*)p)[e4];
        s  += v4.x + v4.y + v4.z + v4.w;
        s2 += v4.x*v4.x + v4.y*v4.y + v4.z*v4.z + v4.w*v4.w;
        *(float4*)&hrow[e4 * 4] = make_float4(0.f, 0.f, 0.f, 0.f);
    }
    #pragma unroll
    for (int off = 32; off; off >>= 1) {
        s  += __shfl_down(s, off);
        s2 += __shfl_down(s2, off);
    }
    if ((t & 63) == 0) { redS[t >> 6] = s; redS2[t >> 6] = s2; }
    __syncthreads();
    if (t == 0) {
        float S  = redS[0] + redS[1] + redS[2] + redS[3];
        float S2 = redS2[0] + redS2[1] + redS2[2] + redS2[3];
        float mu = S * (1.f / D_DICT);
        float var = S2 * (1.f / D_DICT) - mu * mu;
        sh_mu = mu;
        sh_sig = sqrtf(fmaxf(var, 1e-20f));
    }
    __syncthreads();
    float Tlo = sh_mu + 1.3f * sh_sig;

    #pragma unroll 2
    for (int c = 0; c < 8; ++c) {
        int e4 = c * 256 + t;
        float4 v4 = ((const float4*)p)[e4];
        float vv[4] = {v4.x, v4.y, v4.z, v4.w};
        #pragma unroll
        for (int j = 0; j < 4; ++j) {
            if (vv[j] > Tlo) {
                int slot = atomicAdd((uint32*)&sh_cnt, 1u);
                if (slot < CCAP) { cand_val[slot] = vv[j]; cand_idx[slot] = e4 * 4 + j; }
            }
        }
    }
    __syncthreads();
    int n = sh_cnt;
    bool found = (n >= TOPK && n <= CCAP);

    float vT0 = 0.f;
    for (int rtry = 0; rtry < 2; ++rtry) {
        uint32 prefix = 0, need = TOPK;
        for (int pass = 0; pass < 4; ++pass) {
            int shift = 24 - 8 * pass;
            hist[t] = 0;
            __syncthreads();
            uint32 mask_hi = pass ? (0xFFFFFFFFu << (shift + 8)) : 0u;
            if (found) {
                for (int e = t; e < n; e += 256) {
                    uint32 u = okey(cand_val[e]);
                    if ((u & mask_hi) == prefix)
                        atomicAdd(&hist[(u >> shift) & 255u], 1u);
                }
            } else {
                for (int e = t; e < D_DICT; e += 256) {
                    uint32 u = okey(p[e]);
                    if ((u & mask_hi) == prefix)
                        atomicAdd(&hist[(u >> shift) & 255u], 1u);
                }
            }
            __syncthreads();
            if (t == 0) {
                uint32 cum = 0;
                int d = 255;
                for (; d > 0; --d) {
                    uint32 h = hist[d];
                    if (cum + h >= need) break;
                    cum += h;
                }
                sh_prefix = prefix | ((uint32)d << shift);
                sh_need = need - cum;
            }
            __syncthreads();
            prefix = sh_prefix;
            need = sh_need;
            __syncthreads();
        }
        uint32 tb = (prefix & 0x80000000u) ? (prefix & 0x7FFFFFFFu) : ~prefix;
        vT0 = __uint_as_float(tb);
        if (!found) break;
        if (vT0 - BAND - 1e-3f > Tlo) break;
        found = false;
        __syncthreads();
    }

    if (t == 0) { c_clear = 0; bcnt = 0; }
    __syncthreads();
    if (found) {
        for (int e = t; e < n; e += 256) {
            float v = cand_val[e];
            int i = cand_idx[e];
            if (v > vT0 + BAND) {
                hrow[i] = fmaxf(v, 0.f);
                atomicAdd((uint32*)&c_clear, 1u);
            } else if (v >= vT0 - BAND) {
                int slot = atomicAdd((uint32*)&bcnt, 1u);
                if (slot < BCAP) bidx_s[slot] = i;
            }
        }
    } else {
        for (int e = t; e < D_DICT; e += 256) {
            float v = p[e];
            if (v > vT0 + BAND) {
                hrow[e] = fmaxf(v, 0.f);
                atomicAdd((uint32*)&c_clear, 1u);
            } else if (v >= vT0 - BAND) {
                int slot = atomicAdd((uint32*)&bcnt, 1u);
                if (slot < BCAP) bidx_s[slot] = e;
            }
        }
    }
    __syncthreads();

    int nb = bcnt < BCAP ? bcnt : BCAP;
    if (t < nb) {
        const float* xr = x + (size_t)grow * D_IN;
        const float* wr = Wenc + (size_t)bidx_s[t] * D_IN;
        float acc = 0.f;
        #pragma unroll 8
        for (int k = 0; k < D_IN; ++k)
            acc = fmaf(xr[k], wr[k], acc);
        bval_s[t] = acc + b_enc[bidx_s[t]];
    }
    __syncthreads();
    if (t == 0) {
        int take = TOPK - c_clear;
        for (int rr = 0; rr < take; ++rr) {
            int best = -1; float bv = 0.f; int bi = 0;
            for (int e = 0; e < nb; ++e) {
                int idx = bidx_s[e];
                if (idx < 0) continue;
                float v = bval_s[e];
                if (best < 0 || v > bv || (v == bv && idx < bi)) {
                    best = e; bv = v; bi = idx;
                }
            }
            if (best < 0) break;
            bidx_s[best] = -1;
            hrow[bi] = fmaxf(bv, 0.f);
        }
    }
}

__launch_bounds__(256)
__global__ void decode_direct_kernel(const float* __restrict__ hidden,
                                     const float* __restrict__ W_dec,
                                     const float* __restrict__ b_dec,
                                     float* __restrict__ recon) {
    __shared__ float  sv[TOPK];
    __shared__ int    sidx[TOPK];
    __shared__ int    offs[257];
    int row = blockIdx.x;
    int t = threadIdx.x;
    const float* hrow = hidden + (size_t)row * D_DICT;

    int base = t * 32;
    int c = 0;
    for (int j = 0; j < 32; ++j) c += (hrow[base + j] > 0.f) ? 1 : 0;
    offs[t + 1] = c;
    __syncthreads();
    if (t == 0) {
        offs[0] = 0;
        for (int i = 0; i < 256; ++i) offs[i + 1] += offs[i];
    }
    __syncthreads();
    int o = offs[t];
    for (int j = 0; j < 32; ++j) {
        float v = hrow[base + j];
        if (v > 0.f) { sv[o] = v; sidx[o] = base + j; ++o; }
    }
    __syncthreads();
    int total = offs[256];

    int d0 = 2 * t;
    float acc0 = b_dec[d0];
    float acc1 = b_dec[d0 + 1];
    for (int k = 0; k < total; ++k) {
        float v = sv[k];
        int idx = sidx[k];
        acc0 = fmaf(v, W_dec[(size_t)d0 * D_DICT + idx], acc0);
        acc1 = fmaf(v, W_dec[(size_t)(d0 + 1) * D_DICT + idx], acc1);
    }
    *(float2*)&recon[(size_t)row * D_IN + d0] = make_float2(acc0, acc1);
}

// ---------------------------------------------------------------------------
extern "C" void kernel_launch(void* const* d_in, const int* in_sizes, int n_in,
                              void* d_out, int out_size, void* d_ws, size_t ws_size,
                              hipStream_t stream) {
    const float* x     = (const float*)d_in[0];
    const float* W_enc = (const float*)d_in[1];
    const float* b_enc = (const float*)d_in[2];
    const float* W_dec = (const float*)d_in[3];
    const float* b_dec = (const float*)d_in[4];

    float* out    = (float*)d_out;
    float* recon  = out;                          // 16384*512 fp32
    float* hidden = out + (size_t)N_ROWS * D_IN;  // 16384*8192 fp32

    const size_t CNT_BYTES  = (size_t)N_ROWS * sizeof(uint32);
    const size_t FLG_BYTES  = (size_t)N_ROWS * sizeof(uint32);
    const size_t WB_BYTES   = (size_t)D_IN * D_DICT * sizeof(unsigned short);   // 8 MiB
    const size_t WEB_BYTES  = (size_t)D_DICT * D_IN * sizeof(unsigned short);   // 8 MiB
    const size_t XB_BYTES   = (size_t)N_ROWS * D_IN * sizeof(unsigned short);   // 16 MiB
    const size_t CAND_BYTES = (size_t)N_ROWS * CAND_CAP * sizeof(uint2);        // 256 MiB
    const size_t FIXED_B    = CNT_BYTES + FLG_BYTES + WB_BYTES + WEB_BYTES + XB_BYTES + CAND_BYTES;
    const size_t ROW_BYTES  = (size_t)D_DICT * sizeof(float);

    char* ws = (char*)d_ws;

    if (ws_size >= FIXED_B) {
        uint32*         CandCnt = (uint32*)ws;
        uint32*         flags   = (uint32*)(ws + CNT_BYTES);
        unsigned short* Wb      = (unsigned short*)(ws + CNT_BYTES + FLG_BYTES);
        unsigned short* Web     = (unsigned short*)(ws + CNT_BYTES + FLG_BYTES + WB_BYTES);
        unsigned short* Xb      = (unsigned short*)(ws + CNT_BYTES + FLG_BYTES + WB_BYTES + WEB_BYTES);
        uint2*          Cand    = (uint2*)(ws + CNT_BYTES + FLG_BYTES + WB_BYTES + WEB_BYTES + XB_BYTES);

        hipMemsetAsync(CandCnt, 0, CNT_BYTES + FLG_BYTES, stream);
        cast_swz_kernel<<<(D_IN * D_DICT / 8) / 256, 256, 0, stream>>>(W_dec, Wb, 10);
        cast_swz_kernel<<<(D_DICT * D_IN / 8) / 256, 256, 0, stream>>>(W_enc, Web, 6);
        cast_swz_kernel<<<(N_ROWS * D_IN / 8) / 256, 256, 0, stream>>>(x, Xb, 6);

        encode_mfma_cand<<<dim3(D_DICT / 128, N_ROWS / 128), 256, 0, stream>>>(
            Xb, Web, b_enc, Cand, CandCnt);
        select_kernel<<<N_ROWS, 256, 0, stream>>>(Cand, CandCnt, x, W_enc, b_enc, hidden, flags);
        repair_kernel<<<N_ROWS, 256, 0, stream>>>(flags, x, W_enc, b_enc, hidden);

        mfma_decode_kernel<<<N_ROWS / 64, 512, 0, stream>>>(hidden, Wb, b_dec, recon);
    } else {
        float* pre = (float*)ws;
        long long cl = (long long)(ws_size / ROW_BYTES);
        int chunk;
        if (cl >= 128) { chunk = (cl > 2048) ? 2048 : (int)cl; chunk &= ~127; }
        else chunk = (cl < 1) ? 1 : (int)cl;

        for (int r0 = 0; r0 < N_ROWS; r0 += chunk) {
            int nr = (N_ROWS - r0 < chunk) ? (N_ROWS - r0) : chunk;
            dim3 grid((nr + 127) / 128, D_DICT / 128);
            encode_gemm_kernel<<<grid, 256, 0, stream>>>(x, W_enc, b_enc, pre, r0, nr);
            topk_band_kernel<<<nr, 256, 0, stream>>>(pre, r0, x, W_enc, b_enc, hidden);
        }
        decode_direct_kernel<<<N_ROWS, 256, 0, stream>>>(hidden, W_dec, b_dec, recon);
    }
}

// Round 16
// 1247.145 us; speedup vs baseline: 1.5073x; 1.0009x over previous
//
#include <hip/hip_runtime.h>

typedef unsigned int uint32;
typedef __attribute__((ext_vector_type(4))) float  f32x4;
typedef __attribute__((ext_vector_type(8))) short  bf16x8;
typedef __attribute__((ext_vector_type(4))) unsigned short us4;
typedef __attribute__((ext_vector_type(8))) unsigned short us8;

#define N_ROWS   16384
#define D_IN     512
#define D_DICT   8192
#define TOPK     256
#define BAND     1.5e-2f
#define BCAP     64
#define CCAP     2048
#define CAND_CAP 1024
#define TFIX     1.38f

__device__ __forceinline__ unsigned short f2bf_rne(float f) {
    unsigned u = __float_as_uint(f);
    unsigned r = u + 0x7FFFu + ((u >> 16) & 1u);
    return (unsigned short)(r >> 16);
}
__device__ __forceinline__ float bf2f(unsigned short h) {
    return __uint_as_float(((unsigned)h) << 16);
}
__device__ __forceinline__ uint32 okey(float v) {
    uint32 u = __float_as_uint(v);
    return (u & 0x80000000u) ? ~u : (u | 0x80000000u);
}
// XOR-swizzled LDS element address (validated r5-r15)
__device__ __forceinline__ int swz(int row, int k) {
    return row * 64 + (k ^ ((row & 7) << 3));
}
__device__ __forceinline__ void gll16(const unsigned short* g, unsigned short* l) {
    __builtin_amdgcn_global_load_lds(
        (const __attribute__((address_space(1))) unsigned int*)g,
        (__attribute__((address_space(3))) unsigned int*)l, 16, 0, 0);
}

// ---------------------------------------------------------------------------
// Kernel 0: fp32 -> bf16 cast with per-row LDS XOR swizzle baked in.
// ---------------------------------------------------------------------------
__launch_bounds__(256)
__global__ void cast_swz_kernel(const float* __restrict__ src,
                                unsigned short* __restrict__ dst,
                                int gprl) {
    int idx = blockIdx.x * 256 + threadIdx.x;
    int row = idx >> gprl;
    int g   = idx & ((1 << gprl) - 1);
    const float* s = src + ((size_t)idx << 3);
    us8 o;
    #pragma unroll
    for (int j = 0; j < 8; ++j) o[j] = f2bf_rne(s[j]);
    int gout = (g & ~7) | ((g ^ row) & 7);
    *(us8*)&dst[(((size_t)row << gprl) + gout) << 3] = o;
}

// ---------------------------------------------------------------------------
// Kernel 1: single-term bf16 MFMA encode + candidate push (validated r15).
// ---------------------------------------------------------------------------
__launch_bounds__(256)
__global__ void encode_mfma_cand(const unsigned short* __restrict__ Xb,
                                 const unsigned short* __restrict__ Web,
                                 const float* __restrict__ b_enc,
                                 uint2* __restrict__ Cand,
                                 uint32* __restrict__ CandCnt) {
    __shared__ unsigned short At[128 * 64];
    __shared__ unsigned short Bt[128 * 64];

    int tid  = threadIdx.x;
    int lane = tid & 63;
    int wid  = tid >> 6;
    int wm   = wid >> 1;
    int wn   = wid & 1;
    int bn   = blockIdx.x * 128;
    int bm   = blockIdx.y * 128;
    int fr   = lane & 15;

    f32x4 acc[4][4];
    #pragma unroll
    for (int i = 0; i < 4; ++i)
        #pragma unroll
        for (int j = 0; j < 4; ++j) acc[i][j] = (f32x4)0.f;

    for (int c = 0; c < 8; ++c) {
        #pragma unroll
        for (int q = 0; q < 4; ++q) {
            int s = q * 256 + tid;
            int row = s >> 3;
            int g8  = (s & 7) * 8;
            gll16(&Xb[(size_t)(bm + row) * D_IN + c * 64 + g8], &At[row * 64 + g8]);
            gll16(&Web[(size_t)(bn + row) * D_IN + c * 64 + g8], &Bt[row * 64 + g8]);
        }
        __syncthreads();

        #pragma unroll
        for (int ks = 0; ks < 2; ++ks) {
            int kb = ks * 32 + (lane >> 4) * 8;
            bf16x8 av[4], bv[4];
            #pragma unroll
            for (int nj = 0; nj < 4; ++nj)
                bv[nj] = *(const bf16x8*)&Bt[swz(wn * 64 + nj * 16 + fr, kb)];
            #pragma unroll
            for (int mi = 0; mi < 4; ++mi)
                av[mi] = *(const bf16x8*)&At[swz(wm * 64 + mi * 16 + fr, kb)];
            #pragma unroll
            for (int mi = 0; mi < 4; ++mi)
                #pragma unroll
                for (int nj = 0; nj < 4; ++nj)
                    acc[mi][nj] = __builtin_amdgcn_mfma_f32_16x16x32_bf16(
                        av[mi], bv[nj], acc[mi][nj], 0, 0, 0);
        }
        __syncthreads();
    }

    float bcol[4];
    #pragma unroll
    for (int nj = 0; nj < 4; ++nj)
        bcol[nj] = b_enc[bn + wn * 64 + nj * 16 + fr];

    #pragma unroll
    for (int mi = 0; mi < 4; ++mi) {
        int rbase = bm + wm * 64 + mi * 16 + (lane >> 4) * 4;
        #pragma unroll
        for (int reg = 0; reg < 4; ++reg) {
            int r = rbase + reg;
            float v[4]; int pr[4]; int cc = 0;
            #pragma unroll
            for (int nj = 0; nj < 4; ++nj) {
                v[nj] = acc[mi][nj][reg] + bcol[nj];
                pr[nj] = (v[nj] > TFIX) ? 1 : 0;
                cc += pr[nj];
            }
            int incl = cc;
            #pragma unroll
            for (int d = 1; d < 16; d <<= 1) {
                int tv = __shfl_up(incl, d, 16);
                if (fr >= d) incl += tv;
            }
            int total = __shfl(incl, 15, 16);
            if (total > 0) {
                int base = 0;
                if (fr == 0) base = (int)atomicAdd(&CandCnt[r], (uint32)total);
                base = __shfl(base, 0, 16);
                int slot = base + (incl - cc);
                #pragma unroll
                for (int nj = 0; nj < 4; ++nj) {
                    if (pr[nj]) {
                        if (slot < CAND_CAP)
                            Cand[(size_t)r * CAND_CAP + slot] =
                                make_uint2(__float_as_uint(v[nj]),
                                           (uint32)(bn + wn * 64 + nj * 16 + fr));
                        ++slot;
                    }
                }
            }
        }
    }
}

// ---------------------------------------------------------------------------
// Kernel 2 (v4): select. hidden pre-zeroed by hipMemsetAsync -> only scatter
// winners. Emits packed pairs (bf16val<<16 | idx) sorted by idx for the
// pairs-based decode. Flags pathological rows for exact repair.
// ---------------------------------------------------------------------------
__launch_bounds__(256)
__global__ void select_kernel(const uint2* __restrict__ Cand,
                              const uint32* __restrict__ CandCnt,
                              const float* __restrict__ x,
                              const float* __restrict__ Wenc,
                              const float* __restrict__ b_enc,
                              float* __restrict__ hidden,
                              uint32* __restrict__ Pairs,   // [N_ROWS][256]
                              uint32* __restrict__ flags) {
    __shared__ float  cand_val[CAND_CAP];
    __shared__ int    cand_idx[CAND_CAP];
    __shared__ uint32 hist[256];
    __shared__ uint32 pk[256];
    __shared__ uint32 sh_prefix, sh_need;
    __shared__ int    c_clear, bcnt, pcnt;
    __shared__ int    bidx_s[BCAP];
    __shared__ float  bval_s[BCAP];

    int row = blockIdx.x;
    int t = threadIdx.x;
    float* hrow = hidden + (size_t)row * D_DICT;

    int n = (int)CandCnt[row];
    bool ok = (n >= TOPK && n <= CAND_CAP);

    pk[t] = 0x0000FFFFu;                 // pad: val=0, idx=0xFFFF
    if (ok) {
        for (int e = t; e < n; e += 256) {
            uint2 cv = Cand[(size_t)row * CAND_CAP + e];
            cand_val[e] = __uint_as_float(cv.x);
            cand_idx[e] = (int)cv.y;
        }
    }
    __syncthreads();

    float vT0 = 0.f;
    if (ok) {
        uint32 prefix = 0, need = TOPK;
        for (int pass = 0; pass < 4; ++pass) {
            int shift = 24 - 8 * pass;
            hist[t] = 0;
            __syncthreads();
            uint32 mask_hi = pass ? (0xFFFFFFFFu << (shift + 8)) : 0u;
            for (int e = t; e < n; e += 256) {
                uint32 u = okey(cand_val[e]);
                if ((u & mask_hi) == prefix)
                    atomicAdd(&hist[(u >> shift) & 255u], 1u);
            }
            __syncthreads();
            if (t < 64) {
                uint4 h4 = *(const uint4*)&hist[t * 4];
                uint32 lsum = h4.x + h4.y + h4.z + h4.w;
                uint32 s = lsum;
                #pragma unroll
                for (int off = 1; off < 64; off <<= 1) {
                    uint32 vv = __shfl_down(s, off);
                    if (t + off < 64) s += vv;
                }
                uint32 above = s - lsum;
                uint32 suf3 = above + h4.w;
                uint32 suf2 = suf3 + h4.z;
                uint32 suf1 = suf2 + h4.y;
                uint32 suf0 = suf1 + h4.x;
                if (above < need && suf0 >= need) {
                    int j; uint32 sufj, hj;
                    if (suf3 >= need)      { j = 3; sufj = suf3; hj = h4.w; }
                    else if (suf2 >= need) { j = 2; sufj = suf2; hj = h4.z; }
                    else if (suf1 >= need) { j = 1; sufj = suf1; hj = h4.y; }
                    else                   { j = 0; sufj = suf0; hj = h4.x; }
                    sh_prefix = prefix | ((uint32)(t * 4 + j) << shift);
                    sh_need = need - (sufj - hj);
                }
                if (t == 0 && s < need) {
                    sh_prefix = prefix;
                    sh_need = need - (s - h4.x);
                }
            }
            __syncthreads();
            prefix = sh_prefix;
            need = sh_need;
            __syncthreads();
        }
        uint32 tb = (prefix & 0x80000000u) ? (prefix & 0x7FFFFFFFu) : ~prefix;
        vT0 = __uint_as_float(tb);
        if (!(vT0 - BAND - 1e-3f > TFIX)) ok = false;
    }

    if (!ok) {
        if (t == 0) flags[row] = 1u;   // repair writes hidden + pairs
        return;
    }

    if (t == 0) { c_clear = 0; bcnt = 0; pcnt = 0; }
    __syncthreads();
    for (int e = t; e < n; e += 256) {
        float v = cand_val[e];
        int i = cand_idx[e];
        if (v > vT0 + BAND) {
            hrow[i] = v;               // clear winners all > TFIX > 0
            atomicAdd((uint32*)&c_clear, 1u);
            int slot = atomicAdd((uint32*)&pcnt, 1u);
            pk[slot] = ((uint32)f2bf_rne(v) << 16) | (uint32)i;
        } else if (v >= vT0 - BAND) {
            int slot = atomicAdd((uint32*)&bcnt, 1u);
            if (slot < BCAP) bidx_s[slot] = i;
        }
    }
    __syncthreads();

    if (bcnt > BCAP) {
        if (t == 0) flags[row] = 1u;
        return;
    }

    int nb = bcnt;
    if (t < nb) {
        const float* xr = x + (size_t)row * D_IN;
        const float* wr = Wenc + (size_t)bidx_s[t] * D_IN;
        float acc = 0.f;
        #pragma unroll 8
        for (int k = 0; k < D_IN; ++k)   // ascending k — np rounding class
            acc = fmaf(xr[k], wr[k], acc);
        bval_s[t] = acc + b_enc[bidx_s[t]];
    }
    __syncthreads();
    if (t == 0) {
        int take = TOPK - c_clear;
        int pp = pcnt;
        for (int rr = 0; rr < take; ++rr) {
            int best = -1; float bv = 0.f; int bi = 0;
            for (int e = 0; e < nb; ++e) {
                int idx = bidx_s[e];
                if (idx < 0) continue;
                float v = bval_s[e];
                if (best < 0 || v > bv || (v == bv && idx < bi)) {
                    best = e; bv = v; bi = idx;
                }
            }
            if (best < 0) break;
            bidx_s[best] = -1;
            float hv = fmaxf(bv, 0.f);
            if (hv > 0.f) hrow[bi] = hv;     // hidden pre-zeroed
            pk[pp++] = ((uint32)f2bf_rne(hv) << 16) | (uint32)bi;
        }
    }
    __syncthreads();

    // bitonic sort pk by idx (low 16 bits) ascending; pads (0xFFFF) sink to end
    for (int k = 2; k <= 256; k <<= 1) {
        for (int j = k >> 1; j > 0; j >>= 1) {
            int l = t ^ j;
            if (l > t) {
                uint32 a = pk[t], b = pk[l];
                bool up = ((t & k) == 0);
                if (((a & 0xFFFFu) > (b & 0xFFFFu)) == up) { pk[t] = b; pk[l] = a; }
            }
            __syncthreads();
        }
    }
    Pairs[(size_t)row * 256 + t] = pk[t];
}

// ---------------------------------------------------------------------------
// Kernel 2b: exact repair for flagged rows; also emits sorted pairs.
// ---------------------------------------------------------------------------
__launch_bounds__(256)
__global__ void repair_kernel(const uint32* __restrict__ flags,
                              const float* __restrict__ x,
                              const float* __restrict__ Wenc,
                              const float* __restrict__ b_enc,
                              float* __restrict__ hidden,
                              uint32* __restrict__ Pairs) {
    int row = blockIdx.x;
    if (flags[row] == 0u) return;
    __shared__ float  vals[D_DICT];
    __shared__ float  xs[D_IN];
    __shared__ uint32 hist[256];
    __shared__ uint32 pscan[257];
    __shared__ uint32 cnt_eq[256];
    __shared__ int    offs[257];
    __shared__ uint32 sh_prefix, sh_need;
    int t = threadIdx.x;

    for (int c = t; c < D_IN; c += 256) xs[c] = x[(size_t)row * D_IN + c];
    __syncthreads();
    for (int e = t; e < D_DICT; e += 256) {
        const float* wr = Wenc + (size_t)e * D_IN;
        float acc = 0.f;
        #pragma unroll 8
        for (int k = 0; k < D_IN; ++k)   // ascending k — np rounding class
            acc = fmaf(xs[k], wr[k], acc);
        vals[e] = acc + b_enc[e];
    }
    __syncthreads();

    uint32 prefix = 0, need = TOPK;
    for (int pass = 0; pass < 4; ++pass) {
        int shift = 24 - 8 * pass;
        hist[t] = 0;
        __syncthreads();
        uint32 mask_hi = pass ? (0xFFFFFFFFu << (shift + 8)) : 0u;
        #pragma unroll 4
        for (int c = 0; c < 32; ++c) {
            uint32 u = okey(vals[c * 256 + t]);
            if ((u & mask_hi) == prefix)
                atomicAdd(&hist[(u >> shift) & 255u], 1u);
        }
        __syncthreads();
        if (t == 0) {
            uint32 cum = 0;
            int d = 255;
            for (; d > 0; --d) {
                uint32 h = hist[d];
                if (cum + h >= need) break;
                cum += h;
            }
            sh_prefix = prefix | ((uint32)d << shift);
            sh_need = need - cum;
        }
        __syncthreads();
        prefix = sh_prefix;
        need = sh_need;
        __syncthreads();
    }
    uint32 T = prefix;
    uint32 r = need;
    float* hrow = hidden + (size_t)row * D_DICT;

    #pragma unroll 2
    for (int c = 0; c < 32; ++c) {
        int i = c * 256 + t;
        uint32 u = okey(vals[i]);
        float hv = (u > T) ? fmaxf(vals[i], 0.f) : 0.f;
        hrow[i] = hv;
        vals[i] = hv;                 // reuse vals as the relu'd hidden row
    }
    __syncthreads();

    int base = t * 32;
    uint32 local = 0;
    for (int j = 0; j < 32; ++j) {
        int i = base + j;
        // recompute key on original value? vals overwritten: recover tie info:
        // ties have vals[i]==0 unless positive; handle via okey of original is
        // lost — instead mark ties directly below using T on hrow writes.
        local += 0u;
    }
    // tie handling on original values: recompute from x (exact, np class)
    // Simpler: ties are entries where okey(original)==T. Original lost for
    // relu'd entries; recompute the r tie winners exactly:
    cnt_eq[t] = 0;
    __syncthreads();
    // recompute original vals for tie scan (cheap: only needed for equality)
    {
        const float* xr = xs;
        for (int e = t; e < D_DICT; e += 256) {
            const float* wr = Wenc + (size_t)e * D_IN;
            float acc = 0.f;
            #pragma unroll 8
            for (int k = 0; k < D_IN; ++k)
                acc = fmaf(xr[k], wr[k], acc);
            float ov = acc + b_enc[e];
            if (okey(ov) == T) atomicAdd(&cnt_eq[e >> 5], 1u);
        }
    }
    __syncthreads();
    if (t == 0) {
        uint32 s = 0;
        for (int i = 0; i < 256; ++i) { pscan[i] = s; s += cnt_eq[i]; }
    }
    __syncthreads();
    {
        // pass again: within each 32-seg, select ties with global rank < r
        uint32 segbase = pscan[t];
        const float* xr = xs;
        uint32 rank = segbase;
        for (int j = 0; j < 32 && rank < r; ++j) {
            int i = t * 32 + j;
            const float* wr = Wenc + (size_t)i * D_IN;
            float acc = 0.f;
            #pragma unroll 8
            for (int k = 0; k < D_IN; ++k)
                acc = fmaf(xr[k], wr[k], acc);
            float ov = acc + b_enc[i];
            if (okey(ov) == T) {
                float hv = fmaxf(ov, 0.f);
                hrow[i] = hv;
                vals[i] = hv;
                rank++;
            }
        }
    }
    __syncthreads();

    // emit pairs: compact nonzero entries of vals (sorted by construction)
    int base2 = t * 32;
    int c2 = 0;
    for (int j = 0; j < 32; ++j) c2 += (vals[base2 + j] > 0.f) ? 1 : 0;
    offs[t + 1] = c2;
    __syncthreads();
    if (t == 0) {
        offs[0] = 0;
        for (int i = 0; i < 256; ++i) offs[i + 1] += offs[i];
    }
    __syncthreads();
    int o = offs[t];
    for (int j = 0; j < 32; ++j) {
        float v = vals[base2 + j];
        if (v > 0.f) {
            Pairs[(size_t)row * 256 + o] =
                ((uint32)f2bf_rne(v) << 16) | (uint32)(base2 + j);
            ++o;
        }
    }
    __syncthreads();
    int total = offs[256];
    for (int e = total + t; e < 256; e += 256)
        Pairs[(size_t)row * 256 + e] = 0x0000FFFFu;
}

// ---------------------------------------------------------------------------
// Kernel 3 (v3): pairs-based MFMA decode. Stages 64 rows x 256 packed pairs
// (64KB) into LDS once; per k-chunk each row-owner thread zeroes its At row
// and cursor-scatters in-range pairs. At holds bitwise the same bf16 values
// the old hidden-staging produced -> recon numerics unchanged. No hidden read.
// ---------------------------------------------------------------------------
__launch_bounds__(512)
__global__ void mfma_decode_pairs(const uint32* __restrict__ Pairs,
                                  const unsigned short* __restrict__ Wb,
                                  const float* __restrict__ b_dec,
                                  float* __restrict__ recon) {
    __shared__ unsigned short At[64 * 64];    // 8KB
    __shared__ unsigned short Bt[512 * 64];   // 64KB
    __shared__ uint32 prP[64 * 256];          // 64KB packed pairs

    int tid  = threadIdx.x;
    int lane = tid & 63;
    int wn   = tid >> 6;
    int bm   = blockIdx.x * 64;
    int fr   = lane & 15;

    // stage pairs (linear, 4096 x 16B)
    const unsigned short* psrc = (const unsigned short*)(Pairs + (size_t)bm * 256);
    #pragma unroll
    for (int q = 0; q < 8; ++q) {
        int s = q * 512 + tid;
        gll16(&psrc[s * 8], &((unsigned short*)prP)[s * 8]);
    }
    __syncthreads();

    f32x4 acc[4][4];
    #pragma unroll
    for (int i = 0; i < 4; ++i)
        #pragma unroll
        for (int j = 0; j < 4; ++j) acc[i][j] = (f32x4)0.f;

    int cur = 0;   // cursor for row tid (only tid<64 uses it)

    for (int k0 = 0; k0 < D_DICT; k0 += 64) {
        #pragma unroll
        for (int q = 0; q < 8; ++q) {
            int s = q * 512 + tid;
            int row = s >> 3;
            int b8  = (s & 7) * 8;
            gll16(&Wb[(size_t)row * D_DICT + k0 + b8], &Bt[row * 64 + b8]);
        }
        if (tid < 64) {
            int r = tid;
            us8 z = (us8)0;
            #pragma unroll
            for (int g = 0; g < 8; ++g)
                *(us8*)&At[r * 64 + g * 8] = z;
            int kend = k0 + 64;
            while (cur < 256) {
                uint32 p = prP[r * 256 + cur];
                int idx = (int)(p & 0xFFFFu);
                if (idx >= kend) break;
                At[r * 64 + ((idx - k0) ^ ((r & 7) << 3))] = (unsigned short)(p >> 16);
                ++cur;
            }
        }
        __syncthreads();

        #pragma unroll
        for (int ks = 0; ks < 2; ++ks) {
            int kb = ks * 32 + (lane >> 4) * 8;
            bf16x8 av[4], bv[4];
            #pragma unroll
            for (int mi = 0; mi < 4; ++mi)
                av[mi] = *(const bf16x8*)&At[swz(mi * 16 + fr, kb)];
            #pragma unroll
            for (int nj = 0; nj < 4; ++nj)
                bv[nj] = *(const bf16x8*)&Bt[swz(wn * 64 + nj * 16 + fr, kb)];
            #pragma unroll
            for (int mi = 0; mi < 4; ++mi)
                #pragma unroll
                for (int nj = 0; nj < 4; ++nj)
                    acc[mi][nj] = __builtin_amdgcn_mfma_f32_16x16x32_bf16(
                        av[mi], bv[nj], acc[mi][nj], 0, 0, 0);
        }
        __syncthreads();
    }

    #pragma unroll
    for (int mi = 0; mi < 4; ++mi) {
        int r0 = bm + mi * 16 + (lane >> 4) * 4;
        #pragma unroll
        for (int nj = 0; nj < 4; ++nj) {
            int col = wn * 64 + nj * 16 + fr;
            float bd = b_dec[col];
            #pragma unroll
            for (int reg = 0; reg < 4; ++reg)
                recon[(size_t)(r0 + reg) * D_IN + col] = acc[mi][nj][reg] + bd;
        }
    }
}

// ---------------------------------------------------------------------------
// Tier C fallback kernels (validated r10-r15)
// ---------------------------------------------------------------------------
#define EBK 8
#define ESTR 132

__launch_bounds__(256)
__global__ void encode_gemm_kernel(const float* __restrict__ X,
                                   const float* __restrict__ Wenc,
                                   const float* __restrict__ b_enc,
                                   float* __restrict__ P,
                                   int row0, int nrows) {
    __shared__ float As[EBK][ESTR];
    __shared__ float Bs[EBK][ESTR];
    int tid = threadIdx.x;
    int tx = tid & 15;
    int ty = tid >> 4;
    int bm = blockIdx.x * 128;
    int bn = blockIdx.y * 128;
    int srow = tid >> 1;
    int skq  = (tid & 1) * 4;

    float acc[8][8];
    #pragma unroll
    for (int i = 0; i < 8; ++i)
        #pragma unroll
        for (int j = 0; j < 8; ++j) acc[i][j] = 0.f;

    for (int k0 = 0; k0 < D_IN; k0 += EBK) {
        float4 a4 = make_float4(0.f, 0.f, 0.f, 0.f);
        if (bm + srow < nrows)
            a4 = *(const float4*)&X[(size_t)(row0 + bm + srow) * D_IN + k0 + skq];
        float4 b4 = *(const float4*)&Wenc[(size_t)(bn + srow) * D_IN + k0 + skq];
        As[skq + 0][srow] = a4.x; As[skq + 1][srow] = a4.y;
        As[skq + 2][srow] = a4.z; As[skq + 3][srow] = a4.w;
        Bs[skq + 0][srow] = b4.x; Bs[skq + 1][srow] = b4.y;
        Bs[skq + 2][srow] = b4.z; Bs[skq + 3][srow] = b4.w;
        __syncthreads();
        #pragma unroll
        for (int k = 0; k < EBK; ++k) {
            float4 a0 = *(const float4*)&As[k][ty * 4];
            float4 a1 = *(const float4*)&As[k][64 + ty * 4];
            float4 b0 = *(const float4*)&Bs[k][tx * 4];
            float4 b1 = *(const float4*)&Bs[k][64 + tx * 4];
            float a[8] = {a0.x, a0.y, a0.z, a0.w, a1.x, a1.y, a1.z, a1.w};
            float b[8] = {b0.x, b0.y, b0.z, b0.w, b1.x, b1.y, b1.z, b1.w};
            #pragma unroll
            for (int i = 0; i < 8; ++i)
                #pragma unroll
                for (int j = 0; j < 8; ++j)
                    acc[i][j] = fmaf(a[i], b[j], acc[i][j]);
        }
        __syncthreads();
    }

    float4 bias0 = *(const float4*)&b_enc[bn + tx * 4];
    float4 bias1 = *(const float4*)&b_enc[bn + 64 + tx * 4];
    float bb[8] = {bias0.x, bias0.y, bias0.z, bias0.w,
                   bias1.x, bias1.y, bias1.z, bias1.w};
    #pragma unroll
    for (int i = 0; i < 8; ++i) {
        int r = bm + (i < 4 ? ty * 4 + i : 64 + ty * 4 + (i - 4));
        if (r < nrows) {
            float4 o0, o1;
            o0.x = acc[i][0] + bb[0]; o0.y = acc[i][1] + bb[1];
            o0.z = acc[i][2] + bb[2]; o0.w = acc[i][3] + bb[3];
            o1.x = acc[i][4] + bb[4]; o1.y = acc[i][5] + bb[5];
            o1.z = acc[i][6] + bb[6]; o1.w = acc[i][7] + bb[7];
            *(float4*)&P[(size_t)r * D_DICT + bn + tx * 4] = o0;
            *(float4*)&P[(size_t)r * D_DICT + bn + 64 + tx * 4] = o1;
        }
    }
}

__launch_bounds__(256)
__global__ void topk_band_kernel(const float* __restrict__ P,
                                 int row0,
                                 const float* __restrict__ x,
                                 const float* __restrict__ Wenc,
                                 const float* __restrict__ b_enc,
                                 float* __restrict__ hidden) {
    __shared__ float  cand_val[CCAP];
    __shared__ int    cand_idx[CCAP];
    __shared__ uint32 hist[256];
    __shared__ float  redS[4], redS2[4];
    __shared__ float  sh_mu, sh_sig;
    __shared__ uint32 sh_prefix, sh_need;
    __shared__ int    sh_cnt, c_clear, bcnt;
    __shared__ int    bidx_s[BCAP];
    __shared__ float  bval_s[BCAP];

    int lrow = blockIdx.x;
    int grow = row0 + lrow;
    const float* p = P + (size_t)lrow * D_DICT;
    float* hrow = hidden + (size_t)grow * D_DICT;
    int t = threadIdx.x;

    if (t == 0) sh_cnt = 0;
    float s = 0.f, s2 = 0.f;
    #pragma unroll 2
    for (int c = 0; c < 8; ++c) {
        int e4 = c * 256 + t;
        float4 v4 = ((const float4*)p)[e4];
        s  += v4.x + v4.y + v4.z + v4.w;
        s2 += v4.x*v4.x + v4.y*v4.y + v4.z*v4.z + v4.w*v4.w;
        *(float4*)&hrow[e4 * 4] = make_float4(0.f, 0.f, 0.f, 0.f);
    }
    #pragma unroll
    for (int off = 32; off; off >>= 1) {
        s  += __shfl_down(s, off);
        s2 += __shfl_down(s2, off);
    }
    if ((t & 63) == 0) { redS[t >> 6] = s; redS2[t >> 6] = s2; }
    __syncthreads();
    if (t == 0) {
        float S  = redS[0] + redS[1] + redS[2] + redS[3];
        float S2 = redS2[0] + redS2[1] + redS2[2] + redS2[3];
        float mu = S * (1.f / D_DICT);
        float var = S2 * (1.f / D_DICT) - mu * mu;
        sh_mu = mu;
        sh_sig = sqrtf(fmaxf(var, 1e-20f));
    }
    __syncthreads();
    float Tlo = sh_mu + 1.3f * sh_sig;

    #pragma unroll 2
    for (int c = 0; c < 8; ++c) {
        int e4 = c * 256 + t;
        float4 v4 = ((const float4*)p)[e4];
        float vv[4] = {v4.x, v4.y, v4.z, v4.w};
        #pragma unroll
        for (int j = 0; j < 4; ++j) {
            if (vv[j] > Tlo) {
                int slot = atomicAdd((uint32*)&sh_cnt, 1u);
                if (slot < CCAP) { cand_val[slot] = vv[j]; cand_idx[slot] = e4 * 4 + j; }
            }
        }
    }
    __syncthreads();
    int n = sh_cnt;
    bool found = (n >= TOPK && n <= CCAP);

    float vT0 = 0.f;
    for (int rtry = 0; rtry < 2; ++rtry) {
        uint32 prefix = 0, need = TOPK;
        for (int pass = 0; pass < 4; ++pass) {
            int shift = 24 - 8 * pass;
            hist[t] = 0;
            __syncthreads();
            uint32 mask_hi = pass ? (0xFFFFFFFFu << (shift + 8)) : 0u;
            if (found) {
                for (int e = t; e < n; e += 256) {
                    uint32 u = okey(cand_val[e]);
                    if ((u & mask_hi) == prefix)
                        atomicAdd(&hist[(u >> shift) & 255u], 1u);
                }
            } else {
                for (int e = t; e < D_DICT; e += 256) {
                    uint32 u = okey(p[e]);
                    if ((u & mask_hi) == prefix)
                        atomicAdd(&hist[(u >> shift) & 255u], 1u);
                }
            }
            __syncthreads();
            if (t == 0) {
                uint32 cum = 0;
                int d = 255;
                for (; d > 0; --d) {
                    uint32 h = hist[d];
                    if (cum + h >= need) break;
                    cum += h;
                }
                sh_prefix = prefix | ((uint32)d << shift);
                sh_need = need - cum;
            }
            __syncthreads();
            prefix = sh_prefix;
            need = sh_need;
            __syncthreads();
        }
        uint32 tb = (prefix & 0x80000000u) ? (prefix & 0x7FFFFFFFu) : ~prefix;
        vT0 = __uint_as_float(tb);
        if (!found) break;
        if (vT0 - BAND - 1e-3f > Tlo) break;
        found = false;
        __syncthreads();
    }

    if (t == 0) { c_clear = 0; bcnt = 0; }
    __syncthreads();
    if (found) {
        for (int e = t; e < n; e += 256) {
            float v = cand_val[e];
            int i = cand_idx[e];
            if (v > vT0 + BAND) {
                hrow[i] = fmaxf(v, 0.f);
                atomicAdd((uint32*)&c_clear, 1u);
            } else if (v >= vT0 - BAND) {
                int slot = atomicAdd((uint32*)&bcnt, 1u);
                if (slot < BCAP) bidx_s[slot] = i;
            }
        }
    } else {
        for (int e = t; e < D_DICT; e += 256) {
            float v = p[e];
            if (v > vT0 + BAND) {
                hrow[e] = fmaxf(v, 0.f);
                atomicAdd((uint32*)&c_clear, 1u);
            } else if (v >= vT0 - BAND) {
                int slot = atomicAdd((uint32*)&bcnt, 1u);
                if (slot < BCAP) bidx_s[slot] = e;
            }
        }
    }
    __syncthreads();

    int nb = bcnt < BCAP ? bcnt : BCAP;
    if (t < nb) {
        const float* xr = x + (size_t)grow * D_IN;
        const float* wr = Wenc + (size_t)bidx_s[t] * D_IN;
        float acc = 0.f;
        #pragma unroll 8
        for (int k = 0; k < D_IN; ++k)
            acc = fmaf(xr[k], wr[k], acc);
        bval_s[t] = acc + b_enc[bidx_s[t]];
    }
    __syncthreads();
    if (t == 0) {
        int take = TOPK - c_clear;
        for (int rr = 0; rr < take; ++rr) {
            int best = -1; float bv = 0.f; int bi = 0;
            for (int e = 0; e < nb; ++e) {
                int idx = bidx_s[e];
                if (idx < 0) continue;
                float v = bval_s[e];
                if (best < 0 || v > bv || (v == bv && idx < bi)) {
                    best = e; bv = v; bi = idx;
                }
            }
            if (best < 0) break;
            bidx_s[best] = -1;
            hrow[bi] = fmaxf(bv, 0.f);
        }
    }
}

__launch_bounds__(256)
__global__ void decode_direct_kernel(const float* __restrict__ hidden,
                                     const float* __restrict__ W_dec,
                                     const float* __restrict__ b_dec,
                                     float* __restrict__ recon) {
    __shared__ float  sv[TOPK];
    __shared__ int    sidx[TOPK];
    __shared__ int    offs[257];
    int row = blockIdx.x;
    int t = threadIdx.x;
    const float* hrow = hidden + (size_t)row * D_DICT;

    int base = t * 32;
    int c = 0;
    for (int j = 0; j < 32; ++j) c += (hrow[base + j] > 0.f) ? 1 : 0;
    offs[t + 1] = c;
    __syncthreads();
    if (t == 0) {
        offs[0] = 0;
        for (int i = 0; i < 256; ++i) offs[i + 1] += offs[i];
    }
    __syncthreads();
    int o = offs[t];
    for (int j = 0; j < 32; ++j) {
        float v = hrow[base + j];
        if (v > 0.f) { sv[o] = v; sidx[o] = base + j; ++o; }
    }
    __syncthreads();
    int total = offs[256];

    int d0 = 2 * t;
    float acc0 = b_dec[d0];
    float acc1 = b_dec[d0 + 1];
    for (int k = 0; k < total; ++k) {
        float v = sv[k];
        int idx = sidx[k];
        acc0 = fmaf(v, W_dec[(size_t)d0 * D_DICT + idx], acc0);
        acc1 = fmaf(v, W_dec[(size_t)(d0 + 1) * D_DICT + idx], acc1);
    }
    *(float2*)&recon[(size_t)row * D_IN + d0] = make_float2(acc0, acc1);
}

// ---------------------------------------------------------------------------
extern "C" void kernel_launch(void* const* d_in, const int* in_sizes, int n_in,
                              void* d_out, int out_size, void* d_ws, size_t ws_size,
                              hipStream_t stream) {
    const float* x     = (const float*)d_in[0];
    const float* W_enc = (const float*)d_in[1];
    const float* b_enc = (const float*)d_in[2];
    const float* W_dec = (const float*)d_in[3];
    const float* b_dec = (const float*)d_in[4];

    float* out    = (float*)d_out;
    float* recon  = out;                          // 16384*512 fp32
    float* hidden = out + (size_t)N_ROWS * D_IN;  // 16384*8192 fp32

    const size_t CNT_BYTES   = (size_t)N_ROWS * sizeof(uint32);
    const size_t FLG_BYTES   = (size_t)N_ROWS * sizeof(uint32);
    const size_t WB_BYTES    = (size_t)D_IN * D_DICT * sizeof(unsigned short);   // 8 MiB
    const size_t WEB_BYTES   = (size_t)D_DICT * D_IN * sizeof(unsigned short);   // 8 MiB
    const size_t XB_BYTES    = (size_t)N_ROWS * D_IN * sizeof(unsigned short);   // 16 MiB
    const size_t PAIRS_BYTES = (size_t)N_ROWS * 256 * sizeof(uint32);            // 16 MiB
    const size_t CAND_BYTES  = (size_t)N_ROWS * CAND_CAP * sizeof(uint2);        // 128 MiB
    const size_t FIXED_B     = CNT_BYTES + FLG_BYTES + WB_BYTES + WEB_BYTES +
                               XB_BYTES + PAIRS_BYTES + CAND_BYTES;
    const size_t ROW_BYTES   = (size_t)D_DICT * sizeof(float);

    char* ws = (char*)d_ws;

    if (ws_size >= FIXED_B) {
        uint32*         CandCnt = (uint32*)ws;
        uint32*         flags   = (uint32*)(ws + CNT_BYTES);
        unsigned short* Wb      = (unsigned short*)(ws + CNT_BYTES + FLG_BYTES);
        unsigned short* Web     = (unsigned short*)(ws + CNT_BYTES + FLG_BYTES + WB_BYTES);
        unsigned short* Xb      = (unsigned short*)(ws + CNT_BYTES + FLG_BYTES + WB_BYTES + WEB_BYTES);
        uint32*         Pairs   = (uint32*)(ws + CNT_BYTES + FLG_BYTES + WB_BYTES + WEB_BYTES + XB_BYTES);
        uint2*          Cand    = (uint2*)(ws + CNT_BYTES + FLG_BYTES + WB_BYTES + WEB_BYTES + XB_BYTES + PAIRS_BYTES);

        hipMemsetAsync(CandCnt, 0, CNT_BYTES + FLG_BYTES, stream);
        hipMemsetAsync(hidden, 0, (size_t)N_ROWS * D_DICT * sizeof(float), stream);
        cast_swz_kernel<<<(D_IN * D_DICT / 8) / 256, 256, 0, stream>>>(W_dec, Wb, 10);
        cast_swz_kernel<<<(D_DICT * D_IN / 8) / 256, 256, 0, stream>>>(W_enc, Web, 6);
        cast_swz_kernel<<<(N_ROWS * D_IN / 8) / 256, 256, 0, stream>>>(x, Xb, 6);

        encode_mfma_cand<<<dim3(D_DICT / 128, N_ROWS / 128), 256, 0, stream>>>(
            Xb, Web, b_enc, Cand, CandCnt);
        select_kernel<<<N_ROWS, 256, 0, stream>>>(Cand, CandCnt, x, W_enc, b_enc,
                                                  hidden, Pairs, flags);
        repair_kernel<<<N_ROWS, 256, 0, stream>>>(flags, x, W_enc, b_enc, hidden, Pairs);

        mfma_decode_pairs<<<N_ROWS / 64, 512, 0, stream>>>(Pairs, Wb, b_dec, recon);
    } else {
        float* pre = (float*)ws;
        long long cl = (long long)(ws_size / ROW_BYTES);
        int chunk;
        if (cl >= 128) { chunk = (cl > 2048) ? 2048 : (int)cl; chunk &= ~127; }
        else chunk = (cl < 1) ? 1 : (int)cl;

        for (int r0 = 0; r0 < N_ROWS; r0 += chunk) {
            int nr = (N_ROWS - r0 < chunk) ? (N_ROWS - r0) : chunk;
            dim3 grid((nr + 127) / 128, D_DICT / 128);
            encode_gemm_kernel<<<grid, 256, 0, stream>>>(x, W_enc, b_enc, pre, r0, nr);
            topk_band_kernel<<<nr, 256, 0, stream>>>(pre, r0, x, W_enc, b_enc, hidden);
        }
        decode_direct_kernel<<<N_ROWS, 256, 0, stream>>>(hidden, W_dec, b_dec, recon);
    }
}